// Round 3
// baseline (2499.127 us; speedup 1.0000x reference)
//
#include <hip/hip_runtime.h>
#include <math.h>

#define NN 50000
#define NE 600000
#define DD 128
#define D3 384
#define NB_ 20
#define HH 64
#define NG_ 512

__device__ __forceinline__ float silu_f(float z) { return z / (1.0f + expf(-z)); }

// ---------------- utility ----------------
__global__ void zero_f_kernel(float* __restrict__ p, long n) {
  long i = (long)blockIdx.x * blockDim.x + threadIdx.x;
  long s = (long)gridDim.x * blockDim.x;
  for (; i < n; i += s) p[i] = 0.0f;
}

__global__ void zero_i_kernel(int* __restrict__ p, long n) {
  long i = (long)blockIdx.x * blockDim.x + threadIdx.x;
  long s = (long)gridDim.x * blockDim.x;
  for (; i < n; i += s) p[i] = 0;
}

__global__ void init_x_kernel(const int* __restrict__ at_no, const float* __restrict__ emb,
                              float* __restrict__ x) {
  int i = blockIdx.x * blockDim.x + threadIdx.x;
  if (i >= NN * DD) return;
  x[i] = emb[at_no[i >> 7] * DD + (i & 127)];
}

// ---------------- CSR build (dst-sorted), filtering dist>=CUTOFF edges ----------------
__global__ void hist_kernel(const int* __restrict__ ei, const float* __restrict__ pos,
                            int* __restrict__ counts) {
  int e = blockIdx.x * blockDim.x + threadIdx.x;
  if (e >= NE) return;
  int s = ei[e], d = ei[NE + e];
  float dx = pos[3*d]   - pos[3*s];
  float dy = pos[3*d+1] - pos[3*s+1];
  float dz = pos[3*d+2] - pos[3*s+2];
  float d2 = dx*dx + dy*dy + dz*dz + 1e-12f;
  if (d2 < 25.0f) atomicAdd(&counts[d], 1);   // dist < 5 <=> fcut > 0
}

__global__ void scan_kernel(const int* __restrict__ counts, int* __restrict__ indptr, int n) {
  __shared__ int sm[1024];
  __shared__ int carry_s;
  if (threadIdx.x == 0) carry_s = 0;
  __syncthreads();
  for (int start = 0; start < n; start += 1024) {
    int i = start + (int)threadIdx.x;
    int val = (i < n) ? counts[i] : 0;
    sm[threadIdx.x] = val;
    __syncthreads();
    for (int off = 1; off < 1024; off <<= 1) {
      int t = (threadIdx.x >= (unsigned)off) ? sm[threadIdx.x - off] : 0;
      __syncthreads();
      sm[threadIdx.x] += t;
      __syncthreads();
    }
    int c = carry_s;
    if (i < n) indptr[i] = c + sm[threadIdx.x] - val;  // exclusive
    __syncthreads();
    if (threadIdx.x == 0) carry_s = c + sm[1023];
    __syncthreads();
  }
  if (threadIdx.x == 0) indptr[n] = carry_s;
}

// stores SRC node id directly (edge id no longer needed downstream)
__global__ void fill_kernel(const int* __restrict__ ei, const float* __restrict__ pos,
                            const int* __restrict__ indptr, int* __restrict__ cursor,
                            int* __restrict__ srcs) {
  int e = blockIdx.x * blockDim.x + threadIdx.x;
  if (e >= NE) return;
  int s = ei[e], d = ei[NE + e];
  float dx = pos[3*d]   - pos[3*s];
  float dy = pos[3*d+1] - pos[3*s+1];
  float dz = pos[3*d+2] - pos[3*s+2];
  float d2 = dx*dx + dy*dy + dz*dz + 1e-12f;
  if (d2 < 25.0f) {
    int p = atomicAdd(&cursor[d], 1);
    srcs[indptr[d] + p] = s;
  }
}

// ---------------- GEMM: C[M,128] = A[M,K] @ B[K,:] (+bias)(+silu), 8 rows/block ----------------
template<int K, bool SILU, bool BIAS>
__global__ void __launch_bounds__(128) gemm8_kernel(
    const float* __restrict__ A, const float* __restrict__ B, int ldb,
    const float* __restrict__ bias, float* __restrict__ C) {
  int col = threadIdx.x;                 // 128 cols
  long r0 = (long)blockIdx.x * 8;
  const float* a = A + r0 * K;
  float acc[8] = {0,0,0,0,0,0,0,0};
  for (int k = 0; k < K; k += 4) {
    float4 av[8];
    #pragma unroll
    for (int r = 0; r < 8; r++) av[r] = *(const float4*)(a + r*K + k);
    float b0 = B[(long)(k+0)*ldb + col];
    float b1 = B[(long)(k+1)*ldb + col];
    float b2 = B[(long)(k+2)*ldb + col];
    float b3 = B[(long)(k+3)*ldb + col];
    #pragma unroll
    for (int r = 0; r < 8; r++)
      acc[r] += av[r].x*b0 + av[r].y*b1 + av[r].z*b2 + av[r].w*b3;
  }
  float bb = 0.f;
  if constexpr (BIAS) bb = bias[col];
  #pragma unroll
  for (int r = 0; r < 8; r++) {
    float v = acc[r] + bb;
    if constexpr (SILU) v = silu_f(v);
    C[(r0 + r)*DD + col] = v;
  }
}

// ---------------- message pass, one 128-col slice of phi/filt at a time ----------------
// SLICE 0: x += seg(ds);  SLICE 1: vB = vA + seg(dv1*dir);  SLICE 2: vB += seg(dv2*v[src])
template<int SLICE>
__global__ void __launch_bounds__(128) msg_kernel(
    const float* __restrict__ phiS, const float* __restrict__ vA,
    float* __restrict__ vB, float* __restrict__ x,
    const float* __restrict__ pos,
    const int* __restrict__ srcs, const int* __restrict__ indptr,
    const float* __restrict__ Wf_l, const float* __restrict__ bf_l) {
  int n = blockIdx.x;
  int d = threadIdx.x;
  float wf[NB_];
  #pragma unroll
  for (int k = 0; k < NB_; k++) wf[k] = Wf_l[k*D3 + SLICE*DD + d];
  float bfv = bf_l[SLICE*DD + d];
  float px = pos[3*n], py = pos[3*n+1], pz = pos[3*n+2];
  int beg = indptr[n], end = indptr[n+1];
  float a0 = 0.f, a1 = 0.f, a2 = 0.f, xacc = 0.f;
  for (int t = beg; t < end; t++) {
    int s = srcs[t];
    float dx = px - pos[3*s], dy = py - pos[3*s+1], dz = pz - pos[3*s+2];
    float d2 = dx*dx + dy*dy + dz*dz + 1e-12f;
    float dist = sqrtf(d2);
    float inv  = 1.0f / dist;
    float wang = 0.62831853071795864769f * dist;   // pi*dist/CUTOFF
    float s1 = __sinf(wang), c1 = __cosf(wang);
    float fc = 0.5f * (c1 + 1.0f);                 // dist<5 guaranteed by CSR filter
    float c2 = 2.0f * c1;
    // dot = sum_k sin((k+1)*w) * wf[k], Chebyshev-style sine recurrence
    float rkm1 = 0.f, rk = s1, dot = 0.f;
    #pragma unroll
    for (int k = 0; k < NB_; k++) {
      dot = fmaf(rk, wf[k], dot);
      float rn = fmaf(c2, rk, -rkm1);
      rkm1 = rk; rk = rn;
    }
    float f = bfv*fc + fc*inv*dot;
    float m = phiS[(long)s*DD + d] * f;
    if constexpr (SLICE == 0) {
      xacc += m;
    } else if constexpr (SLICE == 1) {
      a0 = fmaf(m, dx*inv, a0);
      a1 = fmaf(m, dy*inv, a1);
      a2 = fmaf(m, dz*inv, a2);
    } else {
      const float* vs = vA + (long)s*D3;
      a0 = fmaf(m, vs[d],      a0);
      a1 = fmaf(m, vs[DD+d],   a1);
      a2 = fmaf(m, vs[2*DD+d], a2);
    }
  }
  if constexpr (SLICE == 0) {
    x[(long)n*DD + d] += xacc;
  } else if constexpr (SLICE == 1) {
    long b = (long)n*D3 + d;
    vB[b]        = vA[b]        + a0;
    vB[b + DD]   = vA[b + DD]   + a1;
    vB[b + 2*DD] = vA[b + 2*DD] + a2;
  } else {
    long b = (long)n*D3 + d;
    vB[b]        += a0;
    vB[b + DD]   += a1;
    vB[b + 2*DD] += a2;
  }
}

// ---------------- fused Uv/Vv/Vn/s: 4 nodes/block ----------------
__global__ void __launch_bounds__(128) uvn_kernel(
    const float* __restrict__ v, const float* __restrict__ U_l,
    const float* __restrict__ V_l, float* __restrict__ Uvbuf,
    float* __restrict__ Vn, float* __restrict__ s_out) {
  __shared__ float vs[4][3][DD];
  long r0 = (long)blockIdx.x * 4;
  int d = threadIdx.x;
  #pragma unroll
  for (int r = 0; r < 4; r++)
    #pragma unroll
    for (int c = 0; c < 3; c++)
      vs[r][c][d] = v[(r0+r)*D3 + c*DD + d];
  __syncthreads();
  float u[4][3] = {}, wv[4][3] = {};
  for (int k = 0; k < DD; k++) {
    float uk = U_l[k*DD + d], vk = V_l[k*DD + d];
    #pragma unroll
    for (int r = 0; r < 4; r++)
      #pragma unroll
      for (int c = 0; c < 3; c++) {
        float a = vs[r][c][k];
        u[r][c]  = fmaf(a, uk, u[r][c]);
        wv[r][c] = fmaf(a, vk, wv[r][c]);
      }
  }
  #pragma unroll
  for (int r = 0; r < 4; r++) {
    long b = (r0+r)*D3 + d;
    Uvbuf[b]        = u[r][0];
    Uvbuf[b + DD]   = u[r][1];
    Uvbuf[b + 2*DD] = u[r][2];
    float w0 = wv[r][0], w1 = wv[r][1], w2 = wv[r][2];
    Vn[(r0+r)*DD + d]    = sqrtf(w0*w0 + w1*w1 + w2*w2 + 1e-8f);
    s_out[(r0+r)*DD + d] = u[r][0]*w0 + u[r][1]*w1 + u[r][2]*w2;
  }
}

// ---------------- fused a-MLP + update: 8 nodes/block, no 'a' buffer ----------------
__global__ void __launch_bounds__(128) aupd_kernel(
    float* __restrict__ x, float* __restrict__ v,
    const float* __restrict__ Vn, const float* __restrict__ s_in,
    const float* __restrict__ Uv,
    const float* __restrict__ Wu1_l, const float* __restrict__ bu1_l,
    const float* __restrict__ Wu2_l, const float* __restrict__ bu2_l) {
  __shared__ float cat[8][2*DD];
  __shared__ float t2[8][DD];
  long r0 = (long)blockIdx.x * 8;
  int d = threadIdx.x;
  #pragma unroll
  for (int r = 0; r < 8; r++) {
    cat[r][d]      = x[(r0+r)*DD + d];
    cat[r][DD + d] = Vn[(r0+r)*DD + d];
  }
  __syncthreads();
  float acc[8] = {};
  for (int k = 0; k < 2*DD; k++) {
    float wu = Wu1_l[k*DD + d];
    #pragma unroll
    for (int r = 0; r < 8; r++) acc[r] = fmaf(cat[r][k], wu, acc[r]);
  }
  float b1 = bu1_l[d];
  #pragma unroll
  for (int r = 0; r < 8; r++) t2[r][d] = silu_f(acc[r] + b1);
  __syncthreads();
  float avv[8] = {}, asv[8] = {}, ass[8] = {};
  for (int k = 0; k < DD; k++) {
    float w0 = Wu2_l[k*D3 + d];
    float w1 = Wu2_l[k*D3 + DD + d];
    float w2 = Wu2_l[k*D3 + 2*DD + d];
    #pragma unroll
    for (int r = 0; r < 8; r++) {
      float tv = t2[r][k];
      avv[r] = fmaf(tv, w0, avv[r]);
      asv[r] = fmaf(tv, w1, asv[r]);
      ass[r] = fmaf(tv, w2, ass[r]);
    }
  }
  float b20 = bu2_l[d], b21 = bu2_l[DD + d], b22 = bu2_l[2*DD + d];
  #pragma unroll
  for (int r = 0; r < 8; r++) {
    long row = r0 + r;
    float sv = s_in[row*DD + d];
    x[row*DD + d] += (ass[r] + b22) + (asv[r] + b21) * sv;
    float av = avv[r] + b20;
    long b = row*D3 + d;
    v[b]        = fmaf(av, Uv[b],        v[b]);
    v[b + DD]   = fmaf(av, Uv[b + DD],   v[b + DD]);
    v[b + 2*DD] = fmaf(av, Uv[b + 2*DD], v[b + 2*DD]);
  }
}

// ---------------- output head + segment sum over batch ----------------
__global__ void __launch_bounds__(64) out_kernel(
    const float* __restrict__ x, const float* __restrict__ Wo1,
    const float* __restrict__ bo1, const float* __restrict__ Wo2,
    const float* __restrict__ bo2, const int* __restrict__ batch,
    float* __restrict__ out) {
  int n = blockIdx.x;
  int t = threadIdx.x;   // 0..63
  const float* xr = x + (long)n * DD;
  float acc = bo1[t];
  #pragma unroll 8
  for (int k = 0; k < DD; k++) acc += xr[k] * Wo1[k*HH + t];
  float h = silu_f(acc);
  float val = h * Wo2[t];
  for (int off = 32; off > 0; off >>= 1) val += __shfl_down(val, off);
  if (t == 0) atomicAdd(&out[batch[n]], val + bo2[0]);
}

// ---------------- launcher ----------------
extern "C" void kernel_launch(void* const* d_in, const int* in_sizes, int n_in,
                              void* d_out, int out_size, void* d_ws, size_t ws_size,
                              hipStream_t stream) {
  const int*   at_no = (const int*)d_in[0];
  const float* pos   = (const float*)d_in[1];
  const int*   ei    = (const int*)d_in[2];
  const int*   batch = (const int*)d_in[3];
  const float* emb   = (const float*)d_in[4];
  const float* Wf    = (const float*)d_in[5];
  const float* bfp   = (const float*)d_in[6];
  const float* Wm1   = (const float*)d_in[7];
  const float* bm1   = (const float*)d_in[8];
  const float* Wm2   = (const float*)d_in[9];
  const float* bm2   = (const float*)d_in[10];
  const float* U     = (const float*)d_in[11];
  const float* V     = (const float*)d_in[12];
  const float* Wu1   = (const float*)d_in[13];
  const float* bu1   = (const float*)d_in[14];
  const float* Wu2   = (const float*)d_in[15];
  const float* bu2   = (const float*)d_in[16];
  const float* Wo1   = (const float*)d_in[17];
  const float* bo1   = (const float*)d_in[18];
  const float* Wo2   = (const float*)d_in[19];
  const float* bo2   = (const float*)d_in[20];
  float* out = (float*)d_out;

  char* w = (char*)d_ws;
  auto alloc = [&](size_t bytes) -> void* {
    void* p = (void*)w;
    w += (bytes + 255) & ~(size_t)255;
    return p;
  };
  float* x      = (float*)alloc(sizeof(float)*(size_t)NN*DD);   // 25.6 MB
  float* v_a    = (float*)alloc(sizeof(float)*(size_t)NN*D3);   // 76.8 MB
  float* v_b    = (float*)alloc(sizeof(float)*(size_t)NN*D3);   // 76.8 MB
  float* t1     = (float*)alloc(sizeof(float)*(size_t)NN*DD);   // 25.6 MB (reused: Vn)
  float* phiS   = (float*)alloc(sizeof(float)*(size_t)NN*DD);   // 25.6 MB (reused: s)
  int*   srcs   = (int*)alloc(sizeof(int)*(size_t)NE);          //  2.4 MB
  int*   indptr = (int*)alloc(sizeof(int)*((size_t)NN+1));
  int*   counts = (int*)alloc(sizeof(int)*(size_t)NN);

  // workspace guard (diagnostic: zeros out => budget still too small)
  if ((size_t)(w - (char*)d_ws) > ws_size) {
    zero_f_kernel<<<2, 256, 0, stream>>>(out, NG_);
    return;
  }

  // init / precompute
  zero_f_kernel<<<2048, 256, 0, stream>>>(v_a, (long)NN*D3);
  zero_f_kernel<<<2, 256, 0, stream>>>(out, NG_);
  zero_i_kernel<<<64, 256, 0, stream>>>(counts, NN);
  init_x_kernel<<<(NN*DD + 255)/256, 256, 0, stream>>>(at_no, emb, x);
  hist_kernel<<<(NE + 255)/256, 256, 0, stream>>>(ei, pos, counts);
  scan_kernel<<<1, 1024, 0, stream>>>(counts, indptr, NN);
  zero_i_kernel<<<64, 256, 0, stream>>>(counts, NN);
  fill_kernel<<<(NE + 255)/256, 256, 0, stream>>>(ei, pos, indptr, counts, srcs);

  float* vcur = v_a;
  float* vnext = v_b;
  for (int l = 0; l < 3; l++) {
    const float* Wf_l  = Wf  + (size_t)l*NB_*D3;
    const float* bf_l  = bfp + (size_t)l*D3;
    const float* Wm1_l = Wm1 + (size_t)l*DD*DD;
    const float* bm1_l = bm1 + (size_t)l*DD;
    const float* Wm2_l = Wm2 + (size_t)l*DD*D3;
    const float* bm2_l = bm2 + (size_t)l*D3;
    const float* U_l   = U   + (size_t)l*DD*DD;
    const float* V_l   = V   + (size_t)l*DD*DD;
    const float* Wu1_l = Wu1 + (size_t)l*2*DD*DD;
    const float* bu1_l = bu1 + (size_t)l*DD;
    const float* Wu2_l = Wu2 + (size_t)l*DD*D3;
    const float* bu2_l = bu2 + (size_t)l*D3;

    // t1 = silu(x@Wm1 + bm1)
    gemm8_kernel<DD, true, true><<<NN/8, 128, 0, stream>>>(x, Wm1_l, DD, bm1_l, t1);
    // per 128-col slice: phiS = t1@Wm2[:,slice] + bm2[slice], then message pass
    gemm8_kernel<DD, false, true><<<NN/8, 128, 0, stream>>>(t1, Wm2_l + 0*DD, D3, bm2_l + 0*DD, phiS);
    msg_kernel<0><<<NN, 128, 0, stream>>>(phiS, vcur, vnext, x, pos, srcs, indptr, Wf_l, bf_l);
    gemm8_kernel<DD, false, true><<<NN/8, 128, 0, stream>>>(t1, Wm2_l + 1*DD, D3, bm2_l + 1*DD, phiS);
    msg_kernel<1><<<NN, 128, 0, stream>>>(phiS, vcur, vnext, x, pos, srcs, indptr, Wf_l, bf_l);
    gemm8_kernel<DD, false, true><<<NN/8, 128, 0, stream>>>(t1, Wm2_l + 2*DD, D3, bm2_l + 2*DD, phiS);
    msg_kernel<2><<<NN, 128, 0, stream>>>(phiS, vcur, vnext, x, pos, srcs, indptr, Wf_l, bf_l);
    // fused Uv/Vv/Vn/s: Uv -> dead vcur buffer, Vn -> dead t1, s -> dead phiS
    uvn_kernel<<<NN/4, 128, 0, stream>>>(vnext, U_l, V_l, vcur, t1, phiS);
    // fused a-MLP + update (reads Vn=t1, s=phiS, Uv=vcur; writes x, vnext)
    aupd_kernel<<<NN/8, 128, 0, stream>>>(x, vnext, t1, phiS, vcur,
                                          Wu1_l, bu1_l, Wu2_l, bu2_l);

    float* tmp = vcur; vcur = vnext; vnext = tmp;
  }

  out_kernel<<<NN, 64, 0, stream>>>(x, Wo1, bo1, Wo2, bo2, batch, out);

  (void)in_sizes; (void)n_in; (void)out_size; (void)ws_size;
}

// Round 4
// 1999.704 us; speedup vs baseline: 1.2497x; 1.2497x over previous
//
#include <hip/hip_runtime.h>
#include <math.h>

#define NN 50000
#define NE 600000
#define DD 128
#define D3 384
#define NB_ 20
#define HH 64
#define NG_ 512
#define LSZ 180224   // shorts per layer of transposed-bf16 weights

typedef short v8s __attribute__((ext_vector_type(8)));
typedef float v4f __attribute__((ext_vector_type(4)));

__device__ __forceinline__ float silu_f(float z) { return z / (1.0f + expf(-z)); }

__device__ __forceinline__ short f2bf(float f) {
  unsigned u = __float_as_uint(f);
  u += 0x7FFF + ((u >> 16) & 1);          // RNE
  return (short)(u >> 16);
}
__device__ __forceinline__ float bf2f(short s) {
  return __uint_as_float(((unsigned)(unsigned short)s) << 16);
}
__device__ __forceinline__ void split2(float x, short& h, short& l) {
  h = f2bf(x);
  l = f2bf(x - bf2f(h));
}

// ---------------- utility ----------------
__global__ void zero_f_kernel(float* __restrict__ p, long n) {
  long i = (long)blockIdx.x * blockDim.x + threadIdx.x;
  long s = (long)gridDim.x * blockDim.x;
  for (; i < n; i += s) p[i] = 0.0f;
}

__global__ void zero_i_kernel(int* __restrict__ p, long n) {
  long i = (long)blockIdx.x * blockDim.x + threadIdx.x;
  long s = (long)gridDim.x * blockDim.x;
  for (; i < n; i += s) p[i] = 0;
}

__global__ void init_x_kernel(const int* __restrict__ at_no, const float* __restrict__ emb,
                              float* __restrict__ x) {
  int i = blockIdx.x * blockDim.x + threadIdx.x;
  if (i >= NN * DD) return;
  x[i] = emb[at_no[i >> 7] * DD + (i & 127)];
}

// ---------------- weight prep: fp32 [K][N] -> transposed bf16 hi/lo [N][K] ----------------
__global__ void prep_w_kernel(const float* __restrict__ Wm1, const float* __restrict__ Wm2,
                              const float* __restrict__ U, const float* __restrict__ V,
                              const float* __restrict__ Wu1, const float* __restrict__ Wu2,
                              short* __restrict__ hi, short* __restrict__ lo) {
  int idx = blockIdx.x * 256 + threadIdx.x;
  if (idx >= 3 * LSZ) return;
  int l = idx / LSZ, r = idx % LSZ;
  const float* src; int K, N, nk;
  if (r < 16384)       { src = Wm1 + (size_t)l*16384; K = 128; N = 128; nk = r; }
  else if (r < 65536)  { src = Wm2 + (size_t)l*49152; K = 128; N = 384; nk = r - 16384; }
  else if (r < 81920)  { src = U   + (size_t)l*16384; K = 128; N = 128; nk = r - 65536; }
  else if (r < 98304)  { src = V   + (size_t)l*16384; K = 128; N = 128; nk = r - 81920; }
  else if (r < 131072) { src = Wu1 + (size_t)l*32768; K = 256; N = 128; nk = r - 98304; }
  else                 { src = Wu2 + (size_t)l*49152; K = 128; N = 384; nk = r - 131072; }
  int n = nk / K, k = nk - n * K;
  float xx = src[(size_t)k * N + n];
  short h = f2bf(xx);
  hi[idx] = h;
  lo[idx] = f2bf(xx - bf2f(h));
}

// ---------------- CSR build (dst-sorted), filtering dist>=CUTOFF edges ----------------
__global__ void hist_kernel(const int* __restrict__ ei, const float* __restrict__ pos,
                            int* __restrict__ counts) {
  int e = blockIdx.x * blockDim.x + threadIdx.x;
  if (e >= NE) return;
  int s = ei[e], d = ei[NE + e];
  float dx = pos[3*d]   - pos[3*s];
  float dy = pos[3*d+1] - pos[3*s+1];
  float dz = pos[3*d+2] - pos[3*s+2];
  float d2 = dx*dx + dy*dy + dz*dz + 1e-12f;
  if (d2 < 25.0f) atomicAdd(&counts[d], 1);
}

__global__ void scan_kernel(const int* __restrict__ counts, int* __restrict__ indptr, int n) {
  __shared__ int sm[1024];
  __shared__ int carry_s;
  if (threadIdx.x == 0) carry_s = 0;
  __syncthreads();
  for (int start = 0; start < n; start += 1024) {
    int i = start + (int)threadIdx.x;
    int val = (i < n) ? counts[i] : 0;
    sm[threadIdx.x] = val;
    __syncthreads();
    for (int off = 1; off < 1024; off <<= 1) {
      int t = (threadIdx.x >= (unsigned)off) ? sm[threadIdx.x - off] : 0;
      __syncthreads();
      sm[threadIdx.x] += t;
      __syncthreads();
    }
    int c = carry_s;
    if (i < n) indptr[i] = c + sm[threadIdx.x] - val;
    __syncthreads();
    if (threadIdx.x == 0) carry_s = c + sm[1023];
    __syncthreads();
  }
  if (threadIdx.x == 0) indptr[n] = carry_s;
}

__global__ void fill_kernel(const int* __restrict__ ei, const float* __restrict__ pos,
                            const int* __restrict__ indptr, int* __restrict__ cursor,
                            int* __restrict__ srcs) {
  int e = blockIdx.x * blockDim.x + threadIdx.x;
  if (e >= NE) return;
  int s = ei[e], d = ei[NE + e];
  float dx = pos[3*d]   - pos[3*s];
  float dy = pos[3*d+1] - pos[3*s+1];
  float dz = pos[3*d+2] - pos[3*s+2];
  float d2 = dx*dx + dy*dy + dz*dz + 1e-12f;
  if (d2 < 25.0f) {
    int p = atomicAdd(&cursor[d], 1);
    srcs[indptr[d] + p] = s;
  }
}

// ---------------- MFMA split-bf16 GEMM: C[M,128] = op(A[M,128] @ B + bias) ----------------
// Bt stored transposed [128 cols][128 k] bf16 hi/lo. grid (ceil(M/32), 4), block 256.
template<bool SILU>
__global__ void __launch_bounds__(256) mfma_gemm_kernel(
    const float* __restrict__ A, const short* __restrict__ Bth,
    const short* __restrict__ Btl, const float* __restrict__ bias,
    float* __restrict__ C, int M) {
  __shared__ float As[32][132];
  int tid = threadIdx.x;
  long r0 = (long)blockIdx.x * 32;
  #pragma unroll
  for (int i = 0; i < 4; i++) {
    int lin = i*256 + tid;
    int r = lin >> 5, c4 = lin & 31;
    long row = r0 + r; if (row >= M) row = M - 1;
    *(float4*)&As[r][c4*4] = *(const float4*)(A + row*128 + c4*4);
  }
  __syncthreads();
  int lane = tid & 63, wv = tid >> 6;
  int l15 = lane & 15, q = lane >> 4;
  int wr = wv & 1, wc = wv >> 1;
  int m = wr*16 + l15;
  int n = blockIdx.y*32 + wc*16 + l15;
  v4f acc = {0.f, 0.f, 0.f, 0.f};
  #pragma unroll
  for (int s = 0; s < 4; s++) {
    const float* ap = &As[m][s*32 + q*8];
    float4 f0 = *(const float4*)(ap);
    float4 f1 = *(const float4*)(ap + 4);
    v8s ah, al;
    { short h,l;
      split2(f0.x,h,l); ah[0]=h; al[0]=l;  split2(f0.y,h,l); ah[1]=h; al[1]=l;
      split2(f0.z,h,l); ah[2]=h; al[2]=l;  split2(f0.w,h,l); ah[3]=h; al[3]=l;
      split2(f1.x,h,l); ah[4]=h; al[4]=l;  split2(f1.y,h,l); ah[5]=h; al[5]=l;
      split2(f1.z,h,l); ah[6]=h; al[6]=l;  split2(f1.w,h,l); ah[7]=h; al[7]=l; }
    v8s bh = *(const v8s*)(Bth + (long)n*128 + s*32 + q*8);
    v8s bl = *(const v8s*)(Btl + (long)n*128 + s*32 + q*8);
    acc = __builtin_amdgcn_mfma_f32_16x16x32_bf16(ah, bh, acc, 0, 0, 0);
    acc = __builtin_amdgcn_mfma_f32_16x16x32_bf16(al, bh, acc, 0, 0, 0);
    acc = __builtin_amdgcn_mfma_f32_16x16x32_bf16(ah, bl, acc, 0, 0, 0);
  }
  float bb = bias[n];
  #pragma unroll
  for (int i = 0; i < 4; i++) {
    long row = r0 + wr*16 + q*4 + i;
    if (row < M) {
      float val = acc[i] + bb;
      if constexpr (SILU) val = silu_f(val);
      C[row*128 + n] = val;
    }
  }
}

// ---------------- message pass, one 128-col slice of phi/filt at a time ----------------
template<int SLICE>
__global__ void __launch_bounds__(128) msg_kernel(
    const float* __restrict__ phiS, const float* __restrict__ vA,
    float* __restrict__ vB, float* __restrict__ x,
    const float* __restrict__ pos,
    const int* __restrict__ srcs, const int* __restrict__ indptr,
    const float* __restrict__ Wf_l, const float* __restrict__ bf_l) {
  int n = blockIdx.x;
  int d = threadIdx.x;
  float wf[NB_];
  #pragma unroll
  for (int k = 0; k < NB_; k++) wf[k] = Wf_l[k*D3 + SLICE*DD + d];
  float bfv = bf_l[SLICE*DD + d];
  float px = pos[3*n], py = pos[3*n+1], pz = pos[3*n+2];
  int beg = indptr[n], end = indptr[n+1];
  float a0 = 0.f, a1 = 0.f, a2 = 0.f, xacc = 0.f;
  for (int t = beg; t < end; t++) {
    int s = srcs[t];
    float dx = px - pos[3*s], dy = py - pos[3*s+1], dz = pz - pos[3*s+2];
    float d2 = dx*dx + dy*dy + dz*dz + 1e-12f;
    float dist = sqrtf(d2);
    float inv  = 1.0f / dist;
    float wang = 0.62831853071795864769f * dist;
    float s1 = __sinf(wang), c1 = __cosf(wang);
    float fc = 0.5f * (c1 + 1.0f);
    float c2 = 2.0f * c1;
    float rkm1 = 0.f, rk = s1, dot = 0.f;
    #pragma unroll
    for (int k = 0; k < NB_; k++) {
      dot = fmaf(rk, wf[k], dot);
      float rn = fmaf(c2, rk, -rkm1);
      rkm1 = rk; rk = rn;
    }
    float f = bfv*fc + fc*inv*dot;
    float m = phiS[(long)s*DD + d] * f;
    if constexpr (SLICE == 0) {
      xacc += m;
    } else if constexpr (SLICE == 1) {
      a0 = fmaf(m, dx*inv, a0);
      a1 = fmaf(m, dy*inv, a1);
      a2 = fmaf(m, dz*inv, a2);
    } else {
      const float* vs = vA + (long)s*D3;
      a0 = fmaf(m, vs[d],      a0);
      a1 = fmaf(m, vs[DD+d],   a1);
      a2 = fmaf(m, vs[2*DD+d], a2);
    }
  }
  if constexpr (SLICE == 0) {
    x[(long)n*DD + d] += xacc;
  } else if constexpr (SLICE == 1) {
    long b = (long)n*D3 + d;
    vB[b]        = vA[b]        + a0;
    vB[b + DD]   = vA[b + DD]   + a1;
    vB[b + 2*DD] = vA[b + 2*DD] + a2;
  } else {
    long b = (long)n*D3 + d;
    vB[b]        += a0;
    vB[b + DD]   += a1;
    vB[b + 2*DD] += a2;
  }
}

// ---------------- MFMA fused Uv/Vv/Vn/s ----------------
// rows = (node,channel) flat (150000), block tile 48 rows x 64 cols; grid (3125, 2).
// Wave w: matrix = w&1 (0:U writes global+LDS, 1:V LDS only), n-pair = w>>1.
__global__ void __launch_bounds__(256) uvn_mfma_kernel(
    const float* __restrict__ v, const short* __restrict__ Uth, const short* __restrict__ Utl,
    const short* __restrict__ Vth, const short* __restrict__ Vtl,
    float* __restrict__ Uv, float* __restrict__ Vn, float* __restrict__ s_out) {
  __shared__ float As[48][132];
  __shared__ float Us[48][68];
  __shared__ float Vs[48][68];
  int tid = threadIdx.x;
  long r0 = (long)blockIdx.x * 48;
  int c0 = blockIdx.y * 64;
  #pragma unroll
  for (int i = 0; i < 6; i++) {
    int lin = i*256 + tid;
    int r = lin >> 5, c4 = lin & 31;
    *(float4*)&As[r][c4*4] = *(const float4*)(v + (r0 + r)*128 + c4*4);
  }
  __syncthreads();
  int lane = tid & 63, wv = tid >> 6;
  int l15 = lane & 15, q = lane >> 4;
  int mat = wv & 1, np = wv >> 1;
  const short* Bh = mat ? Vth : Uth;
  const short* Bl = mat ? Vtl : Utl;
  v4f acc[3][2] = {};
  #pragma unroll
  for (int s = 0; s < 4; s++) {
    v8s ah[3], al[3];
    #pragma unroll
    for (int mt = 0; mt < 3; mt++) {
      const float* ap = &As[mt*16 + l15][s*32 + q*8];
      float4 f0 = *(const float4*)(ap);
      float4 f1 = *(const float4*)(ap + 4);
      short h,l;
      split2(f0.x,h,l); ah[mt][0]=h; al[mt][0]=l;  split2(f0.y,h,l); ah[mt][1]=h; al[mt][1]=l;
      split2(f0.z,h,l); ah[mt][2]=h; al[mt][2]=l;  split2(f0.w,h,l); ah[mt][3]=h; al[mt][3]=l;
      split2(f1.x,h,l); ah[mt][4]=h; al[mt][4]=l;  split2(f1.y,h,l); ah[mt][5]=h; al[mt][5]=l;
      split2(f1.z,h,l); ah[mt][6]=h; al[mt][6]=l;  split2(f1.w,h,l); ah[mt][7]=h; al[mt][7]=l;
    }
    #pragma unroll
    for (int nt = 0; nt < 2; nt++) {
      int n = c0 + (2*np + nt)*16 + l15;
      v8s bh = *(const v8s*)(Bh + (long)n*128 + s*32 + q*8);
      v8s bl = *(const v8s*)(Bl + (long)n*128 + s*32 + q*8);
      #pragma unroll
      for (int mt = 0; mt < 3; mt++) {
        acc[mt][nt] = __builtin_amdgcn_mfma_f32_16x16x32_bf16(ah[mt], bh, acc[mt][nt], 0, 0, 0);
        acc[mt][nt] = __builtin_amdgcn_mfma_f32_16x16x32_bf16(al[mt], bh, acc[mt][nt], 0, 0, 0);
        acc[mt][nt] = __builtin_amdgcn_mfma_f32_16x16x32_bf16(ah[mt], bl, acc[mt][nt], 0, 0, 0);
      }
    }
  }
  #pragma unroll
  for (int mt = 0; mt < 3; mt++)
    #pragma unroll
    for (int nt = 0; nt < 2; nt++) {
      int lc = (2*np + nt)*16 + l15;
      #pragma unroll
      for (int i = 0; i < 4; i++) {
        int lr = mt*16 + q*4 + i;
        float val = acc[mt][nt][i];
        if (mat == 0) {
          Us[lr][lc] = val;
          Uv[(r0 + lr)*128 + c0 + lc] = val;
        } else {
          Vs[lr][lc] = val;
        }
      }
    }
  __syncthreads();
  #pragma unroll
  for (int it = 0; it < 4; it++) {
    int e = it*256 + tid;          // 0..1023 = 16 nodes x 64 cols
    int nn = e >> 6, dl = e & 63;
    float u0 = Us[3*nn][dl], u1 = Us[3*nn+1][dl], u2 = Us[3*nn+2][dl];
    float w0 = Vs[3*nn][dl], w1 = Vs[3*nn+1][dl], w2 = Vs[3*nn+2][dl];
    long node = r0/3 + nn;
    Vn[node*128 + c0 + dl]    = sqrtf(w0*w0 + w1*w1 + w2*w2 + 1e-8f);
    s_out[node*128 + c0 + dl] = u0*w0 + u1*w1 + u2*w2;
  }
}

// ---------------- MFMA fused a-MLP + update ----------------
// Block = 32 nodes; GEMM1 t2=silu([x|Vn]@Wu1+b1) (K=256,N=128) kept in LDS;
// GEMM2 a=t2@Wu2+b2 (K=128,N=384) with avv/asv/ass column-paired per wave;
// epilogue updates x and v in place. grid (ceil(NN/32)), block 256.
__global__ void __launch_bounds__(256) aupd_mfma_kernel(
    float* __restrict__ x, float* __restrict__ v,
    const float* __restrict__ Vn, const float* __restrict__ s_in,
    const float* __restrict__ Uv,
    const short* __restrict__ W1h, const short* __restrict__ W1l, const float* __restrict__ b1,
    const short* __restrict__ W2h, const short* __restrict__ W2l, const float* __restrict__ b2) {
  __shared__ float cat[32][264];
  __shared__ float t2s[32][136];
  int tid = threadIdx.x;
  long r0 = (long)blockIdx.x * 32;
  #pragma unroll
  for (int i = 0; i < 4; i++) {
    int lin = i*256 + tid;
    int r = lin >> 5, c4 = lin & 31;
    long row = r0 + r; if (row >= NN) row = NN - 1;
    *(float4*)&cat[r][c4*4]       = *(const float4*)(x  + row*128 + c4*4);
    *(float4*)&cat[r][128 + c4*4] = *(const float4*)(Vn + row*128 + c4*4);
  }
  __syncthreads();
  int lane = tid & 63, wv = tid >> 6;
  int l15 = lane & 15, q = lane >> 4;
  // GEMM1: wave w covers n-tiles {2w, 2w+1}, both m-tiles
  {
    v4f acc[2][2] = {};
    #pragma unroll
    for (int s = 0; s < 8; s++) {
      v8s ah[2], al[2];
      #pragma unroll
      for (int mt = 0; mt < 2; mt++) {
        const float* ap = &cat[mt*16 + l15][s*32 + q*8];
        float4 f0 = *(const float4*)(ap);
        float4 f1 = *(const float4*)(ap + 4);
        short h,l;
        split2(f0.x,h,l); ah[mt][0]=h; al[mt][0]=l;  split2(f0.y,h,l); ah[mt][1]=h; al[mt][1]=l;
        split2(f0.z,h,l); ah[mt][2]=h; al[mt][2]=l;  split2(f0.w,h,l); ah[mt][3]=h; al[mt][3]=l;
        split2(f1.x,h,l); ah[mt][4]=h; al[mt][4]=l;  split2(f1.y,h,l); ah[mt][5]=h; al[mt][5]=l;
        split2(f1.z,h,l); ah[mt][6]=h; al[mt][6]=l;  split2(f1.w,h,l); ah[mt][7]=h; al[mt][7]=l;
      }
      #pragma unroll
      for (int nt = 0; nt < 2; nt++) {
        int n = (2*wv + nt)*16 + l15;
        v8s bh = *(const v8s*)(W1h + (long)n*256 + s*32 + q*8);
        v8s bl = *(const v8s*)(W1l + (long)n*256 + s*32 + q*8);
        #pragma unroll
        for (int mt = 0; mt < 2; mt++) {
          acc[mt][nt] = __builtin_amdgcn_mfma_f32_16x16x32_bf16(ah[mt], bh, acc[mt][nt], 0, 0, 0);
          acc[mt][nt] = __builtin_amdgcn_mfma_f32_16x16x32_bf16(al[mt], bh, acc[mt][nt], 0, 0, 0);
          acc[mt][nt] = __builtin_amdgcn_mfma_f32_16x16x32_bf16(ah[mt], bl, acc[mt][nt], 0, 0, 0);
        }
      }
    }
    #pragma unroll
    for (int mt = 0; mt < 2; mt++)
      #pragma unroll
      for (int nt = 0; nt < 2; nt++) {
        int n = (2*wv + nt)*16 + l15;
        float bb = b1[n];
        #pragma unroll
        for (int i = 0; i < 4; i++)
          t2s[mt*16 + q*4 + i][n] = silu_f(acc[mt][nt][i] + bb);
      }
  }
  __syncthreads();
  // GEMM2 + update. groups g: 0,1=avv(n-tiles 2w+p), 2,3=asv(+8), 4,5=ass(+16)
  {
    v4f acc[2][6] = {};
    #pragma unroll
    for (int s = 0; s < 4; s++) {
      v8s ah[2], al[2];
      #pragma unroll
      for (int mt = 0; mt < 2; mt++) {
        const float* ap = &t2s[mt*16 + l15][s*32 + q*8];
        float4 f0 = *(const float4*)(ap);
        float4 f1 = *(const float4*)(ap + 4);
        short h,l;
        split2(f0.x,h,l); ah[mt][0]=h; al[mt][0]=l;  split2(f0.y,h,l); ah[mt][1]=h; al[mt][1]=l;
        split2(f0.z,h,l); ah[mt][2]=h; al[mt][2]=l;  split2(f0.w,h,l); ah[mt][3]=h; al[mt][3]=l;
        split2(f1.x,h,l); ah[mt][4]=h; al[mt][4]=l;  split2(f1.y,h,l); ah[mt][5]=h; al[mt][5]=l;
        split2(f1.z,h,l); ah[mt][6]=h; al[mt][6]=l;  split2(f1.w,h,l); ah[mt][7]=h; al[mt][7]=l;
      }
      #pragma unroll
      for (int g = 0; g < 6; g++) {
        int nt = (g >> 1)*8 + 2*wv + (g & 1);
        int n = nt*16 + l15;                 // 0..383
        v8s bh = *(const v8s*)(W2h + (long)n*128 + s*32 + q*8);
        v8s bl = *(const v8s*)(W2l + (long)n*128 + s*32 + q*8);
        #pragma unroll
        for (int mt = 0; mt < 2; mt++) {
          acc[mt][g] = __builtin_amdgcn_mfma_f32_16x16x32_bf16(ah[mt], bh, acc[mt][g], 0, 0, 0);
          acc[mt][g] = __builtin_amdgcn_mfma_f32_16x16x32_bf16(al[mt], bh, acc[mt][g], 0, 0, 0);
          acc[mt][g] = __builtin_amdgcn_mfma_f32_16x16x32_bf16(ah[mt], bl, acc[mt][g], 0, 0, 0);
        }
      }
    }
    #pragma unroll
    for (int mt = 0; mt < 2; mt++)
      #pragma unroll
      for (int p = 0; p < 2; p++) {
        int d = (2*wv + p)*16 + l15;         // 0..127
        float bavv = b2[d], basv = b2[128 + d], bass = b2[256 + d];
        #pragma unroll
        for (int i = 0; i < 4; i++) {
          int lr = mt*16 + q*4 + i;
          long row = r0 + lr;
          if (row < NN) {
            float avv = acc[mt][p][i]     + bavv;
            float asv = acc[mt][2 + p][i] + basv;
            float ass = acc[mt][4 + p][i] + bass;
            float sv = s_in[row*128 + d];
            x[row*128 + d] = cat[lr][d] + ass + asv * sv;
            long vb = row*384 + d;
            v[vb]       = fmaf(avv, Uv[vb],       v[vb]);
            v[vb + 128] = fmaf(avv, Uv[vb + 128], v[vb + 128]);
            v[vb + 256] = fmaf(avv, Uv[vb + 256], v[vb + 256]);
          }
        }
      }
  }
}

// ---------------- output head + segment sum over batch ----------------
__global__ void __launch_bounds__(64) out_kernel(
    const float* __restrict__ x, const float* __restrict__ Wo1,
    const float* __restrict__ bo1, const float* __restrict__ Wo2,
    const float* __restrict__ bo2, const int* __restrict__ batch,
    float* __restrict__ out) {
  int n = blockIdx.x;
  int t = threadIdx.x;
  const float* xr = x + (long)n * DD;
  float acc = bo1[t];
  #pragma unroll 8
  for (int k = 0; k < DD; k++) acc += xr[k] * Wo1[k*HH + t];
  float h = silu_f(acc);
  float val = h * Wo2[t];
  for (int off = 32; off > 0; off >>= 1) val += __shfl_down(val, off);
  if (t == 0) atomicAdd(&out[batch[n]], val + bo2[0]);
}

// ---------------- launcher ----------------
extern "C" void kernel_launch(void* const* d_in, const int* in_sizes, int n_in,
                              void* d_out, int out_size, void* d_ws, size_t ws_size,
                              hipStream_t stream) {
  const int*   at_no = (const int*)d_in[0];
  const float* pos   = (const float*)d_in[1];
  const int*   ei    = (const int*)d_in[2];
  const int*   batch = (const int*)d_in[3];
  const float* emb   = (const float*)d_in[4];
  const float* Wf    = (const float*)d_in[5];
  const float* bfp   = (const float*)d_in[6];
  const float* Wm1   = (const float*)d_in[7];
  const float* bm1   = (const float*)d_in[8];
  const float* Wm2   = (const float*)d_in[9];
  const float* bm2   = (const float*)d_in[10];
  const float* U     = (const float*)d_in[11];
  const float* V     = (const float*)d_in[12];
  const float* Wu1   = (const float*)d_in[13];
  const float* bu1   = (const float*)d_in[14];
  const float* Wu2   = (const float*)d_in[15];
  const float* bu2   = (const float*)d_in[16];
  const float* Wo1   = (const float*)d_in[17];
  const float* bo1   = (const float*)d_in[18];
  const float* Wo2   = (const float*)d_in[19];
  const float* bo2   = (const float*)d_in[20];
  float* out = (float*)d_out;

  char* w = (char*)d_ws;
  auto alloc = [&](size_t bytes) -> void* {
    void* p = (void*)w;
    w += (bytes + 255) & ~(size_t)255;
    return p;
  };
  float* x      = (float*)alloc(sizeof(float)*(size_t)NN*DD);
  float* v_a    = (float*)alloc(sizeof(float)*(size_t)NN*D3);
  float* v_b    = (float*)alloc(sizeof(float)*(size_t)NN*D3);
  float* t1     = (float*)alloc(sizeof(float)*(size_t)NN*DD);   // reused: Vn
  float* phiS   = (float*)alloc(sizeof(float)*(size_t)NN*DD);   // reused: s
  short* wbh    = (short*)alloc(sizeof(short)*(size_t)3*LSZ);   // bf16-hi transposed weights
  short* wbl    = (short*)alloc(sizeof(short)*(size_t)3*LSZ);   // bf16-lo
  int*   srcs   = (int*)alloc(sizeof(int)*(size_t)NE);
  int*   indptr = (int*)alloc(sizeof(int)*((size_t)NN+1));
  int*   counts = (int*)alloc(sizeof(int)*(size_t)NN);

  if ((size_t)(w - (char*)d_ws) > ws_size) {   // diagnostic guard: zeros => ws too small
    zero_f_kernel<<<2, 256, 0, stream>>>(out, NG_);
    return;
  }

  zero_f_kernel<<<2048, 256, 0, stream>>>(v_a, (long)NN*D3);
  zero_f_kernel<<<2, 256, 0, stream>>>(out, NG_);
  zero_i_kernel<<<64, 256, 0, stream>>>(counts, NN);
  init_x_kernel<<<(NN*DD + 255)/256, 256, 0, stream>>>(at_no, emb, x);
  prep_w_kernel<<<(3*LSZ + 255)/256, 256, 0, stream>>>(Wm1, Wm2, U, V, Wu1, Wu2, wbh, wbl);
  hist_kernel<<<(NE + 255)/256, 256, 0, stream>>>(ei, pos, counts);
  scan_kernel<<<1, 1024, 0, stream>>>(counts, indptr, NN);
  zero_i_kernel<<<64, 256, 0, stream>>>(counts, NN);
  fill_kernel<<<(NE + 255)/256, 256, 0, stream>>>(ei, pos, indptr, counts, srcs);

  const int MB = (NN + 31) / 32;    // 1563
  float* vcur = v_a;
  float* vnext = v_b;
  for (int l = 0; l < 3; l++) {
    const float* Wf_l  = Wf  + (size_t)l*NB_*D3;
    const float* bf_l  = bfp + (size_t)l*D3;
    const float* bm1_l = bm1 + (size_t)l*DD;
    const float* bm2_l = bm2 + (size_t)l*D3;
    const float* bu1_l = bu1 + (size_t)l*DD;
    const float* bu2_l = bu2 + (size_t)l*D3;
    const short* Lh = wbh + (size_t)l*LSZ;
    const short* Ll = wbl + (size_t)l*LSZ;
    const short* Wm1h = Lh,          *Wm1L = Ll;
    const short* Wm2h = Lh + 16384,  *Wm2L = Ll + 16384;
    const short* Uh   = Lh + 65536,  *UL   = Ll + 65536;
    const short* Vh   = Lh + 81920,  *VL   = Ll + 81920;
    const short* Wu1h = Lh + 98304,  *Wu1L = Ll + 98304;
    const short* Wu2h = Lh + 131072, *Wu2L = Ll + 131072;

    // t1 = silu(x@Wm1 + bm1)
    mfma_gemm_kernel<true><<<dim3(MB, 4), 256, 0, stream>>>(x, Wm1h, Wm1L, bm1_l, t1, NN);
    // phi slices + message pass
    mfma_gemm_kernel<false><<<dim3(MB, 4), 256, 0, stream>>>(t1, Wm2h + 0*16384, Wm2L + 0*16384, bm2_l + 0*DD, phiS, NN);
    msg_kernel<0><<<NN, 128, 0, stream>>>(phiS, vcur, vnext, x, pos, srcs, indptr, Wf_l, bf_l);
    mfma_gemm_kernel<false><<<dim3(MB, 4), 256, 0, stream>>>(t1, Wm2h + 1*16384, Wm2L + 1*16384, bm2_l + 1*DD, phiS, NN);
    msg_kernel<1><<<NN, 128, 0, stream>>>(phiS, vcur, vnext, x, pos, srcs, indptr, Wf_l, bf_l);
    mfma_gemm_kernel<false><<<dim3(MB, 4), 256, 0, stream>>>(t1, Wm2h + 2*16384, Wm2L + 2*16384, bm2_l + 2*DD, phiS, NN);
    msg_kernel<2><<<NN, 128, 0, stream>>>(phiS, vcur, vnext, x, pos, srcs, indptr, Wf_l, bf_l);
    // fused Uv/Vv/Vn/s: Uv -> dead vcur, Vn -> dead t1, s -> dead phiS
    uvn_mfma_kernel<<<dim3(3*NN/48, 2), 256, 0, stream>>>(vnext, Uh, UL, Vh, VL, vcur, t1, phiS);
    // fused a-MLP + update
    aupd_mfma_kernel<<<MB, 256, 0, stream>>>(x, vnext, t1, phiS, vcur,
                                             Wu1h, Wu1L, bu1_l, Wu2h, Wu2L, bu2_l);

    float* tmp = vcur; vcur = vnext; vnext = tmp;
  }

  out_kernel<<<NN, 64, 0, stream>>>(x, Wo1, bo1, Wo2, bo2, batch, out);

  (void)in_sizes; (void)n_in; (void)out_size; (void)ws_size;
}

// Round 5
// 1748.715 us; speedup vs baseline: 1.4291x; 1.1435x over previous
//
#include <hip/hip_runtime.h>
#include <math.h>

#define NN 50000
#define NE 600000
#define DD 128
#define D3 384
#define NB_ 20
#define HH 64
#define NG_ 512
#define LSZ 180224   // shorts per layer of transposed-bf16 weights

typedef short v8s __attribute__((ext_vector_type(8)));
typedef float v4f __attribute__((ext_vector_type(4)));

__device__ __forceinline__ float silu_f(float z) { return z / (1.0f + expf(-z)); }

__device__ __forceinline__ short f2bf(float f) {
  unsigned u = __float_as_uint(f);
  u += 0x7FFF + ((u >> 16) & 1);          // RNE
  return (short)(u >> 16);
}
__device__ __forceinline__ float bf2f(short s) {
  return __uint_as_float(((unsigned)(unsigned short)s) << 16);
}
__device__ __forceinline__ void split2(float x, short& h, short& l) {
  h = f2bf(x);
  l = f2bf(x - bf2f(h));
}

// ---------------- utility ----------------
__global__ void zero_f_kernel(float* __restrict__ p, long n) {
  long i = (long)blockIdx.x * blockDim.x + threadIdx.x;
  long s = (long)gridDim.x * blockDim.x;
  for (; i < n; i += s) p[i] = 0.0f;
}

__global__ void zero_i_kernel(int* __restrict__ p, long n) {
  long i = (long)blockIdx.x * blockDim.x + threadIdx.x;
  long s = (long)gridDim.x * blockDim.x;
  for (; i < n; i += s) p[i] = 0;
}

__global__ void init_x_kernel(const int* __restrict__ at_no, const float* __restrict__ emb,
                              float* __restrict__ x) {
  int i = blockIdx.x * blockDim.x + threadIdx.x;
  if (i >= NN * DD) return;
  x[i] = emb[at_no[i >> 7] * DD + (i & 127)];
}

// ---------------- weight prep: fp32 [K][N] -> transposed bf16 hi/lo [N][K] ----------------
__global__ void prep_w_kernel(const float* __restrict__ Wm1, const float* __restrict__ Wm2,
                              const float* __restrict__ U, const float* __restrict__ V,
                              const float* __restrict__ Wu1, const float* __restrict__ Wu2,
                              short* __restrict__ hi, short* __restrict__ lo) {
  int idx = blockIdx.x * 256 + threadIdx.x;
  if (idx >= 3 * LSZ) return;
  int l = idx / LSZ, r = idx % LSZ;
  const float* src; int K, N, nk;
  if (r < 16384)       { src = Wm1 + (size_t)l*16384; K = 128; N = 128; nk = r; }
  else if (r < 65536)  { src = Wm2 + (size_t)l*49152; K = 128; N = 384; nk = r - 16384; }
  else if (r < 81920)  { src = U   + (size_t)l*16384; K = 128; N = 128; nk = r - 65536; }
  else if (r < 98304)  { src = V   + (size_t)l*16384; K = 128; N = 128; nk = r - 81920; }
  else if (r < 131072) { src = Wu1 + (size_t)l*32768; K = 256; N = 128; nk = r - 98304; }
  else                 { src = Wu2 + (size_t)l*49152; K = 128; N = 384; nk = r - 131072; }
  int n = nk / K, k = nk - n * K;
  float xx = src[(size_t)k * N + n];
  short h = f2bf(xx);
  hi[idx] = h;
  lo[idx] = f2bf(xx - bf2f(h));
}

// ---------------- CSR build (dst-sorted), filtering dist>=CUTOFF edges ----------------
__global__ void hist_kernel(const int* __restrict__ ei, const float* __restrict__ pos,
                            int* __restrict__ counts) {
  int e = blockIdx.x * blockDim.x + threadIdx.x;
  if (e >= NE) return;
  int s = ei[e], d = ei[NE + e];
  float dx = pos[3*d]   - pos[3*s];
  float dy = pos[3*d+1] - pos[3*s+1];
  float dz = pos[3*d+2] - pos[3*s+2];
  float d2 = dx*dx + dy*dy + dz*dz + 1e-12f;
  if (d2 < 25.0f) atomicAdd(&counts[d], 1);
}

__global__ void scan_kernel(const int* __restrict__ counts, int* __restrict__ indptr, int n) {
  __shared__ int sm[1024];
  __shared__ int carry_s;
  if (threadIdx.x == 0) carry_s = 0;
  __syncthreads();
  for (int start = 0; start < n; start += 1024) {
    int i = start + (int)threadIdx.x;
    int val = (i < n) ? counts[i] : 0;
    sm[threadIdx.x] = val;
    __syncthreads();
    for (int off = 1; off < 1024; off <<= 1) {
      int t = (threadIdx.x >= (unsigned)off) ? sm[threadIdx.x - off] : 0;
      __syncthreads();
      sm[threadIdx.x] += t;
      __syncthreads();
    }
    int c = carry_s;
    if (i < n) indptr[i] = c + sm[threadIdx.x] - val;
    __syncthreads();
    if (threadIdx.x == 0) carry_s = c + sm[1023];
    __syncthreads();
  }
  if (threadIdx.x == 0) indptr[n] = carry_s;
}

// writes src id + per-slot edge geometry (streamed later by msg)
__global__ void fill_kernel(const int* __restrict__ ei, const float* __restrict__ pos,
                            const int* __restrict__ indptr, int* __restrict__ cursor,
                            int* __restrict__ srcs, float4* __restrict__ eg1,
                            float4* __restrict__ eg2) {
  int e = blockIdx.x * blockDim.x + threadIdx.x;
  if (e >= NE) return;
  int s = ei[e], d = ei[NE + e];
  float dx = pos[3*d]   - pos[3*s];
  float dy = pos[3*d+1] - pos[3*s+1];
  float dz = pos[3*d+2] - pos[3*s+2];
  float d2 = dx*dx + dy*dy + dz*dz + 1e-12f;
  if (d2 < 25.0f) {
    int p = atomicAdd(&cursor[d], 1);
    int slot = indptr[d] + p;
    float dist = sqrtf(d2);
    float inv = 1.0f / dist;
    float wang = 0.62831853071795864769f * dist;   // pi*dist/CUTOFF
    float s1 = __sinf(wang), c1 = __cosf(wang);
    float fc = 0.5f * (c1 + 1.0f);
    srcs[slot] = s;
    eg1[slot] = make_float4(s1, c1, fc, fc * inv);
    eg2[slot] = make_float4(dx * inv, dy * inv, dz * inv, 0.0f);
  }
}

// ---------------- MFMA split-bf16 GEMM: C[M,128] = op(A[M,128] @ B + bias) ----------------
// One block = 32 rows x all 128 cols. 4 waves x (2 m-tiles x 2 n-tiles).
template<bool SILU>
__global__ void __launch_bounds__(256) mfma_gemm_kernel(
    const float* __restrict__ A, const short* __restrict__ Bth,
    const short* __restrict__ Btl, const float* __restrict__ bias,
    float* __restrict__ C, int M) {
  __shared__ float As[32][132];
  int tid = threadIdx.x;
  long r0 = (long)blockIdx.x * 32;
  #pragma unroll
  for (int i = 0; i < 4; i++) {
    int lin = i*256 + tid;
    int r = lin >> 5, c4 = lin & 31;
    long row = r0 + r; if (row >= M) row = M - 1;
    *(float4*)&As[r][c4*4] = *(const float4*)(A + row*128 + c4*4);
  }
  __syncthreads();
  int lane = tid & 63, wv = tid >> 6;
  int l15 = lane & 15, q = lane >> 4;
  v4f acc[2][2] = {};
  #pragma unroll
  for (int s = 0; s < 4; s++) {
    v8s ah[2], al[2];
    #pragma unroll
    for (int mt = 0; mt < 2; mt++) {
      const float* ap = &As[mt*16 + l15][s*32 + q*8];
      float4 f0 = *(const float4*)(ap);
      float4 f1 = *(const float4*)(ap + 4);
      short h,l;
      split2(f0.x,h,l); ah[mt][0]=h; al[mt][0]=l;  split2(f0.y,h,l); ah[mt][1]=h; al[mt][1]=l;
      split2(f0.z,h,l); ah[mt][2]=h; al[mt][2]=l;  split2(f0.w,h,l); ah[mt][3]=h; al[mt][3]=l;
      split2(f1.x,h,l); ah[mt][4]=h; al[mt][4]=l;  split2(f1.y,h,l); ah[mt][5]=h; al[mt][5]=l;
      split2(f1.z,h,l); ah[mt][6]=h; al[mt][6]=l;  split2(f1.w,h,l); ah[mt][7]=h; al[mt][7]=l;
    }
    #pragma unroll
    for (int nt = 0; nt < 2; nt++) {
      int n = (2*wv + nt)*16 + l15;
      v8s bh = *(const v8s*)(Bth + (long)n*128 + s*32 + q*8);
      v8s bl = *(const v8s*)(Btl + (long)n*128 + s*32 + q*8);
      #pragma unroll
      for (int mt = 0; mt < 2; mt++) {
        acc[mt][nt] = __builtin_amdgcn_mfma_f32_16x16x32_bf16(ah[mt], bh, acc[mt][nt], 0, 0, 0);
        acc[mt][nt] = __builtin_amdgcn_mfma_f32_16x16x32_bf16(al[mt], bh, acc[mt][nt], 0, 0, 0);
        acc[mt][nt] = __builtin_amdgcn_mfma_f32_16x16x32_bf16(ah[mt], bl, acc[mt][nt], 0, 0, 0);
      }
    }
  }
  #pragma unroll
  for (int nt = 0; nt < 2; nt++) {
    int n = (2*wv + nt)*16 + l15;
    float bb = bias[n];
    #pragma unroll
    for (int mt = 0; mt < 2; mt++)
      #pragma unroll
      for (int i = 0; i < 4; i++) {
        long row = r0 + mt*16 + q*4 + i;
        if (row < M) {
          float val = acc[mt][nt][i] + bb;
          if constexpr (SILU) val = silu_f(val);
          C[row*128 + n] = val;
        }
      }
  }
}

// ---------------- message pass, one 128-col slice of phi/filt at a time ----------------
template<int SLICE>
__global__ void __launch_bounds__(128) msg_kernel(
    const float* __restrict__ phiS, const float* __restrict__ vA,
    float* __restrict__ vB, float* __restrict__ x,
    const int* __restrict__ srcs, const float4* __restrict__ eg1,
    const float4* __restrict__ eg2, const int* __restrict__ indptr,
    const float* __restrict__ Wf_l, const float* __restrict__ bf_l) {
  int n = blockIdx.x;
  int d = threadIdx.x;
  float wf[NB_];
  #pragma unroll
  for (int k = 0; k < NB_; k++) wf[k] = Wf_l[k*D3 + SLICE*DD + d];
  float bfv = bf_l[SLICE*DD + d];
  int beg = indptr[n], end = indptr[n+1];
  float a0 = 0.f, a1 = 0.f, a2 = 0.f, xacc = 0.f;
  for (int t = beg; t < end; t++) {
    int s = srcs[t];
    float4 g = eg1[t];             // sin(w), cos(w), fc, fc/dist
    float c2 = 2.0f * g.y;
    float rkm1 = 0.f, rk = g.x, dot = 0.f;
    #pragma unroll
    for (int k = 0; k < NB_; k++) {
      dot = fmaf(rk, wf[k], dot);
      float rn = fmaf(c2, rk, -rkm1);
      rkm1 = rk; rk = rn;
    }
    float f = bfv*g.z + g.w*dot;
    float m = phiS[(long)s*DD + d] * f;
    if constexpr (SLICE == 0) {
      xacc += m;
    } else if constexpr (SLICE == 1) {
      float4 dv = eg2[t];
      a0 = fmaf(m, dv.x, a0);
      a1 = fmaf(m, dv.y, a1);
      a2 = fmaf(m, dv.z, a2);
    } else {
      const float* vs = vA + (long)s*D3;
      a0 = fmaf(m, vs[d],      a0);
      a1 = fmaf(m, vs[DD+d],   a1);
      a2 = fmaf(m, vs[2*DD+d], a2);
    }
  }
  if constexpr (SLICE == 0) {
    x[(long)n*DD + d] += xacc;
  } else if constexpr (SLICE == 1) {
    long b = (long)n*D3 + d;
    vB[b]        = vA[b]        + a0;
    vB[b + DD]   = vA[b + DD]   + a1;
    vB[b + 2*DD] = vA[b + 2*DD] + a2;
  } else {
    long b = (long)n*D3 + d;
    vB[b]        += a0;
    vB[b + DD]   += a1;
    vB[b + 2*DD] += a2;
  }
}

// ---------------- MFMA fused Uv/Vv/Vn/s ----------------
// 48 rows (16 nodes) x full 128 cols per block. Each wave computes BOTH the
// U- and V-projections for its 2 n-tiles, so u,w coexist per lane; epilogue
// stores u*w and w*w per row (LDS unioned with the A tile), then reduces
// over the 3 channel-rows of each node.
__global__ void __launch_bounds__(256) uvn_mfma_kernel(
    const float* __restrict__ v, const short* __restrict__ Uth, const short* __restrict__ Utl,
    const short* __restrict__ Vth, const short* __restrict__ Vtl,
    float* __restrict__ Uv, float* __restrict__ Vn, float* __restrict__ s_out) {
  __shared__ float smem[2 * 48 * 132];
  float (*As)[132] = (float(*)[132])smem;            // phase 1
  float (*P)[132]  = (float(*)[132])smem;            // phase 2 (u*w)
  float (*Q)[132]  = (float(*)[132])(smem + 48*132); // phase 2 (w*w)
  int tid = threadIdx.x;
  long r0 = (long)blockIdx.x * 48;
  #pragma unroll
  for (int i = 0; i < 6; i++) {
    int lin = i*256 + tid;
    int r = lin >> 5, c4 = lin & 31;
    *(float4*)&As[r][c4*4] = *(const float4*)(v + (r0 + r)*128 + c4*4);
  }
  __syncthreads();
  int lane = tid & 63, wv = tid >> 6;
  int l15 = lane & 15, q = lane >> 4;
  v4f aU[3][2] = {}, aV[3][2] = {};
  #pragma unroll
  for (int s = 0; s < 4; s++) {
    v8s ah[3], al[3];
    #pragma unroll
    for (int mt = 0; mt < 3; mt++) {
      const float* ap = &As[mt*16 + l15][s*32 + q*8];
      float4 f0 = *(const float4*)(ap);
      float4 f1 = *(const float4*)(ap + 4);
      short h,l;
      split2(f0.x,h,l); ah[mt][0]=h; al[mt][0]=l;  split2(f0.y,h,l); ah[mt][1]=h; al[mt][1]=l;
      split2(f0.z,h,l); ah[mt][2]=h; al[mt][2]=l;  split2(f0.w,h,l); ah[mt][3]=h; al[mt][3]=l;
      split2(f1.x,h,l); ah[mt][4]=h; al[mt][4]=l;  split2(f1.y,h,l); ah[mt][5]=h; al[mt][5]=l;
      split2(f1.z,h,l); ah[mt][6]=h; al[mt][6]=l;  split2(f1.w,h,l); ah[mt][7]=h; al[mt][7]=l;
    }
    #pragma unroll
    for (int nt = 0; nt < 2; nt++) {
      int n = (2*wv + nt)*16 + l15;
      long boff = (long)n*128 + s*32 + q*8;
      v8s buh = *(const v8s*)(Uth + boff);
      v8s bul = *(const v8s*)(Utl + boff);
      v8s bvh = *(const v8s*)(Vth + boff);
      v8s bvl = *(const v8s*)(Vtl + boff);
      #pragma unroll
      for (int mt = 0; mt < 3; mt++) {
        aU[mt][nt] = __builtin_amdgcn_mfma_f32_16x16x32_bf16(ah[mt], buh, aU[mt][nt], 0, 0, 0);
        aU[mt][nt] = __builtin_amdgcn_mfma_f32_16x16x32_bf16(al[mt], buh, aU[mt][nt], 0, 0, 0);
        aU[mt][nt] = __builtin_amdgcn_mfma_f32_16x16x32_bf16(ah[mt], bul, aU[mt][nt], 0, 0, 0);
        aV[mt][nt] = __builtin_amdgcn_mfma_f32_16x16x32_bf16(ah[mt], bvh, aV[mt][nt], 0, 0, 0);
        aV[mt][nt] = __builtin_amdgcn_mfma_f32_16x16x32_bf16(al[mt], bvh, aV[mt][nt], 0, 0, 0);
        aV[mt][nt] = __builtin_amdgcn_mfma_f32_16x16x32_bf16(ah[mt], bvl, aV[mt][nt], 0, 0, 0);
      }
    }
  }
  __syncthreads();   // done reading As; safe to overwrite with P
  #pragma unroll
  for (int mt = 0; mt < 3; mt++)
    #pragma unroll
    for (int nt = 0; nt < 2; nt++) {
      int lc = (2*wv + nt)*16 + l15;
      #pragma unroll
      for (int i = 0; i < 4; i++) {
        int lr = mt*16 + q*4 + i;
        float u = aU[mt][nt][i], w = aV[mt][nt][i];
        Uv[(r0 + lr)*128 + lc] = u;
        P[lr][lc] = u * w;
        Q[lr][lc] = w * w;
      }
    }
  __syncthreads();
  #pragma unroll
  for (int it = 0; it < 8; it++) {
    int e = it*256 + tid;           // 0..2047 = 16 nodes x 128 cols
    int nn = e >> 7, dl = e & 127;
    float p  = P[3*nn][dl] + P[3*nn+1][dl] + P[3*nn+2][dl];
    float qq = Q[3*nn][dl] + Q[3*nn+1][dl] + Q[3*nn+2][dl];
    long node = r0/3 + nn;
    Vn[node*128 + dl]    = sqrtf(qq + 1e-8f);
    s_out[node*128 + dl] = p;
  }
}

// ---------------- MFMA fused a-MLP + update: 16 nodes/block ----------------
__global__ void __launch_bounds__(256) aupd_mfma_kernel(
    float* __restrict__ x, float* __restrict__ v,
    const float* __restrict__ Vn, const float* __restrict__ s_in,
    const float* __restrict__ Uv,
    const short* __restrict__ W1h, const short* __restrict__ W1l, const float* __restrict__ b1,
    const short* __restrict__ W2h, const short* __restrict__ W2l, const float* __restrict__ b2) {
  __shared__ float cat[16][268];
  __shared__ float t2s[16][140];
  int tid = threadIdx.x;
  long r0 = (long)blockIdx.x * 16;
  #pragma unroll
  for (int i = 0; i < 2; i++) {
    int lin = i*256 + tid;
    int r = lin >> 5, c4 = lin & 31;
    long row = r0 + r;
    *(float4*)&cat[r][c4*4]       = *(const float4*)(x  + row*128 + c4*4);
    *(float4*)&cat[r][128 + c4*4] = *(const float4*)(Vn + row*128 + c4*4);
  }
  __syncthreads();
  int lane = tid & 63, wv = tid >> 6;
  int l15 = lane & 15, q = lane >> 4;
  // GEMM1: t2 = silu([x|Vn] @ Wu1 + b1), K=256, N=128
  {
    v4f acc[2] = {};
    #pragma unroll
    for (int s = 0; s < 8; s++) {
      const float* ap = &cat[l15][s*32 + q*8];
      float4 f0 = *(const float4*)(ap);
      float4 f1 = *(const float4*)(ap + 4);
      v8s ah, al;
      { short h,l;
        split2(f0.x,h,l); ah[0]=h; al[0]=l;  split2(f0.y,h,l); ah[1]=h; al[1]=l;
        split2(f0.z,h,l); ah[2]=h; al[2]=l;  split2(f0.w,h,l); ah[3]=h; al[3]=l;
        split2(f1.x,h,l); ah[4]=h; al[4]=l;  split2(f1.y,h,l); ah[5]=h; al[5]=l;
        split2(f1.z,h,l); ah[6]=h; al[6]=l;  split2(f1.w,h,l); ah[7]=h; al[7]=l; }
      #pragma unroll
      for (int nt = 0; nt < 2; nt++) {
        int n = (2*wv + nt)*16 + l15;
        v8s bh = *(const v8s*)(W1h + (long)n*256 + s*32 + q*8);
        v8s bl = *(const v8s*)(W1l + (long)n*256 + s*32 + q*8);
        acc[nt] = __builtin_amdgcn_mfma_f32_16x16x32_bf16(ah, bh, acc[nt], 0, 0, 0);
        acc[nt] = __builtin_amdgcn_mfma_f32_16x16x32_bf16(al, bh, acc[nt], 0, 0, 0);
        acc[nt] = __builtin_amdgcn_mfma_f32_16x16x32_bf16(ah, bl, acc[nt], 0, 0, 0);
      }
    }
    #pragma unroll
    for (int nt = 0; nt < 2; nt++) {
      int n = (2*wv + nt)*16 + l15;
      float bb = b1[n];
      #pragma unroll
      for (int i = 0; i < 4; i++)
        t2s[q*4 + i][n] = silu_f(acc[nt][i] + bb);
    }
  }
  __syncthreads();
  // GEMM2 + update. groups g: 0,1=avv, 2,3=asv, 4,5=ass
  {
    v4f acc[6] = {};
    #pragma unroll
    for (int s = 0; s < 4; s++) {
      const float* ap = &t2s[l15][s*32 + q*8];
      float4 f0 = *(const float4*)(ap);
      float4 f1 = *(const float4*)(ap + 4);
      v8s ah, al;
      { short h,l;
        split2(f0.x,h,l); ah[0]=h; al[0]=l;  split2(f0.y,h,l); ah[1]=h; al[1]=l;
        split2(f0.z,h,l); ah[2]=h; al[2]=l;  split2(f0.w,h,l); ah[3]=h; al[3]=l;
        split2(f1.x,h,l); ah[4]=h; al[4]=l;  split2(f1.y,h,l); ah[5]=h; al[5]=l;
        split2(f1.z,h,l); ah[6]=h; al[6]=l;  split2(f1.w,h,l); ah[7]=h; al[7]=l; }
      #pragma unroll
      for (int g = 0; g < 6; g++) {
        int nt = (g >> 1)*8 + 2*wv + (g & 1);
        int n = nt*16 + l15;                 // 0..383
        v8s bh = *(const v8s*)(W2h + (long)n*128 + s*32 + q*8);
        v8s bl = *(const v8s*)(W2l + (long)n*128 + s*32 + q*8);
        acc[g] = __builtin_amdgcn_mfma_f32_16x16x32_bf16(ah, bh, acc[g], 0, 0, 0);
        acc[g] = __builtin_amdgcn_mfma_f32_16x16x32_bf16(al, bh, acc[g], 0, 0, 0);
        acc[g] = __builtin_amdgcn_mfma_f32_16x16x32_bf16(ah, bl, acc[g], 0, 0, 0);
      }
    }
    #pragma unroll
    for (int p = 0; p < 2; p++) {
      int d = (2*wv + p)*16 + l15;           // 0..127
      float bavv = b2[d], basv = b2[128 + d], bass = b2[256 + d];
      #pragma unroll
      for (int i = 0; i < 4; i++) {
        int lr = q*4 + i;
        long row = r0 + lr;
        float avv = acc[p][i]     + bavv;
        float asv = acc[2 + p][i] + basv;
        float ass = acc[4 + p][i] + bass;
        float sv = s_in[row*128 + d];
        x[row*128 + d] = cat[lr][d] + ass + asv * sv;
        long vb = row*384 + d;
        v[vb]       = fmaf(avv, Uv[vb],       v[vb]);
        v[vb + 128] = fmaf(avv, Uv[vb + 128], v[vb + 128]);
        v[vb + 256] = fmaf(avv, Uv[vb + 256], v[vb + 256]);
      }
    }
  }
}

// ---------------- output head + segment sum: 4 nodes/block, LDS-staged x ----------------
__global__ void __launch_bounds__(256) out_kernel(
    const float* __restrict__ x, const float* __restrict__ Wo1,
    const float* __restrict__ bo1, const float* __restrict__ Wo2,
    const float* __restrict__ bo2, const int* __restrict__ batch,
    float* __restrict__ out) {
  __shared__ float xs[4][132];
  int tid = threadIdx.x;
  long n0 = (long)blockIdx.x * 4;
  if (tid < 128) {
    int r = tid >> 5, c4 = tid & 31;
    *(float4*)&xs[r][c4*4] = *(const float4*)(x + (n0 + r)*128 + c4*4);
  }
  __syncthreads();
  int wv = tid >> 6, t = tid & 63;
  float acc = bo1[t];
  #pragma unroll 16
  for (int k = 0; k < DD; k++) acc = fmaf(xs[wv][k], Wo1[k*HH + t], acc);
  float val = silu_f(acc) * Wo2[t];
  #pragma unroll
  for (int off = 32; off > 0; off >>= 1) val += __shfl_down(val, off);
  if (t == 0) atomicAdd(&out[batch[n0 + wv]], val + bo2[0]);
}

// ---------------- launcher ----------------
extern "C" void kernel_launch(void* const* d_in, const int* in_sizes, int n_in,
                              void* d_out, int out_size, void* d_ws, size_t ws_size,
                              hipStream_t stream) {
  const int*   at_no = (const int*)d_in[0];
  const float* pos   = (const float*)d_in[1];
  const int*   ei    = (const int*)d_in[2];
  const int*   batch = (const int*)d_in[3];
  const float* emb   = (const float*)d_in[4];
  const float* Wf    = (const float*)d_in[5];
  const float* bfp   = (const float*)d_in[6];
  const float* Wm1   = (const float*)d_in[7];
  const float* bm1   = (const float*)d_in[8];
  const float* Wm2   = (const float*)d_in[9];
  const float* bm2   = (const float*)d_in[10];
  const float* U     = (const float*)d_in[11];
  const float* V     = (const float*)d_in[12];
  const float* Wu1   = (const float*)d_in[13];
  const float* bu1   = (const float*)d_in[14];
  const float* Wu2   = (const float*)d_in[15];
  const float* bu2   = (const float*)d_in[16];
  const float* Wo1   = (const float*)d_in[17];
  const float* bo1   = (const float*)d_in[18];
  const float* Wo2   = (const float*)d_in[19];
  const float* bo2   = (const float*)d_in[20];
  float* out = (float*)d_out;

  char* w = (char*)d_ws;
  auto alloc = [&](size_t bytes) -> void* {
    void* p = (void*)w;
    w += (bytes + 255) & ~(size_t)255;
    return p;
  };
  float*  x      = (float*)alloc(sizeof(float)*(size_t)NN*DD);
  float*  v_a    = (float*)alloc(sizeof(float)*(size_t)NN*D3);
  float*  v_b    = (float*)alloc(sizeof(float)*(size_t)NN*D3);
  float*  t1     = (float*)alloc(sizeof(float)*(size_t)NN*DD);   // reused: Vn
  float*  phiS   = (float*)alloc(sizeof(float)*(size_t)NN*DD);   // reused: s
  short*  wbh    = (short*)alloc(sizeof(short)*(size_t)3*LSZ);
  short*  wbl    = (short*)alloc(sizeof(short)*(size_t)3*LSZ);
  int*    srcs   = (int*)alloc(sizeof(int)*(size_t)NE);
  float4* eg1    = (float4*)alloc(sizeof(float4)*(size_t)NE);
  float4* eg2    = (float4*)alloc(sizeof(float4)*(size_t)NE);
  int*    indptr = (int*)alloc(sizeof(int)*((size_t)NN+1));
  int*    counts = (int*)alloc(sizeof(int)*(size_t)NN);

  if ((size_t)(w - (char*)d_ws) > ws_size) {   // diagnostic guard: zeros => ws too small
    zero_f_kernel<<<2, 256, 0, stream>>>(out, NG_);
    return;
  }

  zero_f_kernel<<<2048, 256, 0, stream>>>(v_a, (long)NN*D3);
  zero_f_kernel<<<2, 256, 0, stream>>>(out, NG_);
  zero_i_kernel<<<64, 256, 0, stream>>>(counts, NN);
  init_x_kernel<<<(NN*DD + 255)/256, 256, 0, stream>>>(at_no, emb, x);
  prep_w_kernel<<<(3*LSZ + 255)/256, 256, 0, stream>>>(Wm1, Wm2, U, V, Wu1, Wu2, wbh, wbl);
  hist_kernel<<<(NE + 255)/256, 256, 0, stream>>>(ei, pos, counts);
  scan_kernel<<<1, 1024, 0, stream>>>(counts, indptr, NN);
  zero_i_kernel<<<64, 256, 0, stream>>>(counts, NN);
  fill_kernel<<<(NE + 255)/256, 256, 0, stream>>>(ei, pos, indptr, counts, srcs, eg1, eg2);

  const int MB = (NN + 31) / 32;    // 1563
  float* vcur = v_a;
  float* vnext = v_b;
  for (int l = 0; l < 3; l++) {
    const float* Wf_l  = Wf  + (size_t)l*NB_*D3;
    const float* bf_l  = bfp + (size_t)l*D3;
    const float* bm1_l = bm1 + (size_t)l*DD;
    const float* bm2_l = bm2 + (size_t)l*D3;
    const float* bu1_l = bu1 + (size_t)l*DD;
    const float* bu2_l = bu2 + (size_t)l*D3;
    const short* Lh = wbh + (size_t)l*LSZ;
    const short* Ll = wbl + (size_t)l*LSZ;
    const short* Wm1h = Lh,          *Wm1L = Ll;
    const short* Wm2h = Lh + 16384,  *Wm2L = Ll + 16384;
    const short* Uh   = Lh + 65536,  *UL   = Ll + 65536;
    const short* Vh   = Lh + 81920,  *VL   = Ll + 81920;
    const short* Wu1h = Lh + 98304,  *Wu1L = Ll + 98304;
    const short* Wu2h = Lh + 131072, *Wu2L = Ll + 131072;

    // t1 = silu(x@Wm1 + bm1)
    mfma_gemm_kernel<true><<<MB, 256, 0, stream>>>(x, Wm1h, Wm1L, bm1_l, t1, NN);
    // phi slices + message pass
    mfma_gemm_kernel<false><<<MB, 256, 0, stream>>>(t1, Wm2h + 0*16384, Wm2L + 0*16384, bm2_l + 0*DD, phiS, NN);
    msg_kernel<0><<<NN, 128, 0, stream>>>(phiS, vcur, vnext, x, srcs, eg1, eg2, indptr, Wf_l, bf_l);
    mfma_gemm_kernel<false><<<MB, 256, 0, stream>>>(t1, Wm2h + 1*16384, Wm2L + 1*16384, bm2_l + 1*DD, phiS, NN);
    msg_kernel<1><<<NN, 128, 0, stream>>>(phiS, vcur, vnext, x, srcs, eg1, eg2, indptr, Wf_l, bf_l);
    mfma_gemm_kernel<false><<<MB, 256, 0, stream>>>(t1, Wm2h + 2*16384, Wm2L + 2*16384, bm2_l + 2*DD, phiS, NN);
    msg_kernel<2><<<NN, 128, 0, stream>>>(phiS, vcur, vnext, x, srcs, eg1, eg2, indptr, Wf_l, bf_l);
    // fused Uv/Vv/Vn/s: Uv -> dead vcur, Vn -> dead t1, s -> dead phiS
    uvn_mfma_kernel<<<3*NN/48, 256, 0, stream>>>(vnext, Uh, UL, Vh, VL, vcur, t1, phiS);
    // fused a-MLP + update
    aupd_mfma_kernel<<<NN/16, 256, 0, stream>>>(x, vnext, t1, phiS, vcur,
                                                Wu1h, Wu1L, bu1_l, Wu2h, Wu2L, bu2_l);

    float* tmp = vcur; vcur = vnext; vnext = tmp;
  }

  out_kernel<<<NN/4, 256, 0, stream>>>(x, Wo1, bo1, Wo2, bo2, batch, out);

  (void)in_sizes; (void)n_in; (void)out_size; (void)ws_size;
}

// Round 6
// 1616.666 us; speedup vs baseline: 1.5459x; 1.0817x over previous
//
#include <hip/hip_runtime.h>
#include <math.h>

#define NN 50000
#define NE 600000
#define DD 128
#define D3 384
#define NB_ 20
#define HH 64
#define NG_ 512
#define LSZ 180224   // shorts per layer of transposed-bf16 weights

typedef short v8s __attribute__((ext_vector_type(8)));
typedef float v4f __attribute__((ext_vector_type(4)));

__device__ __forceinline__ float silu_f(float z) { return z / (1.0f + expf(-z)); }

__device__ __forceinline__ short f2bf(float f) {
  unsigned u = __float_as_uint(f);
  u += 0x7FFF + ((u >> 16) & 1);          // RNE
  return (short)(u >> 16);
}
__device__ __forceinline__ float bf2f(short s) {
  return __uint_as_float(((unsigned)(unsigned short)s) << 16);
}
__device__ __forceinline__ void split2(float x, short& h, short& l) {
  h = f2bf(x);
  l = f2bf(x - bf2f(h));
}

// ---------------- utility ----------------
__global__ void zero_f_kernel(float* __restrict__ p, long n) {
  long i = (long)blockIdx.x * blockDim.x + threadIdx.x;
  long s = (long)gridDim.x * blockDim.x;
  for (; i < n; i += s) p[i] = 0.0f;
}

__global__ void zero_i_kernel(int* __restrict__ p, long n) {
  long i = (long)blockIdx.x * blockDim.x + threadIdx.x;
  long s = (long)gridDim.x * blockDim.x;
  for (; i < n; i += s) p[i] = 0;
}

__global__ void init_x_kernel(const int* __restrict__ at_no, const float* __restrict__ emb,
                              float* __restrict__ x) {
  int i = blockIdx.x * blockDim.x + threadIdx.x;
  if (i >= NN * DD) return;
  x[i] = emb[at_no[i >> 7] * DD + (i & 127)];
}

// ---------------- weight prep: fp32 [K][N] -> transposed bf16 hi/lo [N][K] ----------------
__global__ void prep_w_kernel(const float* __restrict__ Wm1, const float* __restrict__ Wm2,
                              const float* __restrict__ U, const float* __restrict__ V,
                              const float* __restrict__ Wu1, const float* __restrict__ Wu2,
                              short* __restrict__ hi, short* __restrict__ lo) {
  int idx = blockIdx.x * 256 + threadIdx.x;
  if (idx >= 3 * LSZ) return;
  int l = idx / LSZ, r = idx % LSZ;
  const float* src; int K, N, nk;
  if (r < 16384)       { src = Wm1 + (size_t)l*16384; K = 128; N = 128; nk = r; }
  else if (r < 65536)  { src = Wm2 + (size_t)l*49152; K = 128; N = 384; nk = r - 16384; }
  else if (r < 81920)  { src = U   + (size_t)l*16384; K = 128; N = 128; nk = r - 65536; }
  else if (r < 98304)  { src = V   + (size_t)l*16384; K = 128; N = 128; nk = r - 81920; }
  else if (r < 131072) { src = Wu1 + (size_t)l*32768; K = 256; N = 128; nk = r - 98304; }
  else                 { src = Wu2 + (size_t)l*49152; K = 128; N = 384; nk = r - 131072; }
  int n = nk / K, k = nk - n * K;
  float xx = src[(size_t)k * N + n];
  short h = f2bf(xx);
  hi[idx] = h;
  lo[idx] = f2bf(xx - bf2f(h));
}

// ---------------- CSR build (dst-sorted), filtering dist>=CUTOFF edges ----------------
__global__ void hist_kernel(const int* __restrict__ ei, const float* __restrict__ pos,
                            int* __restrict__ counts) {
  int e = blockIdx.x * blockDim.x + threadIdx.x;
  if (e >= NE) return;
  int s = ei[e], d = ei[NE + e];
  float dx = pos[3*d]   - pos[3*s];
  float dy = pos[3*d+1] - pos[3*s+1];
  float dz = pos[3*d+2] - pos[3*s+2];
  float d2 = dx*dx + dy*dy + dz*dz + 1e-12f;
  if (d2 < 25.0f) atomicAdd(&counts[d], 1);
}

__global__ void scan_kernel(const int* __restrict__ counts, int* __restrict__ indptr, int n) {
  __shared__ int sm[1024];
  __shared__ int carry_s;
  if (threadIdx.x == 0) carry_s = 0;
  __syncthreads();
  for (int start = 0; start < n; start += 1024) {
    int i = start + (int)threadIdx.x;
    int val = (i < n) ? counts[i] : 0;
    sm[threadIdx.x] = val;
    __syncthreads();
    for (int off = 1; off < 1024; off <<= 1) {
      int t = (threadIdx.x >= (unsigned)off) ? sm[threadIdx.x - off] : 0;
      __syncthreads();
      sm[threadIdx.x] += t;
      __syncthreads();
    }
    int c = carry_s;
    if (i < n) indptr[i] = c + sm[threadIdx.x] - val;
    __syncthreads();
    if (threadIdx.x == 0) carry_s = c + sm[1023];
    __syncthreads();
  }
  if (threadIdx.x == 0) indptr[n] = carry_s;
}

__global__ void fill_kernel(const int* __restrict__ ei, const float* __restrict__ pos,
                            const int* __restrict__ indptr, int* __restrict__ cursor,
                            int* __restrict__ srcs, float4* __restrict__ eg1,
                            float4* __restrict__ eg2) {
  int e = blockIdx.x * blockDim.x + threadIdx.x;
  if (e >= NE) return;
  int s = ei[e], d = ei[NE + e];
  float dx = pos[3*d]   - pos[3*s];
  float dy = pos[3*d+1] - pos[3*s+1];
  float dz = pos[3*d+2] - pos[3*s+2];
  float d2 = dx*dx + dy*dy + dz*dz + 1e-12f;
  if (d2 < 25.0f) {
    int p = atomicAdd(&cursor[d], 1);
    int slot = indptr[d] + p;
    float dist = sqrtf(d2);
    float inv = 1.0f / dist;
    float wang = 0.62831853071795864769f * dist;   // pi*dist/CUTOFF
    float s1 = __sinf(wang), c1 = __cosf(wang);
    float fc = 0.5f * (c1 + 1.0f);
    srcs[slot] = s;
    eg1[slot] = make_float4(s1, c1, fc, fc * inv);
    eg2[slot] = make_float4(dx * inv, dy * inv, dz * inv, 0.0f);
  }
}

// ---------------- MFMA split-bf16 GEMM: C[M,128] = op(A[M,128] @ B + bias) ----------------
// In-place (C==A) safe: A-tile fully staged to LDS before any store.
template<bool SILU>
__global__ void __launch_bounds__(256) mfma_gemm_kernel(
    const float* A, const short* __restrict__ Bth,
    const short* __restrict__ Btl, const float* __restrict__ bias,
    float* C, int M) {
  __shared__ float As[32][132];
  int tid = threadIdx.x;
  long r0 = (long)blockIdx.x * 32;
  #pragma unroll
  for (int i = 0; i < 4; i++) {
    int lin = i*256 + tid;
    int r = lin >> 5, c4 = lin & 31;
    long row = r0 + r; if (row >= M) row = M - 1;
    *(float4*)&As[r][c4*4] = *(const float4*)(A + row*128 + c4*4);
  }
  __syncthreads();
  int lane = tid & 63, wv = tid >> 6;
  int l15 = lane & 15, q = lane >> 4;
  v4f acc[2][2] = {};
  #pragma unroll
  for (int s = 0; s < 4; s++) {
    v8s ah[2], al[2];
    #pragma unroll
    for (int mt = 0; mt < 2; mt++) {
      const float* ap = &As[mt*16 + l15][s*32 + q*8];
      float4 f0 = *(const float4*)(ap);
      float4 f1 = *(const float4*)(ap + 4);
      short h,l;
      split2(f0.x,h,l); ah[mt][0]=h; al[mt][0]=l;  split2(f0.y,h,l); ah[mt][1]=h; al[mt][1]=l;
      split2(f0.z,h,l); ah[mt][2]=h; al[mt][2]=l;  split2(f0.w,h,l); ah[mt][3]=h; al[mt][3]=l;
      split2(f1.x,h,l); ah[mt][4]=h; al[mt][4]=l;  split2(f1.y,h,l); ah[mt][5]=h; al[mt][5]=l;
      split2(f1.z,h,l); ah[mt][6]=h; al[mt][6]=l;  split2(f1.w,h,l); ah[mt][7]=h; al[mt][7]=l;
    }
    #pragma unroll
    for (int nt = 0; nt < 2; nt++) {
      int n = (2*wv + nt)*16 + l15;
      v8s bh = *(const v8s*)(Bth + (long)n*128 + s*32 + q*8);
      v8s bl = *(const v8s*)(Btl + (long)n*128 + s*32 + q*8);
      #pragma unroll
      for (int mt = 0; mt < 2; mt++) {
        acc[mt][nt] = __builtin_amdgcn_mfma_f32_16x16x32_bf16(ah[mt], bh, acc[mt][nt], 0, 0, 0);
        acc[mt][nt] = __builtin_amdgcn_mfma_f32_16x16x32_bf16(al[mt], bh, acc[mt][nt], 0, 0, 0);
        acc[mt][nt] = __builtin_amdgcn_mfma_f32_16x16x32_bf16(ah[mt], bl, acc[mt][nt], 0, 0, 0);
      }
    }
  }
  #pragma unroll
  for (int nt = 0; nt < 2; nt++) {
    int n = (2*wv + nt)*16 + l15;
    float bb = bias[n];
    #pragma unroll
    for (int mt = 0; mt < 2; mt++)
      #pragma unroll
      for (int i = 0; i < 4; i++) {
        long row = r0 + mt*16 + q*4 + i;
        if (row < M) {
          float val = acc[mt][nt][i] + bb;
          if constexpr (SILU) val = silu_f(val);
          C[row*128 + n] = val;
        }
      }
  }
}

// ---------------- msg slice 0: x += seg(ds). 8 nodes/block ----------------
__global__ void __launch_bounds__(128) msg0_kernel(
    const float* __restrict__ phiS, float* __restrict__ x,
    const int* __restrict__ srcs, const float4* __restrict__ eg1,
    const int* __restrict__ indptr,
    const float* __restrict__ Wf_l, const float* __restrict__ bf_l) {
  int d = threadIdx.x;
  float wf[NB_];
  #pragma unroll
  for (int k = 0; k < NB_; k++) wf[k] = Wf_l[k*D3 + d];
  float bfv = bf_l[d];
  int n0 = blockIdx.x * 8;
  for (int j = 0; j < 8; j++) {
    int n = n0 + j;
    int t = indptr[n], end = indptr[n+1];
    float xacc = 0.f;
    int sN = 0; float4 g1N = {};
    if (t < end) { sN = srcs[t]; g1N = eg1[t]; }
    while (t < end) {
      int s = sN; float4 g = g1N;
      t++;
      if (t < end) { sN = srcs[t]; g1N = eg1[t]; }
      float p1 = phiS[(long)s*DD + d];
      float c2 = 2.0f * g.y;
      float rkm1 = 0.f, rk = g.x, dot = 0.f;
      #pragma unroll
      for (int k = 0; k < NB_; k++) {
        dot = fmaf(rk, wf[k], dot);
        float rn = fmaf(c2, rk, -rkm1);
        rkm1 = rk; rk = rn;
      }
      xacc = fmaf(p1, bfv*g.z + g.w*dot, xacc);
    }
    x[(long)n*DD + d] += xacc;
  }
}

// ---------------- msg slices 1+2 merged: vB = vA + seg(dv1*dir + dv2*v[src]) ----------------
__global__ void __launch_bounds__(128) msg12_kernel(
    const float* __restrict__ phi1, const float* __restrict__ phi2,
    const float* __restrict__ vA, float* __restrict__ vB,
    const int* __restrict__ srcs, const float4* __restrict__ eg1,
    const float4* __restrict__ eg2, const int* __restrict__ indptr,
    const float* __restrict__ Wf_l, const float* __restrict__ bf_l) {
  int d = threadIdx.x;
  float wf1[NB_], wf2[NB_];
  #pragma unroll
  for (int k = 0; k < NB_; k++) {
    wf1[k] = Wf_l[k*D3 + DD + d];
    wf2[k] = Wf_l[k*D3 + 2*DD + d];
  }
  float bf1 = bf_l[DD + d], bf2 = bf_l[2*DD + d];
  int n0 = blockIdx.x * 8;
  for (int j = 0; j < 8; j++) {
    int n = n0 + j;
    int t = indptr[n], end = indptr[n+1];
    float a0 = 0.f, a1 = 0.f, a2 = 0.f;
    int sN = 0; float4 g1N = {}, g2N = {};
    if (t < end) { sN = srcs[t]; g1N = eg1[t]; g2N = eg2[t]; }
    while (t < end) {
      int s = sN; float4 g = g1N; float4 dv = g2N;
      t++;
      if (t < end) { sN = srcs[t]; g1N = eg1[t]; g2N = eg2[t]; }
      float p1  = phi1[(long)s*DD + d];
      float p2  = phi2[(long)s*DD + d];
      const float* vs = vA + (long)s*D3;
      float vs0 = vs[d], vs1 = vs[DD + d], vs2 = vs[2*DD + d];
      float c2 = 2.0f * g.y;
      float rkm1 = 0.f, rk = g.x, dot1 = 0.f, dot2 = 0.f;
      #pragma unroll
      for (int k = 0; k < NB_; k++) {
        dot1 = fmaf(rk, wf1[k], dot1);
        dot2 = fmaf(rk, wf2[k], dot2);
        float rn = fmaf(c2, rk, -rkm1);
        rkm1 = rk; rk = rn;
      }
      float m1 = p1 * (bf1*g.z + g.w*dot1);
      float m2 = p2 * (bf2*g.z + g.w*dot2);
      a0 = fmaf(m1, dv.x, fmaf(m2, vs0, a0));
      a1 = fmaf(m1, dv.y, fmaf(m2, vs1, a1));
      a2 = fmaf(m1, dv.z, fmaf(m2, vs2, a2));
    }
    long b = (long)n*D3 + d;
    vB[b]        = vA[b]        + a0;
    vB[b + DD]   = vA[b + DD]   + a1;
    vB[b + 2*DD] = vA[b + 2*DD] + a2;
  }
}

// ---------------- fused Uv/Vv/Vn/s + a-MLP + update (uva): 16 nodes/block ----------------
// Phase1: U,V projections of the 48-row v-tile via MFMA. Phase2: LDS-accumulate
// s=sum_c Uv*Vv, Vn2=sum_c Vv^2 (each (node,d) owned by exactly one wave);
// Vn goes straight into cat (overlaying the dead v-tile). GEMM1+GEMM2+update.
__global__ void __launch_bounds__(256) uva_kernel(
    float* __restrict__ x, float* __restrict__ v,
    const short* __restrict__ Uth, const short* __restrict__ Utl,
    const short* __restrict__ Vth, const short* __restrict__ Vtl,
    const short* __restrict__ W1h, const short* __restrict__ W1l, const float* __restrict__ b1,
    const short* __restrict__ W2h, const short* __restrict__ W2l, const float* __restrict__ b2) {
  __shared__ float smemA[48*132];       // phase1: As[48][132]; later: cat[16][264] | t2s[16][132]
  __shared__ float Uvs[48][132];
  __shared__ float sacc[16][132];
  __shared__ float nacc[16][132];
  float (*As)[132]  = (float(*)[132])smemA;
  float (*cat)[264] = (float(*)[264])smemA;
  float (*t2s)[132] = (float(*)[132])(smemA + 16*264);
  int tid = threadIdx.x;
  long nb = (long)blockIdx.x * 16;      // first node
  long r0 = nb * 3;                     // first v-row
  // load v tile + zero accumulators
  #pragma unroll
  for (int i = 0; i < 6; i++) {
    int lin = i*256 + tid;
    int r = lin >> 5, c4 = lin & 31;
    *(float4*)&As[r][c4*4] = *(const float4*)(v + (r0 + r)*128 + c4*4);
  }
  for (int i = tid; i < 16*132; i += 256) { ((float*)sacc)[i] = 0.f; ((float*)nacc)[i] = 0.f; }
  __syncthreads();
  int lane = tid & 63, wv = tid >> 6;
  int l15 = lane & 15, q = lane >> 4;
  // ---- phase 1: U & V projections ----
  v4f aU[3][2] = {}, aV[3][2] = {};
  #pragma unroll
  for (int s = 0; s < 4; s++) {
    v8s ah[3], al[3];
    #pragma unroll
    for (int mt = 0; mt < 3; mt++) {
      const float* ap = &As[mt*16 + l15][s*32 + q*8];
      float4 f0 = *(const float4*)(ap);
      float4 f1 = *(const float4*)(ap + 4);
      short h,l;
      split2(f0.x,h,l); ah[mt][0]=h; al[mt][0]=l;  split2(f0.y,h,l); ah[mt][1]=h; al[mt][1]=l;
      split2(f0.z,h,l); ah[mt][2]=h; al[mt][2]=l;  split2(f0.w,h,l); ah[mt][3]=h; al[mt][3]=l;
      split2(f1.x,h,l); ah[mt][4]=h; al[mt][4]=l;  split2(f1.y,h,l); ah[mt][5]=h; al[mt][5]=l;
      split2(f1.z,h,l); ah[mt][6]=h; al[mt][6]=l;  split2(f1.w,h,l); ah[mt][7]=h; al[mt][7]=l;
    }
    #pragma unroll
    for (int nt = 0; nt < 2; nt++) {
      int n = (2*wv + nt)*16 + l15;
      long boff = (long)n*128 + s*32 + q*8;
      v8s buh = *(const v8s*)(Uth + boff);
      v8s bul = *(const v8s*)(Utl + boff);
      v8s bvh = *(const v8s*)(Vth + boff);
      v8s bvl = *(const v8s*)(Vtl + boff);
      #pragma unroll
      for (int mt = 0; mt < 3; mt++) {
        aU[mt][nt] = __builtin_amdgcn_mfma_f32_16x16x32_bf16(ah[mt], buh, aU[mt][nt], 0, 0, 0);
        aU[mt][nt] = __builtin_amdgcn_mfma_f32_16x16x32_bf16(al[mt], buh, aU[mt][nt], 0, 0, 0);
        aU[mt][nt] = __builtin_amdgcn_mfma_f32_16x16x32_bf16(ah[mt], bul, aU[mt][nt], 0, 0, 0);
        aV[mt][nt] = __builtin_amdgcn_mfma_f32_16x16x32_bf16(ah[mt], bvh, aV[mt][nt], 0, 0, 0);
        aV[mt][nt] = __builtin_amdgcn_mfma_f32_16x16x32_bf16(al[mt], bvh, aV[mt][nt], 0, 0, 0);
        aV[mt][nt] = __builtin_amdgcn_mfma_f32_16x16x32_bf16(ah[mt], bvl, aV[mt][nt], 0, 0, 0);
      }
    }
  }
  // ---- phase 2a: stash Uv, accumulate s and Vn^2 (no races: see header) ----
  #pragma unroll
  for (int mt = 0; mt < 3; mt++)
    #pragma unroll
    for (int nt = 0; nt < 2; nt++) {
      int lc = (2*wv + nt)*16 + l15;
      #pragma unroll
      for (int i = 0; i < 4; i++) {
        int row = mt*16 + q*4 + i;
        int node = row / 3;              // 0..15
        float u = aU[mt][nt][i], w = aV[mt][nt][i];
        Uvs[row][lc] = u;
        sacc[node][lc] += u * w;
        nacc[node][lc] += w * w;
      }
    }
  __syncthreads();   // all done with As + accumulation complete
  // ---- phase 2b: build cat = [x | Vn] (overlays As) ----
  #pragma unroll
  for (int i = 0; i < 2; i++) {
    int lin = i*256 + tid;
    int r = lin >> 5, c4 = lin & 31;
    *(float4*)&cat[r][c4*4] = *(const float4*)(x + (nb + r)*128 + c4*4);
  }
  #pragma unroll
  for (int i = 0; i < 8; i++) {
    int e = i*256 + tid;
    int node = e >> 7, d = e & 127;
    cat[node][128 + d] = sqrtf(nacc[node][d] + 1e-8f);
  }
  __syncthreads();
  // ---- GEMM1: t2 = silu(cat @ Wu1 + b1), K=256, N=128 ----
  {
    v4f acc[2] = {};
    #pragma unroll
    for (int s = 0; s < 8; s++) {
      const float* ap = &cat[l15][s*32 + q*8];
      float4 f0 = *(const float4*)(ap);
      float4 f1 = *(const float4*)(ap + 4);
      v8s ah, al;
      { short h,l;
        split2(f0.x,h,l); ah[0]=h; al[0]=l;  split2(f0.y,h,l); ah[1]=h; al[1]=l;
        split2(f0.z,h,l); ah[2]=h; al[2]=l;  split2(f0.w,h,l); ah[3]=h; al[3]=l;
        split2(f1.x,h,l); ah[4]=h; al[4]=l;  split2(f1.y,h,l); ah[5]=h; al[5]=l;
        split2(f1.z,h,l); ah[6]=h; al[6]=l;  split2(f1.w,h,l); ah[7]=h; al[7]=l; }
      #pragma unroll
      for (int nt = 0; nt < 2; nt++) {
        int n = (2*wv + nt)*16 + l15;
        v8s bh = *(const v8s*)(W1h + (long)n*256 + s*32 + q*8);
        v8s bl = *(const v8s*)(W1l + (long)n*256 + s*32 + q*8);
        acc[nt] = __builtin_amdgcn_mfma_f32_16x16x32_bf16(ah, bh, acc[nt], 0, 0, 0);
        acc[nt] = __builtin_amdgcn_mfma_f32_16x16x32_bf16(al, bh, acc[nt], 0, 0, 0);
        acc[nt] = __builtin_amdgcn_mfma_f32_16x16x32_bf16(ah, bl, acc[nt], 0, 0, 0);
      }
    }
    #pragma unroll
    for (int nt = 0; nt < 2; nt++) {
      int n = (2*wv + nt)*16 + l15;
      float bb = b1[n];
      #pragma unroll
      for (int i = 0; i < 4; i++)
        t2s[q*4 + i][n] = silu_f(acc[nt][i] + bb);
    }
  }
  __syncthreads();
  // ---- GEMM2 (+ prefetch old v) + update ----
  {
    // prefetch v-old for the epilogue (addresses independent of GEMM2)
    float vold[2][4][3];
    #pragma unroll
    for (int p = 0; p < 2; p++) {
      int d = (2*wv + p)*16 + l15;
      #pragma unroll
      for (int i = 0; i < 4; i++) {
        long row = nb + q*4 + i;
        #pragma unroll
        for (int c = 0; c < 3; c++) vold[p][i][c] = v[row*384 + c*128 + d];
      }
    }
    v4f acc[6] = {};
    #pragma unroll
    for (int s = 0; s < 4; s++) {
      const float* ap = &t2s[l15][s*32 + q*8];
      float4 f0 = *(const float4*)(ap);
      float4 f1 = *(const float4*)(ap + 4);
      v8s ah, al;
      { short h,l;
        split2(f0.x,h,l); ah[0]=h; al[0]=l;  split2(f0.y,h,l); ah[1]=h; al[1]=l;
        split2(f0.z,h,l); ah[2]=h; al[2]=l;  split2(f0.w,h,l); ah[3]=h; al[3]=l;
        split2(f1.x,h,l); ah[4]=h; al[4]=l;  split2(f1.y,h,l); ah[5]=h; al[5]=l;
        split2(f1.z,h,l); ah[6]=h; al[6]=l;  split2(f1.w,h,l); ah[7]=h; al[7]=l; }
      #pragma unroll
      for (int g = 0; g < 6; g++) {
        int nt = (g >> 1)*8 + 2*wv + (g & 1);
        int n = nt*16 + l15;                 // 0..383
        v8s bh = *(const v8s*)(W2h + (long)n*128 + s*32 + q*8);
        v8s bl = *(const v8s*)(W2l + (long)n*128 + s*32 + q*8);
        acc[g] = __builtin_amdgcn_mfma_f32_16x16x32_bf16(ah, bh, acc[g], 0, 0, 0);
        acc[g] = __builtin_amdgcn_mfma_f32_16x16x32_bf16(al, bh, acc[g], 0, 0, 0);
        acc[g] = __builtin_amdgcn_mfma_f32_16x16x32_bf16(ah, bl, acc[g], 0, 0, 0);
      }
    }
    #pragma unroll
    for (int p = 0; p < 2; p++) {
      int d = (2*wv + p)*16 + l15;           // 0..127
      float bavv = b2[d], basv = b2[128 + d], bass = b2[256 + d];
      #pragma unroll
      for (int i = 0; i < 4; i++) {
        int lr = q*4 + i;                    // local node
        long row = nb + lr;
        float avv = acc[p][i]     + bavv;
        float asv = acc[2 + p][i] + basv;
        float ass = acc[4 + p][i] + bass;
        x[row*128 + d] = cat[lr][d] + ass + asv * sacc[lr][d];
        #pragma unroll
        for (int c = 0; c < 3; c++)
          v[row*384 + c*128 + d] = fmaf(avv, Uvs[3*lr + c][d], vold[p][i][c]);
      }
    }
  }
}

// ---------------- output head + segment sum: 4 nodes/block, LDS-staged x ----------------
__global__ void __launch_bounds__(256) out_kernel(
    const float* __restrict__ x, const float* __restrict__ Wo1,
    const float* __restrict__ bo1, const float* __restrict__ Wo2,
    const float* __restrict__ bo2, const int* __restrict__ batch,
    float* __restrict__ out) {
  __shared__ float xs[4][132];
  int tid = threadIdx.x;
  long n0 = (long)blockIdx.x * 4;
  if (tid < 128) {
    int r = tid >> 5, c4 = tid & 31;
    *(float4*)&xs[r][c4*4] = *(const float4*)(x + (n0 + r)*128 + c4*4);
  }
  __syncthreads();
  int wv = tid >> 6, t = tid & 63;
  float acc = bo1[t];
  #pragma unroll 16
  for (int k = 0; k < DD; k++) acc = fmaf(xs[wv][k], Wo1[k*HH + t], acc);
  float val = silu_f(acc) * Wo2[t];
  #pragma unroll
  for (int off = 32; off > 0; off >>= 1) val += __shfl_down(val, off);
  if (t == 0) atomicAdd(&out[batch[n0 + wv]], val + bo2[0]);
}

// ---------------- launcher ----------------
extern "C" void kernel_launch(void* const* d_in, const int* in_sizes, int n_in,
                              void* d_out, int out_size, void* d_ws, size_t ws_size,
                              hipStream_t stream) {
  const int*   at_no = (const int*)d_in[0];
  const float* pos   = (const float*)d_in[1];
  const int*   ei    = (const int*)d_in[2];
  const int*   batch = (const int*)d_in[3];
  const float* emb   = (const float*)d_in[4];
  const float* Wf    = (const float*)d_in[5];
  const float* bfp   = (const float*)d_in[6];
  const float* Wm1   = (const float*)d_in[7];
  const float* bm1   = (const float*)d_in[8];
  const float* Wm2   = (const float*)d_in[9];
  const float* bm2   = (const float*)d_in[10];
  const float* U     = (const float*)d_in[11];
  const float* V     = (const float*)d_in[12];
  const float* Wu1   = (const float*)d_in[13];
  const float* bu1   = (const float*)d_in[14];
  const float* Wu2   = (const float*)d_in[15];
  const float* bu2   = (const float*)d_in[16];
  const float* Wo1   = (const float*)d_in[17];
  const float* bo1   = (const float*)d_in[18];
  const float* Wo2   = (const float*)d_in[19];
  const float* bo2   = (const float*)d_in[20];
  float* out = (float*)d_out;

  char* w = (char*)d_ws;
  auto alloc = [&](size_t bytes) -> void* {
    void* p = (void*)w;
    w += (bytes + 255) & ~(size_t)255;
    return p;
  };
  float*  x      = (float*)alloc(sizeof(float)*(size_t)NN*DD);
  float*  v_a    = (float*)alloc(sizeof(float)*(size_t)NN*D3);
  float*  v_b    = (float*)alloc(sizeof(float)*(size_t)NN*D3);
  float*  t1     = (float*)alloc(sizeof(float)*(size_t)NN*DD);   // phi slice 2 (in-place)
  float*  phiS   = (float*)alloc(sizeof(float)*(size_t)NN*DD);   // phi slices 0 / 1
  short*  wbh    = (short*)alloc(sizeof(short)*(size_t)3*LSZ);
  short*  wbl    = (short*)alloc(sizeof(short)*(size_t)3*LSZ);
  int*    srcs   = (int*)alloc(sizeof(int)*(size_t)NE);
  float4* eg1    = (float4*)alloc(sizeof(float4)*(size_t)NE);
  float4* eg2    = (float4*)alloc(sizeof(float4)*(size_t)NE);
  int*    indptr = (int*)alloc(sizeof(int)*((size_t)NN+1));
  int*    counts = (int*)alloc(sizeof(int)*(size_t)NN);

  if ((size_t)(w - (char*)d_ws) > ws_size) {   // diagnostic guard: zeros => ws too small
    zero_f_kernel<<<2, 256, 0, stream>>>(out, NG_);
    return;
  }

  zero_f_kernel<<<2048, 256, 0, stream>>>(v_a, (long)NN*D3);
  zero_f_kernel<<<2, 256, 0, stream>>>(out, NG_);
  zero_i_kernel<<<64, 256, 0, stream>>>(counts, NN);
  init_x_kernel<<<(NN*DD + 255)/256, 256, 0, stream>>>(at_no, emb, x);
  prep_w_kernel<<<(3*LSZ + 255)/256, 256, 0, stream>>>(Wm1, Wm2, U, V, Wu1, Wu2, wbh, wbl);
  hist_kernel<<<(NE + 255)/256, 256, 0, stream>>>(ei, pos, counts);
  scan_kernel<<<1, 1024, 0, stream>>>(counts, indptr, NN);
  zero_i_kernel<<<64, 256, 0, stream>>>(counts, NN);
  fill_kernel<<<(NE + 255)/256, 256, 0, stream>>>(ei, pos, indptr, counts, srcs, eg1, eg2);

  const int MB = (NN + 31) / 32;    // 1563
  float* vcur = v_a;
  float* vnext = v_b;
  for (int l = 0; l < 3; l++) {
    const float* Wf_l  = Wf  + (size_t)l*NB_*D3;
    const float* bf_l  = bfp + (size_t)l*D3;
    const float* bm1_l = bm1 + (size_t)l*DD;
    const float* bm2_l = bm2 + (size_t)l*D3;
    const float* bu1_l = bu1 + (size_t)l*DD;
    const float* bu2_l = bu2 + (size_t)l*D3;
    const short* Lh = wbh + (size_t)l*LSZ;
    const short* Ll = wbl + (size_t)l*LSZ;
    const short* Wm1h = Lh,          *Wm1L = Ll;
    const short* Wm2h = Lh + 16384,  *Wm2L = Ll + 16384;
    const short* Uh   = Lh + 65536,  *UL   = Ll + 65536;
    const short* Vh   = Lh + 81920,  *VL   = Ll + 81920;
    const short* Wu1h = Lh + 98304,  *Wu1L = Ll + 98304;
    const short* Wu2h = Lh + 131072, *Wu2L = Ll + 131072;

    // t1 = silu(x@Wm1 + bm1)
    mfma_gemm_kernel<true><<<MB, 256, 0, stream>>>(x, Wm1h, Wm1L, bm1_l, t1, NN);
    // slice 0 -> phiS, consume into x
    mfma_gemm_kernel<false><<<MB, 256, 0, stream>>>(t1, Wm2h + 0*16384, Wm2L + 0*16384, bm2_l + 0*DD, phiS, NN);
    msg0_kernel<<<NN/8, 128, 0, stream>>>(phiS, x, srcs, eg1, indptr, Wf_l, bf_l);
    // slice 1 -> phiS ; slice 2 -> t1 (in place) ; merged message pass
    mfma_gemm_kernel<false><<<MB, 256, 0, stream>>>(t1, Wm2h + 1*16384, Wm2L + 1*16384, bm2_l + 1*DD, phiS, NN);
    mfma_gemm_kernel<false><<<MB, 256, 0, stream>>>(t1, Wm2h + 2*16384, Wm2L + 2*16384, bm2_l + 2*DD, t1, NN);
    msg12_kernel<<<NN/8, 128, 0, stream>>>(phiS, t1, vcur, vnext, srcs, eg1, eg2, indptr, Wf_l, bf_l);
    // fused Uv/Vv/Vn/s + a-MLP + x,v update
    uva_kernel<<<NN/16, 256, 0, stream>>>(x, vnext, Uh, UL, Vh, VL,
                                          Wu1h, Wu1L, bu1_l, Wu2h, Wu2L, bu2_l);

    float* tmp = vcur; vcur = vnext; vnext = tmp;
  }

  out_kernel<<<NN/4, 256, 0, stream>>>(x, Wo1, bo1, Wo2, bo2, batch, out);

  (void)in_sizes; (void)n_in; (void)out_size; (void)ws_size;
}

// Round 7
// 1589.946 us; speedup vs baseline: 1.5718x; 1.0168x over previous
//
#include <hip/hip_runtime.h>
#include <math.h>

#define NN 50000
#define NE 600000
#define DD 128
#define D3 384
#define NB_ 20
#define HH 64
#define NG_ 512
#define LSZ 180224   // shorts per layer of transposed-bf16 weights

typedef short v8s __attribute__((ext_vector_type(8)));
typedef float v4f __attribute__((ext_vector_type(4)));

__device__ __forceinline__ float silu_f(float z) { return z / (1.0f + expf(-z)); }

__device__ __forceinline__ short f2bf(float f) {
  unsigned u = __float_as_uint(f);
  u += 0x7FFF + ((u >> 16) & 1);          // RNE
  return (short)(u >> 16);
}
__device__ __forceinline__ float bf2f(short s) {
  return __uint_as_float(((unsigned)(unsigned short)s) << 16);
}
__device__ __forceinline__ void split2(float x, short& h, short& l) {
  h = f2bf(x);
  l = f2bf(x - bf2f(h));
}
#define SPLIT8(f0, f1, ah, al) { short h,l; \
  split2(f0.x,h,l); ah[0]=h; al[0]=l;  split2(f0.y,h,l); ah[1]=h; al[1]=l; \
  split2(f0.z,h,l); ah[2]=h; al[2]=l;  split2(f0.w,h,l); ah[3]=h; al[3]=l; \
  split2(f1.x,h,l); ah[4]=h; al[4]=l;  split2(f1.y,h,l); ah[5]=h; al[5]=l; \
  split2(f1.z,h,l); ah[6]=h; al[6]=l;  split2(f1.w,h,l); ah[7]=h; al[7]=l; }

// ---------------- utility ----------------
__global__ void zero_f_kernel(float* __restrict__ p, long n) {
  long i = (long)blockIdx.x * blockDim.x + threadIdx.x;
  long s = (long)gridDim.x * blockDim.x;
  for (; i < n; i += s) p[i] = 0.0f;
}

__global__ void zero_i_kernel(int* __restrict__ p, long n) {
  long i = (long)blockIdx.x * blockDim.x + threadIdx.x;
  long s = (long)gridDim.x * blockDim.x;
  for (; i < n; i += s) p[i] = 0;
}

__global__ void init_x_kernel(const int* __restrict__ at_no, const float* __restrict__ emb,
                              float* __restrict__ x) {
  int i = blockIdx.x * blockDim.x + threadIdx.x;
  if (i >= NN * DD) return;
  x[i] = emb[at_no[i >> 7] * DD + (i & 127)];
}

// ---------------- weight prep: fp32 [K][N] -> transposed bf16 hi/lo [N][K] ----------------
__global__ void prep_w_kernel(const float* __restrict__ Wm1, const float* __restrict__ Wm2,
                              const float* __restrict__ U, const float* __restrict__ V,
                              const float* __restrict__ Wu1, const float* __restrict__ Wu2,
                              short* __restrict__ hi, short* __restrict__ lo) {
  int idx = blockIdx.x * 256 + threadIdx.x;
  if (idx >= 3 * LSZ) return;
  int l = idx / LSZ, r = idx % LSZ;
  const float* src; int K, N, nk;
  if (r < 16384)       { src = Wm1 + (size_t)l*16384; K = 128; N = 128; nk = r; }
  else if (r < 65536)  { src = Wm2 + (size_t)l*49152; K = 128; N = 384; nk = r - 16384; }
  else if (r < 81920)  { src = U   + (size_t)l*16384; K = 128; N = 128; nk = r - 65536; }
  else if (r < 98304)  { src = V   + (size_t)l*16384; K = 128; N = 128; nk = r - 81920; }
  else if (r < 131072) { src = Wu1 + (size_t)l*32768; K = 256; N = 128; nk = r - 98304; }
  else                 { src = Wu2 + (size_t)l*49152; K = 128; N = 384; nk = r - 131072; }
  int n = nk / K, k = nk - n * K;
  float xx = src[(size_t)k * N + n];
  short h = f2bf(xx);
  hi[idx] = h;
  lo[idx] = f2bf(xx - bf2f(h));
}

// ---------------- CSR build (dst-sorted), filtering dist>=CUTOFF edges ----------------
__global__ void hist_kernel(const int* __restrict__ ei, const float* __restrict__ pos,
                            int* __restrict__ counts) {
  int e = blockIdx.x * blockDim.x + threadIdx.x;
  if (e >= NE) return;
  int s = ei[e], d = ei[NE + e];
  float dx = pos[3*d]   - pos[3*s];
  float dy = pos[3*d+1] - pos[3*s+1];
  float dz = pos[3*d+2] - pos[3*s+2];
  float d2 = dx*dx + dy*dy + dz*dz + 1e-12f;
  if (d2 < 25.0f) atomicAdd(&counts[d], 1);
}

__global__ void scan_kernel(const int* __restrict__ counts, int* __restrict__ indptr, int n) {
  __shared__ int sm[1024];
  __shared__ int carry_s;
  if (threadIdx.x == 0) carry_s = 0;
  __syncthreads();
  for (int start = 0; start < n; start += 1024) {
    int i = start + (int)threadIdx.x;
    int val = (i < n) ? counts[i] : 0;
    sm[threadIdx.x] = val;
    __syncthreads();
    for (int off = 1; off < 1024; off <<= 1) {
      int t = (threadIdx.x >= (unsigned)off) ? sm[threadIdx.x - off] : 0;
      __syncthreads();
      sm[threadIdx.x] += t;
      __syncthreads();
    }
    int c = carry_s;
    if (i < n) indptr[i] = c + sm[threadIdx.x] - val;
    __syncthreads();
    if (threadIdx.x == 0) carry_s = c + sm[1023];
    __syncthreads();
  }
  if (threadIdx.x == 0) indptr[n] = carry_s;
}

__global__ void fill_kernel(const int* __restrict__ ei, const float* __restrict__ pos,
                            const int* __restrict__ indptr, int* __restrict__ cursor,
                            int* __restrict__ srcs, float4* __restrict__ eg1,
                            float4* __restrict__ eg2) {
  int e = blockIdx.x * blockDim.x + threadIdx.x;
  if (e >= NE) return;
  int s = ei[e], d = ei[NE + e];
  float dx = pos[3*d]   - pos[3*s];
  float dy = pos[3*d+1] - pos[3*s+1];
  float dz = pos[3*d+2] - pos[3*s+2];
  float d2 = dx*dx + dy*dy + dz*dz + 1e-12f;
  if (d2 < 25.0f) {
    int p = atomicAdd(&cursor[d], 1);
    int slot = indptr[d] + p;
    float dist = sqrtf(d2);
    float inv = 1.0f / dist;
    float wang = 0.62831853071795864769f * dist;   // pi*dist/CUTOFF
    float s1 = __sinf(wang), c1 = __cosf(wang);
    float fc = 0.5f * (c1 + 1.0f);
    srcs[slot] = s;
    eg1[slot] = make_float4(s1, c1, fc, fc * inv);
    eg2[slot] = make_float4(dx * inv, dy * inv, dz * inv, 0.0f);
  }
}

// ---------------- MFMA split-bf16 GEMM: C[M,128] = op(A[M,128] @ B + bias) ----------------
// In-place (C==A) safe: A-tile fully staged to LDS before any store.
template<bool SILU>
__global__ void __launch_bounds__(256) mfma_gemm_kernel(
    const float* A, const short* __restrict__ Bth,
    const short* __restrict__ Btl, const float* __restrict__ bias,
    float* C, int M) {
  __shared__ float As[32][132];
  int tid = threadIdx.x;
  long r0 = (long)blockIdx.x * 32;
  #pragma unroll
  for (int i = 0; i < 4; i++) {
    int lin = i*256 + tid;
    int r = lin >> 5, c4 = lin & 31;
    long row = r0 + r; if (row >= M) row = M - 1;
    *(float4*)&As[r][c4*4] = *(const float4*)(A + row*128 + c4*4);
  }
  __syncthreads();
  int lane = tid & 63, wv = tid >> 6;
  int l15 = lane & 15, q = lane >> 4;
  v4f acc[2][2] = {};
  #pragma unroll
  for (int s = 0; s < 4; s++) {
    v8s ah[2], al[2];
    #pragma unroll
    for (int mt = 0; mt < 2; mt++) {
      const float* ap = &As[mt*16 + l15][s*32 + q*8];
      float4 f0 = *(const float4*)(ap);
      float4 f1 = *(const float4*)(ap + 4);
      SPLIT8(f0, f1, ah[mt], al[mt]);
    }
    #pragma unroll
    for (int nt = 0; nt < 2; nt++) {
      int n = (2*wv + nt)*16 + l15;
      v8s bh = *(const v8s*)(Bth + (long)n*128 + s*32 + q*8);
      v8s bl = *(const v8s*)(Btl + (long)n*128 + s*32 + q*8);
      #pragma unroll
      for (int mt = 0; mt < 2; mt++) {
        acc[mt][nt] = __builtin_amdgcn_mfma_f32_16x16x32_bf16(ah[mt], bh, acc[mt][nt], 0, 0, 0);
        acc[mt][nt] = __builtin_amdgcn_mfma_f32_16x16x32_bf16(al[mt], bh, acc[mt][nt], 0, 0, 0);
        acc[mt][nt] = __builtin_amdgcn_mfma_f32_16x16x32_bf16(ah[mt], bl, acc[mt][nt], 0, 0, 0);
      }
    }
  }
  #pragma unroll
  for (int nt = 0; nt < 2; nt++) {
    int n = (2*wv + nt)*16 + l15;
    float bb = bias[n];
    #pragma unroll
    for (int mt = 0; mt < 2; mt++)
      #pragma unroll
      for (int i = 0; i < 4; i++) {
        long row = r0 + mt*16 + q*4 + i;
        if (row < M) {
          float val = acc[mt][nt][i] + bb;
          if constexpr (SILU) val = silu_f(val);
          C[row*128 + n] = val;
        }
      }
  }
}

// ---------------- dual-slice GEMM: C1 = A@B1+b1, C2 = A@B2+b2 (C2==A safe) ----------------
// waves 0,1 -> slice 1; waves 2,3 -> slice 2. A-tile read once.
__global__ void __launch_bounds__(256) mfma_gemm_dual_kernel(
    const float* A, const short* __restrict__ B1h, const short* __restrict__ B1l,
    const short* __restrict__ B2h, const short* __restrict__ B2l,
    const float* __restrict__ bias1, const float* __restrict__ bias2,
    float* C1, float* C2, int M) {
  __shared__ float As[32][132];
  int tid = threadIdx.x;
  long r0 = (long)blockIdx.x * 32;
  #pragma unroll
  for (int i = 0; i < 4; i++) {
    int lin = i*256 + tid;
    int r = lin >> 5, c4 = lin & 31;
    long row = r0 + r; if (row >= M) row = M - 1;
    *(float4*)&As[r][c4*4] = *(const float4*)(A + row*128 + c4*4);
  }
  __syncthreads();
  int lane = tid & 63, wv = tid >> 6;
  int l15 = lane & 15, q = lane >> 4;
  const short* Bh = (wv < 2) ? B1h : B2h;
  const short* Bl = (wv < 2) ? B1l : B2l;
  const float* bias = (wv < 2) ? bias1 : bias2;
  float* C = (wv < 2) ? C1 : C2;
  int nc0 = (wv & 1) * 64;
  v4f acc[2][4] = {};
  #pragma unroll
  for (int s = 0; s < 4; s++) {
    v8s ah[2], al[2];
    #pragma unroll
    for (int mt = 0; mt < 2; mt++) {
      const float* ap = &As[mt*16 + l15][s*32 + q*8];
      float4 f0 = *(const float4*)(ap);
      float4 f1 = *(const float4*)(ap + 4);
      SPLIT8(f0, f1, ah[mt], al[mt]);
    }
    #pragma unroll
    for (int nt = 0; nt < 4; nt++) {
      int n = nc0 + nt*16 + l15;
      v8s bh = *(const v8s*)(Bh + (long)n*128 + s*32 + q*8);
      v8s bl = *(const v8s*)(Bl + (long)n*128 + s*32 + q*8);
      #pragma unroll
      for (int mt = 0; mt < 2; mt++) {
        acc[mt][nt] = __builtin_amdgcn_mfma_f32_16x16x32_bf16(ah[mt], bh, acc[mt][nt], 0, 0, 0);
        acc[mt][nt] = __builtin_amdgcn_mfma_f32_16x16x32_bf16(al[mt], bh, acc[mt][nt], 0, 0, 0);
        acc[mt][nt] = __builtin_amdgcn_mfma_f32_16x16x32_bf16(ah[mt], bl, acc[mt][nt], 0, 0, 0);
      }
    }
  }
  #pragma unroll
  for (int nt = 0; nt < 4; nt++) {
    int n = nc0 + nt*16 + l15;
    float bb = bias[n];
    #pragma unroll
    for (int mt = 0; mt < 2; mt++)
      #pragma unroll
      for (int i = 0; i < 4; i++) {
        long row = r0 + mt*16 + q*4 + i;
        if (row < M) C[row*128 + n] = acc[mt][nt][i] + bb;
      }
  }
}

// ---------------- msg slice 0: x += seg(ds). 8 nodes/block, value prefetch ----------------
__global__ void __launch_bounds__(128) msg0_kernel(
    const float* __restrict__ phiS, float* __restrict__ x,
    const int* __restrict__ srcs, const float4* __restrict__ eg1,
    const int* __restrict__ indptr,
    const float* __restrict__ Wf_l, const float* __restrict__ bf_l) {
  int d = threadIdx.x;
  float wf[NB_];
  #pragma unroll
  for (int k = 0; k < NB_; k++) wf[k] = Wf_l[k*D3 + d];
  float bfv = bf_l[d];
  int n0 = blockIdx.x * 8;
  for (int j = 0; j < 8; j++) {
    int n = n0 + j;
    int t = indptr[n], end = indptr[n+1];
    float xacc = 0.f;
    float4 g1C = {}; float p1C = 0.f;
    if (t < end) {
      int s0 = srcs[t]; g1C = eg1[t]; p1C = phiS[(long)s0*DD + d];
    }
    for (; t < end; t++) {
      float4 g = g1C; float p1 = p1C;
      if (t + 1 < end) {
        int sN = srcs[t+1]; g1C = eg1[t+1]; p1C = phiS[(long)sN*DD + d];
      }
      float c2 = 2.0f * g.y;
      float rkm1 = 0.f, rk = g.x, dot = 0.f;
      #pragma unroll
      for (int k = 0; k < NB_; k++) {
        dot = fmaf(rk, wf[k], dot);
        float rn = fmaf(c2, rk, -rkm1);
        rkm1 = rk; rk = rn;
      }
      xacc = fmaf(p1, bfv*g.z + g.w*dot, xacc);
    }
    x[(long)n*DD + d] += xacc;
  }
}

// ---------------- msg slices 1+2: vB = vA + seg(dv1*dir + dv2*v[src]) (plane layout) ----------------
__global__ void __launch_bounds__(128) msg12_kernel(
    const float* __restrict__ phi1, const float* __restrict__ phi2,
    const float* __restrict__ vA, float* __restrict__ vB,
    const int* __restrict__ srcs, const float4* __restrict__ eg1,
    const float4* __restrict__ eg2, const int* __restrict__ indptr,
    const float* __restrict__ Wf_l, const float* __restrict__ bf_l) {
  const long NND = (long)NN*DD;
  int d = threadIdx.x;
  float wf1[NB_], wf2[NB_];
  #pragma unroll
  for (int k = 0; k < NB_; k++) {
    wf1[k] = Wf_l[k*D3 + DD + d];
    wf2[k] = Wf_l[k*D3 + 2*DD + d];
  }
  float bf1 = bf_l[DD + d], bf2 = bf_l[2*DD + d];
  int n0 = blockIdx.x * 8;
  for (int j = 0; j < 8; j++) {
    int n = n0 + j;
    int t = indptr[n], end = indptr[n+1];
    float a0 = 0.f, a1 = 0.f, a2 = 0.f;
    float4 g1C = {}, g2C = {};
    float p1C = 0.f, p2C = 0.f, w0C = 0.f, w1C = 0.f, w2C = 0.f;
    if (t < end) {
      int s0 = srcs[t]; g1C = eg1[t]; g2C = eg2[t];
      long b = (long)s0*DD + d;
      p1C = phi1[b]; p2C = phi2[b];
      w0C = vA[b]; w1C = vA[NND + b]; w2C = vA[2*NND + b];
    }
    for (; t < end; t++) {
      float4 g = g1C, dv = g2C;
      float p1 = p1C, p2 = p2C, w0 = w0C, w1 = w1C, w2 = w2C;
      if (t + 1 < end) {
        int sN = srcs[t+1]; g1C = eg1[t+1]; g2C = eg2[t+1];
        long b = (long)sN*DD + d;
        p1C = phi1[b]; p2C = phi2[b];
        w0C = vA[b]; w1C = vA[NND + b]; w2C = vA[2*NND + b];
      }
      float c2 = 2.0f * g.y;
      float rkm1 = 0.f, rk = g.x, dot1 = 0.f, dot2 = 0.f;
      #pragma unroll
      for (int k = 0; k < NB_; k++) {
        dot1 = fmaf(rk, wf1[k], dot1);
        dot2 = fmaf(rk, wf2[k], dot2);
        float rn = fmaf(c2, rk, -rkm1);
        rkm1 = rk; rk = rn;
      }
      float m1 = p1 * (bf1*g.z + g.w*dot1);
      float m2 = p2 * (bf2*g.z + g.w*dot2);
      a0 = fmaf(m1, dv.x, fmaf(m2, w0, a0));
      a1 = fmaf(m1, dv.y, fmaf(m2, w1, a1));
      a2 = fmaf(m1, dv.z, fmaf(m2, w2, a2));
    }
    long b = (long)n*DD + d;
    vB[b]         = vA[b]         + a0;
    vB[NND + b]   = vA[NND + b]   + a1;
    vB[2*NND + b] = vA[2*NND + b] + a2;
  }
}

// ---------------- fused Uv/Vv/Vn/s + a-MLP + update (uva): 16 nodes/block ----------------
// v in plane layout [c][N][128]. M-tile = 16 nodes per channel, so the MFMA
// C-layout (row=node, col=d) is IDENTICAL for aU/aV, s, Vn^2, the GEMM2 gates,
// and the x/v update -> s, Vn^2, Uv all stay in registers. LDS = 26.1 KB.
__global__ void __launch_bounds__(256) uva_kernel(
    float* __restrict__ x, float* __restrict__ v,
    const short* __restrict__ Uth, const short* __restrict__ Utl,
    const short* __restrict__ Vth, const short* __restrict__ Vtl,
    const short* __restrict__ W1h, const short* __restrict__ W1l, const float* __restrict__ b1,
    const short* __restrict__ W2h, const short* __restrict__ W2l, const float* __restrict__ b2) {
  __shared__ float smem[16*268 + 16*140];             // 6528 floats = 26112 B
  float (*vs)[132]  = (float(*)[132])smem;            // [48][132] = 6336 floats (phase 1)
  float (*cat)[268] = (float(*)[268])smem;            // [16][268] (overlays vs)
  float (*t2s)[140] = (float(*)[140])(smem + 16*268); // [16][140]
  const long NND = (long)NN*DD;
  int tid = threadIdx.x;
  long nb = (long)blockIdx.x * 16;
  // load v tile: 48 rows = 3 planes x 16 nodes
  #pragma unroll
  for (int i = 0; i < 6; i++) {
    int lin = i*256 + tid;
    int r = lin >> 5, c4 = lin & 31;
    int c = r >> 4, nr = r & 15;
    *(float4*)&vs[r][c4*4] = *(const float4*)(v + (long)c*NND + (nb + nr)*DD + c4*4);
  }
  __syncthreads();
  int lane = tid & 63, wv = tid >> 6;
  int l15 = lane & 15, q = lane >> 4;
  // ---- phase 1: U & V projections, per channel ----
  v4f aU[3][2] = {}, aV[3][2] = {};
  #pragma unroll
  for (int s = 0; s < 4; s++) {
    v8s buh[2], bul[2], bvh[2], bvl[2];
    #pragma unroll
    for (int nt = 0; nt < 2; nt++) {
      int n = (2*wv + nt)*16 + l15;
      long boff = (long)n*128 + s*32 + q*8;
      buh[nt] = *(const v8s*)(Uth + boff);
      bul[nt] = *(const v8s*)(Utl + boff);
      bvh[nt] = *(const v8s*)(Vth + boff);
      bvl[nt] = *(const v8s*)(Vtl + boff);
    }
    #pragma unroll
    for (int c = 0; c < 3; c++) {
      const float* ap = &vs[c*16 + l15][s*32 + q*8];
      float4 f0 = *(const float4*)(ap);
      float4 f1 = *(const float4*)(ap + 4);
      v8s ah, al;
      SPLIT8(f0, f1, ah, al);
      #pragma unroll
      for (int nt = 0; nt < 2; nt++) {
        aU[c][nt] = __builtin_amdgcn_mfma_f32_16x16x32_bf16(ah, buh[nt], aU[c][nt], 0, 0, 0);
        aU[c][nt] = __builtin_amdgcn_mfma_f32_16x16x32_bf16(al, buh[nt], aU[c][nt], 0, 0, 0);
        aU[c][nt] = __builtin_amdgcn_mfma_f32_16x16x32_bf16(ah, bul[nt], aU[c][nt], 0, 0, 0);
        aV[c][nt] = __builtin_amdgcn_mfma_f32_16x16x32_bf16(ah, bvh[nt], aV[c][nt], 0, 0, 0);
        aV[c][nt] = __builtin_amdgcn_mfma_f32_16x16x32_bf16(al, bvh[nt], aV[c][nt], 0, 0, 0);
        aV[c][nt] = __builtin_amdgcn_mfma_f32_16x16x32_bf16(ah, bvl[nt], aV[c][nt], 0, 0, 0);
      }
    }
  }
  // ---- s and Vn^2 fully in-register (aV dies here) ----
  float sreg[2][4], vn2[2][4];
  #pragma unroll
  for (int nt = 0; nt < 2; nt++)
    #pragma unroll
    for (int i = 0; i < 4; i++) {
      sreg[nt][i] = aU[0][nt][i]*aV[0][nt][i] + aU[1][nt][i]*aV[1][nt][i] + aU[2][nt][i]*aV[2][nt][i];
      vn2[nt][i]  = aV[0][nt][i]*aV[0][nt][i] + aV[1][nt][i]*aV[1][nt][i] + aV[2][nt][i]*aV[2][nt][i];
    }
  __syncthreads();   // done reading vs
  // ---- build cat = [x | Vn] (overlays vs) ----
  #pragma unroll
  for (int i = 0; i < 2; i++) {
    int lin = i*256 + tid;
    int r = lin >> 5, c4 = lin & 31;
    *(float4*)&cat[r][c4*4] = *(const float4*)(x + (nb + r)*DD + c4*4);
  }
  #pragma unroll
  for (int nt = 0; nt < 2; nt++)
    #pragma unroll
    for (int i = 0; i < 4; i++)
      cat[q*4 + i][128 + (2*wv + nt)*16 + l15] = sqrtf(vn2[nt][i] + 1e-8f);
  __syncthreads();
  // ---- GEMM1: t2 = silu(cat @ Wu1 + b1), K=256, N=128 ----
  {
    v4f acc[2] = {};
    #pragma unroll
    for (int s = 0; s < 8; s++) {
      const float* ap = &cat[l15][s*32 + q*8];
      float4 f0 = *(const float4*)(ap);
      float4 f1 = *(const float4*)(ap + 4);
      v8s ah, al;
      SPLIT8(f0, f1, ah, al);
      #pragma unroll
      for (int nt = 0; nt < 2; nt++) {
        int n = (2*wv + nt)*16 + l15;
        v8s bh = *(const v8s*)(W1h + (long)n*256 + s*32 + q*8);
        v8s bl = *(const v8s*)(W1l + (long)n*256 + s*32 + q*8);
        acc[nt] = __builtin_amdgcn_mfma_f32_16x16x32_bf16(ah, bh, acc[nt], 0, 0, 0);
        acc[nt] = __builtin_amdgcn_mfma_f32_16x16x32_bf16(al, bh, acc[nt], 0, 0, 0);
        acc[nt] = __builtin_amdgcn_mfma_f32_16x16x32_bf16(ah, bl, acc[nt], 0, 0, 0);
      }
    }
    #pragma unroll
    for (int nt = 0; nt < 2; nt++) {
      int n = (2*wv + nt)*16 + l15;
      float bb = b1[n];
      #pragma unroll
      for (int i = 0; i < 4; i++)
        t2s[q*4 + i][n] = silu_f(acc[nt][i] + bb);
    }
  }
  __syncthreads();
  // ---- GEMM2 (+ v-old prefetch) + in-register update ----
  {
    float vold[2][4][3];
    #pragma unroll
    for (int p = 0; p < 2; p++) {
      int d = (2*wv + p)*16 + l15;
      #pragma unroll
      for (int i = 0; i < 4; i++) {
        long row = nb + q*4 + i;
        #pragma unroll
        for (int c = 0; c < 3; c++) vold[p][i][c] = v[(long)c*NND + row*DD + d];
      }
    }
    v4f acc[6] = {};
    #pragma unroll
    for (int s = 0; s < 4; s++) {
      const float* ap = &t2s[l15][s*32 + q*8];
      float4 f0 = *(const float4*)(ap);
      float4 f1 = *(const float4*)(ap + 4);
      v8s ah, al;
      SPLIT8(f0, f1, ah, al);
      #pragma unroll
      for (int g = 0; g < 6; g++) {
        int nt = (g >> 1)*8 + 2*wv + (g & 1);
        int n = nt*16 + l15;                 // 0..383
        v8s bh = *(const v8s*)(W2h + (long)n*128 + s*32 + q*8);
        v8s bl = *(const v8s*)(W2l + (long)n*128 + s*32 + q*8);
        acc[g] = __builtin_amdgcn_mfma_f32_16x16x32_bf16(ah, bh, acc[g], 0, 0, 0);
        acc[g] = __builtin_amdgcn_mfma_f32_16x16x32_bf16(al, bh, acc[g], 0, 0, 0);
        acc[g] = __builtin_amdgcn_mfma_f32_16x16x32_bf16(ah, bl, acc[g], 0, 0, 0);
      }
    }
    #pragma unroll
    for (int p = 0; p < 2; p++) {
      int d = (2*wv + p)*16 + l15;           // 0..127, matches aU/sreg col
      float bavv = b2[d], basv = b2[128 + d], bass = b2[256 + d];
      #pragma unroll
      for (int i = 0; i < 4; i++) {
        int lr = q*4 + i;
        long row = nb + lr;
        float avv = acc[p][i]     + bavv;
        float asv = acc[2 + p][i] + basv;
        float ass = acc[4 + p][i] + bass;
        x[row*DD + d] = cat[lr][d] + ass + asv * sreg[p][i];
        #pragma unroll
        for (int c = 0; c < 3; c++)
          v[(long)c*NND + row*DD + d] = fmaf(avv, aU[c][p][i], vold[p][i][c]);
      }
    }
  }
}

// ---------------- output head + segment sum: 4 nodes/block, LDS-staged x ----------------
__global__ void __launch_bounds__(256) out_kernel(
    const float* __restrict__ x, const float* __restrict__ Wo1,
    const float* __restrict__ bo1, const float* __restrict__ Wo2,
    const float* __restrict__ bo2, const int* __restrict__ batch,
    float* __restrict__ out) {
  __shared__ float xs[4][132];
  int tid = threadIdx.x;
  long n0 = (long)blockIdx.x * 4;
  if (tid < 128) {
    int r = tid >> 5, c4 = tid & 31;
    *(float4*)&xs[r][c4*4] = *(const float4*)(x + (n0 + r)*128 + c4*4);
  }
  __syncthreads();
  int wv = tid >> 6, t = tid & 63;
  float acc = bo1[t];
  #pragma unroll 16
  for (int k = 0; k < DD; k++) acc = fmaf(xs[wv][k], Wo1[k*HH + t], acc);
  float val = silu_f(acc) * Wo2[t];
  #pragma unroll
  for (int off = 32; off > 0; off >>= 1) val += __shfl_down(val, off);
  if (t == 0) atomicAdd(&out[batch[n0 + wv]], val + bo2[0]);
}

// ---------------- launcher ----------------
extern "C" void kernel_launch(void* const* d_in, const int* in_sizes, int n_in,
                              void* d_out, int out_size, void* d_ws, size_t ws_size,
                              hipStream_t stream) {
  const int*   at_no = (const int*)d_in[0];
  const float* pos   = (const float*)d_in[1];
  const int*   ei    = (const int*)d_in[2];
  const int*   batch = (const int*)d_in[3];
  const float* emb   = (const float*)d_in[4];
  const float* Wf    = (const float*)d_in[5];
  const float* bfp   = (const float*)d_in[6];
  const float* Wm1   = (const float*)d_in[7];
  const float* bm1   = (const float*)d_in[8];
  const float* Wm2   = (const float*)d_in[9];
  const float* bm2   = (const float*)d_in[10];
  const float* U     = (const float*)d_in[11];
  const float* V     = (const float*)d_in[12];
  const float* Wu1   = (const float*)d_in[13];
  const float* bu1   = (const float*)d_in[14];
  const float* Wu2   = (const float*)d_in[15];
  const float* bu2   = (const float*)d_in[16];
  const float* Wo1   = (const float*)d_in[17];
  const float* bo1   = (const float*)d_in[18];
  const float* Wo2   = (const float*)d_in[19];
  const float* bo2   = (const float*)d_in[20];
  float* out = (float*)d_out;

  char* w = (char*)d_ws;
  auto alloc = [&](size_t bytes) -> void* {
    void* p = (void*)w;
    w += (bytes + 255) & ~(size_t)255;
    return p;
  };
  float*  x      = (float*)alloc(sizeof(float)*(size_t)NN*DD);
  float*  v_a    = (float*)alloc(sizeof(float)*(size_t)NN*D3);   // plane layout [3][NN][DD]
  float*  v_b    = (float*)alloc(sizeof(float)*(size_t)NN*D3);
  float*  t1     = (float*)alloc(sizeof(float)*(size_t)NN*DD);   // phi slice 2 (in-place)
  float*  phiS   = (float*)alloc(sizeof(float)*(size_t)NN*DD);   // phi slices 0 / 1
  short*  wbh    = (short*)alloc(sizeof(short)*(size_t)3*LSZ);
  short*  wbl    = (short*)alloc(sizeof(short)*(size_t)3*LSZ);
  int*    srcs   = (int*)alloc(sizeof(int)*(size_t)NE);
  float4* eg1    = (float4*)alloc(sizeof(float4)*(size_t)NE);
  float4* eg2    = (float4*)alloc(sizeof(float4)*(size_t)NE);
  int*    indptr = (int*)alloc(sizeof(int)*((size_t)NN+1));
  int*    counts = (int*)alloc(sizeof(int)*(size_t)NN);

  if ((size_t)(w - (char*)d_ws) > ws_size) {   // diagnostic guard: zeros => ws too small
    zero_f_kernel<<<2, 256, 0, stream>>>(out, NG_);
    return;
  }

  zero_f_kernel<<<2048, 256, 0, stream>>>(v_a, (long)NN*D3);
  zero_f_kernel<<<2, 256, 0, stream>>>(out, NG_);
  zero_i_kernel<<<64, 256, 0, stream>>>(counts, NN);
  init_x_kernel<<<(NN*DD + 255)/256, 256, 0, stream>>>(at_no, emb, x);
  prep_w_kernel<<<(3*LSZ + 255)/256, 256, 0, stream>>>(Wm1, Wm2, U, V, Wu1, Wu2, wbh, wbl);
  hist_kernel<<<(NE + 255)/256, 256, 0, stream>>>(ei, pos, counts);
  scan_kernel<<<1, 1024, 0, stream>>>(counts, indptr, NN);
  zero_i_kernel<<<64, 256, 0, stream>>>(counts, NN);
  fill_kernel<<<(NE + 255)/256, 256, 0, stream>>>(ei, pos, indptr, counts, srcs, eg1, eg2);

  const int MB = (NN + 31) / 32;    // 1563
  float* vcur = v_a;
  float* vnext = v_b;
  for (int l = 0; l < 3; l++) {
    const float* Wf_l  = Wf  + (size_t)l*NB_*D3;
    const float* bf_l  = bfp + (size_t)l*D3;
    const float* bm1_l = bm1 + (size_t)l*DD;
    const float* bm2_l = bm2 + (size_t)l*D3;
    const float* bu1_l = bu1 + (size_t)l*DD;
    const float* bu2_l = bu2 + (size_t)l*D3;
    const short* Lh = wbh + (size_t)l*LSZ;
    const short* Ll = wbl + (size_t)l*LSZ;
    const short* Wm1h = Lh,          *Wm1L = Ll;
    const short* Wm2h = Lh + 16384,  *Wm2L = Ll + 16384;
    const short* Uh   = Lh + 65536,  *UL   = Ll + 65536;
    const short* Vh   = Lh + 81920,  *VL   = Ll + 81920;
    const short* Wu1h = Lh + 98304,  *Wu1L = Ll + 98304;
    const short* Wu2h = Lh + 131072, *Wu2L = Ll + 131072;

    // t1 = silu(x@Wm1 + bm1)
    mfma_gemm_kernel<true><<<MB, 256, 0, stream>>>(x, Wm1h, Wm1L, bm1_l, t1, NN);
    // slice 0 -> phiS, consume into x
    mfma_gemm_kernel<false><<<MB, 256, 0, stream>>>(t1, Wm2h, Wm2L, bm2_l, phiS, NN);
    msg0_kernel<<<NN/8, 128, 0, stream>>>(phiS, x, srcs, eg1, indptr, Wf_l, bf_l);
    // slices 1,2 in ONE pass over t1: slice1 -> phiS, slice2 -> t1 (in place)
    mfma_gemm_dual_kernel<<<MB, 256, 0, stream>>>(
        t1, Wm2h + 1*16384, Wm2L + 1*16384, Wm2h + 2*16384, Wm2L + 2*16384,
        bm2_l + DD, bm2_l + 2*DD, phiS, t1, NN);
    msg12_kernel<<<NN/8, 128, 0, stream>>>(phiS, t1, vcur, vnext, srcs, eg1, eg2, indptr, Wf_l, bf_l);
    // fused Uv/Vv/Vn/s + a-MLP + x,v update (all node-local state in registers)
    uva_kernel<<<NN/16, 256, 0, stream>>>(x, vnext, Uh, UL, Vh, VL,
                                          Wu1h, Wu1L, bu1_l, Wu2h, Wu2L, bu2_l);

    float* tmp = vcur; vcur = vnext; vnext = tmp;
  }

  out_kernel<<<NN/4, 256, 0, stream>>>(x, Wo1, bo1, Wo2, bo2, batch, out);

  (void)in_sizes; (void)n_in; (void)out_size; (void)ws_size;
}

// Round 9
// 1525.229 us; speedup vs baseline: 1.6385x; 1.0424x over previous
//
#include <hip/hip_runtime.h>
#include <math.h>

#define NN 50000
#define NE 600000
#define ECAP 230000  // capacity for filtered edges (actual ~183K)
#define DD 128
#define D3 384
#define NB_ 20
#define HH 64
#define NG_ 512
#define LSZ 180224   // shorts per layer of transposed-bf16 weights

typedef short v8s __attribute__((ext_vector_type(8)));
typedef float v4f __attribute__((ext_vector_type(4)));

__device__ __forceinline__ float silu_f(float z) { return z / (1.0f + expf(-z)); }

__device__ __forceinline__ short f2bf(float f) {
  unsigned u = __float_as_uint(f);
  u += 0x7FFF + ((u >> 16) & 1);          // RNE
  return (short)(u >> 16);
}
__device__ __forceinline__ float bf2f(short s) {
  return __uint_as_float(((unsigned)(unsigned short)s) << 16);
}
__device__ __forceinline__ void split2(float x, short& h, short& l) {
  h = f2bf(x);
  l = f2bf(x - bf2f(h));
}
#define SPLIT8(f0, f1, ah, al) { short h,l; \
  split2(f0.x,h,l); ah[0]=h; al[0]=l;  split2(f0.y,h,l); ah[1]=h; al[1]=l; \
  split2(f0.z,h,l); ah[2]=h; al[2]=l;  split2(f0.w,h,l); ah[3]=h; al[3]=l; \
  split2(f1.x,h,l); ah[4]=h; al[4]=l;  split2(f1.y,h,l); ah[5]=h; al[5]=l; \
  split2(f1.z,h,l); ah[6]=h; al[6]=l;  split2(f1.w,h,l); ah[7]=h; al[7]=l; }
// 3-term Markidis split: acc += ah@bh + al@bh + ah@bl   (proven: absmax 4.3e9)
#define MFMA3(acc, ah, al, bh, bl) \
  acc = __builtin_amdgcn_mfma_f32_16x16x32_bf16(ah, bh, acc, 0, 0, 0); \
  acc = __builtin_amdgcn_mfma_f32_16x16x32_bf16(al, bh, acc, 0, 0, 0); \
  acc = __builtin_amdgcn_mfma_f32_16x16x32_bf16(ah, bl, acc, 0, 0, 0);

// ---------------- utility ----------------
__global__ void zero_f_kernel(float* __restrict__ p, long n) {
  long i = (long)blockIdx.x * blockDim.x + threadIdx.x;
  long s = (long)gridDim.x * blockDim.x;
  for (; i < n; i += s) p[i] = 0.0f;
}

__global__ void zero_i_kernel(int* __restrict__ p, long n) {
  long i = (long)blockIdx.x * blockDim.x + threadIdx.x;
  long s = (long)gridDim.x * blockDim.x;
  for (; i < n; i += s) p[i] = 0;
}

__global__ void init_x_kernel(const int* __restrict__ at_no, const float* __restrict__ emb,
                              float* __restrict__ x) {
  int i = blockIdx.x * blockDim.x + threadIdx.x;
  if (i >= NN * DD) return;
  x[i] = emb[at_no[i >> 7] * DD + (i & 127)];
}

// ---------------- weight prep: fp32 [K][N] -> transposed bf16 hi/lo [N][K] ----------------
__global__ void prep_w_kernel(const float* __restrict__ Wm1, const float* __restrict__ Wm2,
                              const float* __restrict__ U, const float* __restrict__ V,
                              const float* __restrict__ Wu1, const float* __restrict__ Wu2,
                              short* __restrict__ hi, short* __restrict__ lo) {
  int idx = blockIdx.x * 256 + threadIdx.x;
  if (idx >= 3 * LSZ) return;
  int l = idx / LSZ, r = idx % LSZ;
  const float* src; int K, N, nk;
  if (r < 16384)       { src = Wm1 + (size_t)l*16384; K = 128; N = 128; nk = r; }
  else if (r < 65536)  { src = Wm2 + (size_t)l*49152; K = 128; N = 384; nk = r - 16384; }
  else if (r < 81920)  { src = U   + (size_t)l*16384; K = 128; N = 128; nk = r - 65536; }
  else if (r < 98304)  { src = V   + (size_t)l*16384; K = 128; N = 128; nk = r - 81920; }
  else if (r < 131072) { src = Wu1 + (size_t)l*32768; K = 256; N = 128; nk = r - 98304; }
  else                 { src = Wu2 + (size_t)l*49152; K = 128; N = 384; nk = r - 131072; }
  int n = nk / K, k = nk - n * K;
  float xx = src[(size_t)k * N + n];
  short h = f2bf(xx);
  hi[idx] = h;
  lo[idx] = f2bf(xx - bf2f(h));
}

// ---------------- CSR build (dst-sorted), filtering dist>=CUTOFF edges ----------------
__global__ void hist_kernel(const int* __restrict__ ei, const float* __restrict__ pos,
                            int* __restrict__ counts) {
  int e = blockIdx.x * blockDim.x + threadIdx.x;
  if (e >= NE) return;
  int s = ei[e], d = ei[NE + e];
  float dx = pos[3*d]   - pos[3*s];
  float dy = pos[3*d+1] - pos[3*s+1];
  float dz = pos[3*d+2] - pos[3*s+2];
  float d2 = dx*dx + dy*dy + dz*dz + 1e-12f;
  if (d2 < 25.0f) atomicAdd(&counts[d], 1);
}

__global__ void scan_kernel(const int* __restrict__ counts, int* __restrict__ indptr, int n) {
  __shared__ int sm[1024];
  __shared__ int carry_s;
  if (threadIdx.x == 0) carry_s = 0;
  __syncthreads();
  for (int start = 0; start < n; start += 1024) {
    int i = start + (int)threadIdx.x;
    int val = (i < n) ? counts[i] : 0;
    sm[threadIdx.x] = val;
    __syncthreads();
    for (int off = 1; off < 1024; off <<= 1) {
      int t = (threadIdx.x >= (unsigned)off) ? sm[threadIdx.x - off] : 0;
      __syncthreads();
      sm[threadIdx.x] += t;
      __syncthreads();
    }
    int c = carry_s;
    if (i < n) indptr[i] = c + sm[threadIdx.x] - val;
    __syncthreads();
    if (threadIdx.x == 0) carry_s = c + sm[1023];
    __syncthreads();
  }
  if (threadIdx.x == 0) indptr[n] = carry_s;
}

__global__ void fill_kernel(const int* __restrict__ ei, const float* __restrict__ pos,
                            const int* __restrict__ indptr, int* __restrict__ cursor,
                            int* __restrict__ srcs, float4* __restrict__ eg1,
                            float4* __restrict__ eg2) {
  int e = blockIdx.x * blockDim.x + threadIdx.x;
  if (e >= NE) return;
  int s = ei[e], d = ei[NE + e];
  float dx = pos[3*d]   - pos[3*s];
  float dy = pos[3*d+1] - pos[3*s+1];
  float dz = pos[3*d+2] - pos[3*s+2];
  float d2 = dx*dx + dy*dy + dz*dz + 1e-12f;
  if (d2 < 25.0f) {
    int p = atomicAdd(&cursor[d], 1);
    int slot = indptr[d] + p;
    float dist = sqrtf(d2);
    float inv = 1.0f / dist;
    float wang = 0.62831853071795864769f * dist;   // pi*dist/CUTOFF
    float s1 = __sinf(wang), c1 = __cosf(wang);
    float fc = 0.5f * (c1 + 1.0f);
    srcs[slot] = s;
    eg1[slot] = make_float4(s1, c1, fc, fc * inv);
    eg2[slot] = make_float4(dx * inv, dy * inv, dz * inv, 0.0f);
  }
}

// ---------------- MFMA 3-term GEMM: C[M,128] = op(A[M,128] @ B + bias) ----------------
template<bool SILU>
__global__ void __launch_bounds__(256) mfma_gemm_kernel(
    const float* A, const short* __restrict__ Bth, const short* __restrict__ Btl,
    const float* __restrict__ bias, float* C, int M) {
  __shared__ float As[32][132];
  int tid = threadIdx.x;
  long r0 = (long)blockIdx.x * 32;
  #pragma unroll
  for (int i = 0; i < 4; i++) {
    int lin = i*256 + tid;
    int r = lin >> 5, c4 = lin & 31;
    long row = r0 + r; if (row >= M) row = M - 1;
    *(float4*)&As[r][c4*4] = *(const float4*)(A + row*128 + c4*4);
  }
  __syncthreads();
  int lane = tid & 63, wv = tid >> 6;
  int l15 = lane & 15, q = lane >> 4;
  v4f acc[2][2] = {};
  #pragma unroll
  for (int s = 0; s < 4; s++) {
    v8s ah[2], al[2];
    #pragma unroll
    for (int mt = 0; mt < 2; mt++) {
      const float* ap = &As[mt*16 + l15][s*32 + q*8];
      float4 f0 = *(const float4*)(ap);
      float4 f1 = *(const float4*)(ap + 4);
      SPLIT8(f0, f1, ah[mt], al[mt]);
    }
    #pragma unroll
    for (int nt = 0; nt < 2; nt++) {
      int n = (2*wv + nt)*16 + l15;
      v8s bh = *(const v8s*)(Bth + (long)n*128 + s*32 + q*8);
      v8s bl = *(const v8s*)(Btl + (long)n*128 + s*32 + q*8);
      #pragma unroll
      for (int mt = 0; mt < 2; mt++) { MFMA3(acc[mt][nt], ah[mt], al[mt], bh, bl); }
    }
  }
  #pragma unroll
  for (int nt = 0; nt < 2; nt++) {
    int n = (2*wv + nt)*16 + l15;
    float bb = bias[n];
    #pragma unroll
    for (int mt = 0; mt < 2; mt++)
      #pragma unroll
      for (int i = 0; i < 4; i++) {
        long row = r0 + mt*16 + q*4 + i;
        if (row < M) {
          float val = acc[mt][nt][i] + bb;
          if constexpr (SILU) val = silu_f(val);
          C[row*128 + n] = val;
        }
      }
  }
}

// ---------------- tri-slice phi GEMM: C[M,384] = A[M,128] @ Wm2 + bm2 ----------------
// slice0 -> C0, slice1 -> C1, slice2 -> C2 (C2==A in-place safe: block owns its rows)
__global__ void __launch_bounds__(256) mfma_gemm_phi_kernel(
    const float* A, const short* __restrict__ Bth, const short* __restrict__ Btl,
    const float* __restrict__ bias,
    float* __restrict__ C0, float* __restrict__ C1, float* C2, int M) {
  __shared__ float As[32][132];
  int tid = threadIdx.x;
  long r0 = (long)blockIdx.x * 32;
  #pragma unroll
  for (int i = 0; i < 4; i++) {
    int lin = i*256 + tid;
    int r = lin >> 5, c4 = lin & 31;
    long row = r0 + r; if (row >= M) row = M - 1;
    *(float4*)&As[r][c4*4] = *(const float4*)(A + row*128 + c4*4);
  }
  __syncthreads();
  int lane = tid & 63, wv = tid >> 6;
  int l15 = lane & 15, q = lane >> 4;
  v4f acc[2][6] = {};
  #pragma unroll
  for (int s = 0; s < 4; s++) {
    v8s ah[2], al[2];
    #pragma unroll
    for (int mt = 0; mt < 2; mt++) {
      const float* ap = &As[mt*16 + l15][s*32 + q*8];
      float4 f0 = *(const float4*)(ap);
      float4 f1 = *(const float4*)(ap + 4);
      SPLIT8(f0, f1, ah[mt], al[mt]);
    }
    #pragma unroll
    for (int g = 0; g < 6; g++) {
      int n = (wv*6 + g)*16 + l15;           // 0..383
      v8s bh = *(const v8s*)(Bth + (long)n*128 + s*32 + q*8);
      v8s bl = *(const v8s*)(Btl + (long)n*128 + s*32 + q*8);
      #pragma unroll
      for (int mt = 0; mt < 2; mt++) { MFMA3(acc[mt][g], ah[mt], al[mt], bh, bl); }
    }
  }
  #pragma unroll
  for (int g = 0; g < 6; g++) {
    int n = (wv*6 + g)*16 + l15;
    int sl = n >> 7, col = n & 127;          // slice uniform per (wv,g)
    float* C = (sl == 0) ? C0 : (sl == 1) ? C1 : C2;
    float bb = bias[n];
    #pragma unroll
    for (int mt = 0; mt < 2; mt++)
      #pragma unroll
      for (int i = 0; i < 4; i++) {
        long row = r0 + mt*16 + q*4 + i;
        if (row < M) C[row*128 + col] = acc[mt][g][i] + bb;
      }
  }
}

// ---------------- merged message pass: all 3 slices, one edge sweep ----------------
// x += seg(phi0*f0); vB = vA + seg(phi1*f1*dir + phi2*f2*v[src])   (plane layout)
__global__ void __launch_bounds__(128) msg012_kernel(
    const float* __restrict__ phi0, const float* __restrict__ phi1,
    const float* __restrict__ phi2, const float* __restrict__ vA,
    float* __restrict__ vB, float* __restrict__ x,
    const int* __restrict__ srcs, const float4* __restrict__ eg1,
    const float4* __restrict__ eg2, const int* __restrict__ indptr,
    const float* __restrict__ Wf_l, const float* __restrict__ bf_l) {
  const long NND = (long)NN*DD;
  int d = threadIdx.x;
  float wf0[NB_], wf1[NB_], wf2[NB_];
  #pragma unroll
  for (int k = 0; k < NB_; k++) {
    wf0[k] = Wf_l[k*D3 + d];
    wf1[k] = Wf_l[k*D3 + DD + d];
    wf2[k] = Wf_l[k*D3 + 2*DD + d];
  }
  float bf0 = bf_l[d], bf1 = bf_l[DD + d], bf2 = bf_l[2*DD + d];
  int n0 = blockIdx.x * 8;
  for (int j = 0; j < 8; j++) {
    int n = n0 + j;
    int t = indptr[n], end = indptr[n+1];
    float xacc = 0.f, a0 = 0.f, a1 = 0.f, a2 = 0.f;
    float4 g1C = {}, g2C = {};
    float p0C = 0.f, p1C = 0.f, p2C = 0.f, w0C = 0.f, w1C = 0.f, w2C = 0.f;
    if (t < end) {
      int s0 = srcs[t]; g1C = eg1[t]; g2C = eg2[t];
      long b = (long)s0*DD + d;
      p0C = phi0[b]; p1C = phi1[b]; p2C = phi2[b];
      w0C = vA[b]; w1C = vA[NND + b]; w2C = vA[2*NND + b];
    }
    for (; t < end; t++) {
      float4 g = g1C, dv = g2C;
      float p0 = p0C, p1 = p1C, p2 = p2C, w0 = w0C, w1 = w1C, w2 = w2C;
      if (t + 1 < end) {
        int sN = srcs[t+1]; g1C = eg1[t+1]; g2C = eg2[t+1];
        long b = (long)sN*DD + d;
        p0C = phi0[b]; p1C = phi1[b]; p2C = phi2[b];
        w0C = vA[b]; w1C = vA[NND + b]; w2C = vA[2*NND + b];
      }
      float c2 = 2.0f * g.y;
      float rkm1 = 0.f, rk = g.x, dot0 = 0.f, dot1 = 0.f, dot2 = 0.f;
      #pragma unroll
      for (int k = 0; k < NB_; k++) {
        dot0 = fmaf(rk, wf0[k], dot0);
        dot1 = fmaf(rk, wf1[k], dot1);
        dot2 = fmaf(rk, wf2[k], dot2);
        float rn = fmaf(c2, rk, -rkm1);
        rkm1 = rk; rk = rn;
      }
      xacc = fmaf(p0, bf0*g.z + g.w*dot0, xacc);
      float m1 = p1 * (bf1*g.z + g.w*dot1);
      float m2 = p2 * (bf2*g.z + g.w*dot2);
      a0 = fmaf(m1, dv.x, fmaf(m2, w0, a0));
      a1 = fmaf(m1, dv.y, fmaf(m2, w1, a1));
      a2 = fmaf(m1, dv.z, fmaf(m2, w2, a2));
    }
    long b = (long)n*DD + d;
    x[b] += xacc;
    vB[b]         = vA[b]         + a0;
    vB[NND + b]   = vA[NND + b]   + a1;
    vB[2*NND + b] = vA[2*NND + b] + a2;
  }
}

// ---------------- fused Uv/Vv/Vn/s + a-MLP + update (uva): 16 nodes/block ----------------
// v in plane layout [c][N][128]; node-local state (s, Vn^2, Uv) in registers.
__global__ void __launch_bounds__(256) uva_kernel(
    float* __restrict__ x, float* __restrict__ v,
    const short* __restrict__ Uth, const short* __restrict__ Utl,
    const short* __restrict__ Vth, const short* __restrict__ Vtl,
    const short* __restrict__ W1h, const short* __restrict__ W1l, const float* __restrict__ b1,
    const short* __restrict__ W2h, const short* __restrict__ W2l, const float* __restrict__ b2) {
  __shared__ float smem[16*268 + 16*140];             // 26112 B
  float (*vs)[132]  = (float(*)[132])smem;            // [48][132] (phase 1)
  float (*cat)[268] = (float(*)[268])smem;            // [16][268] (overlays vs)
  float (*t2s)[140] = (float(*)[140])(smem + 16*268); // [16][140]
  const long NND = (long)NN*DD;
  int tid = threadIdx.x;
  long nb = (long)blockIdx.x * 16;
  #pragma unroll
  for (int i = 0; i < 6; i++) {
    int lin = i*256 + tid;
    int r = lin >> 5, c4 = lin & 31;
    int c = r >> 4, nr = r & 15;
    *(float4*)&vs[r][c4*4] = *(const float4*)(v + (long)c*NND + (nb + nr)*DD + c4*4);
  }
  __syncthreads();
  int lane = tid & 63, wv = tid >> 6;
  int l15 = lane & 15, q = lane >> 4;
  // ---- phase 1: U & V projections, per channel ----
  v4f aU[3][2] = {}, aV[3][2] = {};
  #pragma unroll
  for (int s = 0; s < 4; s++) {
    v8s buh[2], bul[2], bvh[2], bvl[2];
    #pragma unroll
    for (int nt = 0; nt < 2; nt++) {
      int n = (2*wv + nt)*16 + l15;
      long boff = (long)n*128 + s*32 + q*8;
      buh[nt] = *(const v8s*)(Uth + boff);
      bul[nt] = *(const v8s*)(Utl + boff);
      bvh[nt] = *(const v8s*)(Vth + boff);
      bvl[nt] = *(const v8s*)(Vtl + boff);
    }
    #pragma unroll
    for (int c = 0; c < 3; c++) {
      const float* ap = &vs[c*16 + l15][s*32 + q*8];
      float4 f0 = *(const float4*)(ap);
      float4 f1 = *(const float4*)(ap + 4);
      v8s ah, al;
      SPLIT8(f0, f1, ah, al);
      #pragma unroll
      for (int nt = 0; nt < 2; nt++) {
        MFMA3(aU[c][nt], ah, al, buh[nt], bul[nt]);
        MFMA3(aV[c][nt], ah, al, bvh[nt], bvl[nt]);
      }
    }
  }
  float sreg[2][4], vn2[2][4];
  #pragma unroll
  for (int nt = 0; nt < 2; nt++)
    #pragma unroll
    for (int i = 0; i < 4; i++) {
      sreg[nt][i] = aU[0][nt][i]*aV[0][nt][i] + aU[1][nt][i]*aV[1][nt][i] + aU[2][nt][i]*aV[2][nt][i];
      vn2[nt][i]  = aV[0][nt][i]*aV[0][nt][i] + aV[1][nt][i]*aV[1][nt][i] + aV[2][nt][i]*aV[2][nt][i];
    }
  __syncthreads();
  // ---- build cat = [x | Vn] ----
  #pragma unroll
  for (int i = 0; i < 2; i++) {
    int lin = i*256 + tid;
    int r = lin >> 5, c4 = lin & 31;
    *(float4*)&cat[r][c4*4] = *(const float4*)(x + (nb + r)*DD + c4*4);
  }
  #pragma unroll
  for (int nt = 0; nt < 2; nt++)
    #pragma unroll
    for (int i = 0; i < 4; i++)
      cat[q*4 + i][128 + (2*wv + nt)*16 + l15] = sqrtf(vn2[nt][i] + 1e-8f);
  __syncthreads();
  // ---- GEMM1: t2 = silu(cat @ Wu1 + b1) ----
  {
    v4f acc[2] = {};
    #pragma unroll
    for (int s = 0; s < 8; s++) {
      const float* ap = &cat[l15][s*32 + q*8];
      float4 f0 = *(const float4*)(ap);
      float4 f1 = *(const float4*)(ap + 4);
      v8s ah, al;
      SPLIT8(f0, f1, ah, al);
      #pragma unroll
      for (int nt = 0; nt < 2; nt++) {
        int n = (2*wv + nt)*16 + l15;
        v8s bh = *(const v8s*)(W1h + (long)n*256 + s*32 + q*8);
        v8s bl = *(const v8s*)(W1l + (long)n*256 + s*32 + q*8);
        MFMA3(acc[nt], ah, al, bh, bl);
      }
    }
    #pragma unroll
    for (int nt = 0; nt < 2; nt++) {
      int n = (2*wv + nt)*16 + l15;
      float bb = b1[n];
      #pragma unroll
      for (int i = 0; i < 4; i++)
        t2s[q*4 + i][n] = silu_f(acc[nt][i] + bb);
    }
  }
  __syncthreads();
  // ---- GEMM2 (+ v-old prefetch) + in-register update ----
  {
    float vold[2][4][3];
    #pragma unroll
    for (int p = 0; p < 2; p++) {
      int d = (2*wv + p)*16 + l15;
      #pragma unroll
      for (int i = 0; i < 4; i++) {
        long row = nb + q*4 + i;
        #pragma unroll
        for (int c = 0; c < 3; c++) vold[p][i][c] = v[(long)c*NND + row*DD + d];
      }
    }
    v4f acc[6] = {};
    #pragma unroll
    for (int s = 0; s < 4; s++) {
      const float* ap = &t2s[l15][s*32 + q*8];
      float4 f0 = *(const float4*)(ap);
      float4 f1 = *(const float4*)(ap + 4);
      v8s ah, al;
      SPLIT8(f0, f1, ah, al);
      #pragma unroll
      for (int g = 0; g < 6; g++) {
        int nt = (g >> 1)*8 + 2*wv + (g & 1);
        int n = nt*16 + l15;                 // 0..383
        v8s bh = *(const v8s*)(W2h + (long)n*128 + s*32 + q*8);
        v8s bl = *(const v8s*)(W2l + (long)n*128 + s*32 + q*8);
        MFMA3(acc[g], ah, al, bh, bl);
      }
    }
    #pragma unroll
    for (int p = 0; p < 2; p++) {
      int d = (2*wv + p)*16 + l15;
      float bavv = b2[d], basv = b2[128 + d], bass = b2[256 + d];
      #pragma unroll
      for (int i = 0; i < 4; i++) {
        int lr = q*4 + i;
        long row = nb + lr;
        float avv = acc[p][i]     + bavv;
        float asv = acc[2 + p][i] + basv;
        float ass = acc[4 + p][i] + bass;
        x[row*DD + d] = cat[lr][d] + ass + asv * sreg[p][i];
        #pragma unroll
        for (int c = 0; c < 3; c++)
          v[(long)c*NND + row*DD + d] = fmaf(avv, aU[c][p][i], vold[p][i][c]);
      }
    }
  }
}

// ---------------- output head + segment sum: 4 nodes/block, LDS-staged x ----------------
__global__ void __launch_bounds__(256) out_kernel(
    const float* __restrict__ x, const float* __restrict__ Wo1,
    const float* __restrict__ bo1, const float* __restrict__ Wo2,
    const float* __restrict__ bo2, const int* __restrict__ batch,
    float* __restrict__ out) {
  __shared__ float xs[4][132];
  int tid = threadIdx.x;
  long n0 = (long)blockIdx.x * 4;
  if (tid < 128) {
    int r = tid >> 5, c4 = tid & 31;
    *(float4*)&xs[r][c4*4] = *(const float4*)(x + (n0 + r)*128 + c4*4);
  }
  __syncthreads();
  int wv = tid >> 6, t = tid & 63;
  float acc = bo1[t];
  #pragma unroll 16
  for (int k = 0; k < DD; k++) acc = fmaf(xs[wv][k], Wo1[k*HH + t], acc);
  float val = silu_f(acc) * Wo2[t];
  #pragma unroll
  for (int off = 32; off > 0; off >>= 1) val += __shfl_down(val, off);
  if (t == 0) atomicAdd(&out[batch[n0 + wv]], val + bo2[0]);
}

// ---------------- launcher ----------------
extern "C" void kernel_launch(void* const* d_in, const int* in_sizes, int n_in,
                              void* d_out, int out_size, void* d_ws, size_t ws_size,
                              hipStream_t stream) {
  const int*   at_no = (const int*)d_in[0];
  const float* pos   = (const float*)d_in[1];
  const int*   ei    = (const int*)d_in[2];
  const int*   batch = (const int*)d_in[3];
  const float* emb   = (const float*)d_in[4];
  const float* Wf    = (const float*)d_in[5];
  const float* bfp   = (const float*)d_in[6];
  const float* Wm1   = (const float*)d_in[7];
  const float* bm1   = (const float*)d_in[8];
  const float* Wm2   = (const float*)d_in[9];
  const float* bm2   = (const float*)d_in[10];
  const float* U     = (const float*)d_in[11];
  const float* V     = (const float*)d_in[12];
  const float* Wu1   = (const float*)d_in[13];
  const float* bu1   = (const float*)d_in[14];
  const float* Wu2   = (const float*)d_in[15];
  const float* bu2   = (const float*)d_in[16];
  const float* Wo1   = (const float*)d_in[17];
  const float* bo1   = (const float*)d_in[18];
  const float* Wo2   = (const float*)d_in[19];
  const float* bo2   = (const float*)d_in[20];
  float* out = (float*)d_out;

  char* w = (char*)d_ws;
  auto alloc = [&](size_t bytes) -> void* {
    void* p = (void*)w;
    w += (bytes + 255) & ~(size_t)255;
    return p;
  };
  float*  x      = (float*)alloc(sizeof(float)*(size_t)NN*DD);
  float*  v_a    = (float*)alloc(sizeof(float)*(size_t)NN*D3);   // plane layout [3][NN][DD]
  float*  v_b    = (float*)alloc(sizeof(float)*(size_t)NN*D3);
  float*  t1     = (float*)alloc(sizeof(float)*(size_t)NN*DD);   // phi slice 2 (in-place)
  float*  phiS   = (float*)alloc(sizeof(float)*(size_t)NN*DD);   // phi slice 1
  float*  phi0   = (float*)alloc(sizeof(float)*(size_t)NN*DD);   // phi slice 0
  short*  wbh    = (short*)alloc(sizeof(short)*(size_t)3*LSZ);   // bf16-hi weights
  short*  wbl    = (short*)alloc(sizeof(short)*(size_t)3*LSZ);   // bf16-lo weights
  int*    srcs   = (int*)alloc(sizeof(int)*(size_t)ECAP);
  float4* eg1    = (float4*)alloc(sizeof(float4)*(size_t)ECAP);
  float4* eg2    = (float4*)alloc(sizeof(float4)*(size_t)ECAP);
  int*    indptr = (int*)alloc(sizeof(int)*((size_t)NN+1));
  int*    counts = (int*)alloc(sizeof(int)*(size_t)NN);

  if ((size_t)(w - (char*)d_ws) > ws_size) {   // diagnostic guard: zeros => ws too small
    zero_f_kernel<<<2, 256, 0, stream>>>(out, NG_);
    return;
  }

  zero_f_kernel<<<2048, 256, 0, stream>>>(v_a, (long)NN*D3);
  zero_f_kernel<<<2, 256, 0, stream>>>(out, NG_);
  zero_i_kernel<<<64, 256, 0, stream>>>(counts, NN);
  init_x_kernel<<<(NN*DD + 255)/256, 256, 0, stream>>>(at_no, emb, x);
  prep_w_kernel<<<(3*LSZ + 255)/256, 256, 0, stream>>>(Wm1, Wm2, U, V, Wu1, Wu2, wbh, wbl);
  hist_kernel<<<(NE + 255)/256, 256, 0, stream>>>(ei, pos, counts);
  scan_kernel<<<1, 1024, 0, stream>>>(counts, indptr, NN);
  zero_i_kernel<<<64, 256, 0, stream>>>(counts, NN);
  fill_kernel<<<(NE + 255)/256, 256, 0, stream>>>(ei, pos, indptr, counts, srcs, eg1, eg2);

  const int MB = (NN + 31) / 32;    // 1563
  float* vcur = v_a;
  float* vnext = v_b;
  for (int l = 0; l < 3; l++) {
    const float* Wf_l  = Wf  + (size_t)l*NB_*D3;
    const float* bf_l  = bfp + (size_t)l*D3;
    const float* bm1_l = bm1 + (size_t)l*DD;
    const float* bm2_l = bm2 + (size_t)l*D3;
    const float* bu1_l = bu1 + (size_t)l*DD;
    const float* bu2_l = bu2 + (size_t)l*D3;
    const short* Lh = wbh + (size_t)l*LSZ;
    const short* Ll = wbl + (size_t)l*LSZ;
    const short* Wm1h = Lh,          *Wm1L = Ll;
    const short* Wm2h = Lh + 16384,  *Wm2L = Ll + 16384;
    const short* Uh   = Lh + 65536,  *UL   = Ll + 65536;
    const short* Vh   = Lh + 81920,  *VL   = Ll + 81920;
    const short* Wu1h = Lh + 98304,  *Wu1L = Ll + 98304;
    const short* Wu2h = Lh + 131072, *Wu2L = Ll + 131072;

    // t1 = silu(x@Wm1 + bm1)
    mfma_gemm_kernel<true><<<MB, 256, 0, stream>>>(x, Wm1h, Wm1L, bm1_l, t1, NN);
    // all 3 phi slices in one pass: slice0->phi0, slice1->phiS, slice2->t1 (in place)
    mfma_gemm_phi_kernel<<<MB, 256, 0, stream>>>(t1, Wm2h, Wm2L, bm2_l, phi0, phiS, t1, NN);
    // merged message pass (one edge sweep for x and v)
    msg012_kernel<<<NN/8, 128, 0, stream>>>(phi0, phiS, t1, vcur, vnext, x,
                                            srcs, eg1, eg2, indptr, Wf_l, bf_l);
    // fused Uv/Vv/Vn/s + a-MLP + x,v update
    uva_kernel<<<NN/16, 256, 0, stream>>>(x, vnext, Uh, UL, Vh, VL,
                                          Wu1h, Wu1L, bu1_l, Wu2h, Wu2L, bu2_l);

    float* tmp = vcur; vcur = vnext; vnext = tmp;
  }

  out_kernel<<<NN/4, 256, 0, stream>>>(x, Wo1, bo1, Wo2, bo2, batch, out);

  (void)in_sizes; (void)n_in; (void)out_size; (void)ws_size;
}

// Round 10
// 1516.059 us; speedup vs baseline: 1.6484x; 1.0060x over previous
//
#include <hip/hip_runtime.h>
#include <math.h>

#define NN 50000
#define NE 600000
#define ECAP 230000  // capacity for filtered edges (actual ~183K)
#define DD 128
#define D3 384
#define NB_ 20
#define HH 64
#define NG_ 512
#define LSZ 180224   // shorts per layer of transposed-bf16 weights

typedef short v8s __attribute__((ext_vector_type(8)));
typedef short v4sh __attribute__((ext_vector_type(4)));
typedef float v4f __attribute__((ext_vector_type(4)));

__device__ __forceinline__ float silu_f(float z) { return z / (1.0f + expf(-z)); }

__device__ __forceinline__ short f2bf(float f) {
  unsigned u = __float_as_uint(f);
  u += 0x7FFF + ((u >> 16) & 1);          // RNE
  return (short)(u >> 16);
}
__device__ __forceinline__ float bf2f(short s) {
  return __uint_as_float(((unsigned)(unsigned short)s) << 16);
}
__device__ __forceinline__ void split2(float x, short& h, short& l) {
  h = f2bf(x);
  l = f2bf(x - bf2f(h));
}
// split a float4 and store hi/lo as short4 (8B LDS stores)
__device__ __forceinline__ void split_store4(float4 f, short* hp, short* lp) {
  short h0,l0,h1,l1,h2,l2,h3,l3;
  split2(f.x,h0,l0); split2(f.y,h1,l1); split2(f.z,h2,l2); split2(f.w,h3,l3);
  v4sh hv = {h0,h1,h2,h3}, lv = {l0,l1,l2,l3};
  *(v4sh*)hp = hv; *(v4sh*)lp = lv;
}
// 3-term Markidis split: acc += ah@bh + al@bh + ah@bl   (proven: absmax 4.3e9)
#define MFMA3(acc, ah, al, bh, bl) \
  acc = __builtin_amdgcn_mfma_f32_16x16x32_bf16(ah, bh, acc, 0, 0, 0); \
  acc = __builtin_amdgcn_mfma_f32_16x16x32_bf16(al, bh, acc, 0, 0, 0); \
  acc = __builtin_amdgcn_mfma_f32_16x16x32_bf16(ah, bl, acc, 0, 0, 0);

// ---------------- utility ----------------
__global__ void zero_f_kernel(float* __restrict__ p, long n) {
  long i = (long)blockIdx.x * blockDim.x + threadIdx.x;
  long s = (long)gridDim.x * blockDim.x;
  for (; i < n; i += s) p[i] = 0.0f;
}

__global__ void zero_i_kernel(int* __restrict__ p, long n) {
  long i = (long)blockIdx.x * blockDim.x + threadIdx.x;
  long s = (long)gridDim.x * blockDim.x;
  for (; i < n; i += s) p[i] = 0;
}

__global__ void init_x_kernel(const int* __restrict__ at_no, const float* __restrict__ emb,
                              float* __restrict__ x) {
  int i = blockIdx.x * blockDim.x + threadIdx.x;
  if (i >= NN * DD) return;
  x[i] = emb[at_no[i >> 7] * DD + (i & 127)];
}

// ---------------- weight prep: fp32 [K][N] -> transposed bf16 hi/lo [N][K] ----------------
__global__ void prep_w_kernel(const float* __restrict__ Wm1, const float* __restrict__ Wm2,
                              const float* __restrict__ U, const float* __restrict__ V,
                              const float* __restrict__ Wu1, const float* __restrict__ Wu2,
                              short* __restrict__ hi, short* __restrict__ lo) {
  int idx = blockIdx.x * 256 + threadIdx.x;
  if (idx >= 3 * LSZ) return;
  int l = idx / LSZ, r = idx % LSZ;
  const float* src; int K, N, nk;
  if (r < 16384)       { src = Wm1 + (size_t)l*16384; K = 128; N = 128; nk = r; }
  else if (r < 65536)  { src = Wm2 + (size_t)l*49152; K = 128; N = 384; nk = r - 16384; }
  else if (r < 81920)  { src = U   + (size_t)l*16384; K = 128; N = 128; nk = r - 65536; }
  else if (r < 98304)  { src = V   + (size_t)l*16384; K = 128; N = 128; nk = r - 81920; }
  else if (r < 131072) { src = Wu1 + (size_t)l*32768; K = 256; N = 128; nk = r - 98304; }
  else                 { src = Wu2 + (size_t)l*49152; K = 128; N = 384; nk = r - 131072; }
  int n = nk / K, k = nk - n * K;
  float xx = src[(size_t)k * N + n];
  short h = f2bf(xx);
  hi[idx] = h;
  lo[idx] = f2bf(xx - bf2f(h));
}

// ---------------- CSR build (dst-sorted), filtering dist>=CUTOFF edges ----------------
__global__ void hist_kernel(const int* __restrict__ ei, const float* __restrict__ pos,
                            int* __restrict__ counts) {
  int e = blockIdx.x * blockDim.x + threadIdx.x;
  if (e >= NE) return;
  int s = ei[e], d = ei[NE + e];
  float dx = pos[3*d]   - pos[3*s];
  float dy = pos[3*d+1] - pos[3*s+1];
  float dz = pos[3*d+2] - pos[3*s+2];
  float d2 = dx*dx + dy*dy + dz*dz + 1e-12f;
  if (d2 < 25.0f) atomicAdd(&counts[d], 1);
}

__global__ void scan_kernel(const int* __restrict__ counts, int* __restrict__ indptr, int n) {
  __shared__ int sm[1024];
  __shared__ int carry_s;
  if (threadIdx.x == 0) carry_s = 0;
  __syncthreads();
  for (int start = 0; start < n; start += 1024) {
    int i = start + (int)threadIdx.x;
    int val = (i < n) ? counts[i] : 0;
    sm[threadIdx.x] = val;
    __syncthreads();
    for (int off = 1; off < 1024; off <<= 1) {
      int t = (threadIdx.x >= (unsigned)off) ? sm[threadIdx.x - off] : 0;
      __syncthreads();
      sm[threadIdx.x] += t;
      __syncthreads();
    }
    int c = carry_s;
    if (i < n) indptr[i] = c + sm[threadIdx.x] - val;
    __syncthreads();
    if (threadIdx.x == 0) carry_s = c + sm[1023];
    __syncthreads();
  }
  if (threadIdx.x == 0) indptr[n] = carry_s;
}

__global__ void fill_kernel(const int* __restrict__ ei, const float* __restrict__ pos,
                            const int* __restrict__ indptr, int* __restrict__ cursor,
                            int* __restrict__ srcs, float4* __restrict__ eg1,
                            float4* __restrict__ eg2) {
  int e = blockIdx.x * blockDim.x + threadIdx.x;
  if (e >= NE) return;
  int s = ei[e], d = ei[NE + e];
  float dx = pos[3*d]   - pos[3*s];
  float dy = pos[3*d+1] - pos[3*s+1];
  float dz = pos[3*d+2] - pos[3*s+2];
  float d2 = dx*dx + dy*dy + dz*dz + 1e-12f;
  if (d2 < 25.0f) {
    int p = atomicAdd(&cursor[d], 1);
    int slot = indptr[d] + p;
    float dist = sqrtf(d2);
    float inv = 1.0f / dist;
    float wang = 0.62831853071795864769f * dist;   // pi*dist/CUTOFF
    float s1 = __sinf(wang), c1 = __cosf(wang);
    float fc = 0.5f * (c1 + 1.0f);
    srcs[slot] = s;
    eg1[slot] = make_float4(s1, c1, fc, fc * inv);
    eg2[slot] = make_float4(dx * inv, dy * inv, dz * inv, 0.0f);
  }
}

// ---------------- MFMA 3-term GEMM (pre-split LDS): C[M,128] = op(A@B + bias) ----------------
template<bool SILU>
__global__ void __launch_bounds__(256) mfma_gemm_kernel(
    const float* A, const short* __restrict__ Bth, const short* __restrict__ Btl,
    const float* __restrict__ bias, float* C, int M) {
  __shared__ short As2[2 * 32 * 136];   // hi[32][136] | lo[32][136]
  #define ASH(r,c) As2[(r)*136 + (c)]
  #define ASL(r,c) As2[4352 + (r)*136 + (c)]
  int tid = threadIdx.x;
  long r0 = (long)blockIdx.x * 32;
  #pragma unroll
  for (int i = 0; i < 4; i++) {
    int lin = i*256 + tid;
    int r = lin >> 5, c4 = lin & 31;
    long row = r0 + r; if (row >= M) row = M - 1;
    float4 f = *(const float4*)(A + row*128 + c4*4);
    split_store4(f, &ASH(r, c4*4), &ASL(r, c4*4));
  }
  __syncthreads();
  int lane = tid & 63, wv = tid >> 6;
  int l15 = lane & 15, q = lane >> 4;
  v4f acc[2][2] = {};
  #pragma unroll
  for (int s = 0; s < 4; s++) {
    v8s ah[2], al[2];
    #pragma unroll
    for (int mt = 0; mt < 2; mt++) {
      ah[mt] = *(const v8s*)&ASH(mt*16 + l15, s*32 + q*8);
      al[mt] = *(const v8s*)&ASL(mt*16 + l15, s*32 + q*8);
    }
    #pragma unroll
    for (int nt = 0; nt < 2; nt++) {
      int n = (2*wv + nt)*16 + l15;
      v8s bh = *(const v8s*)(Bth + (long)n*128 + s*32 + q*8);
      v8s bl = *(const v8s*)(Btl + (long)n*128 + s*32 + q*8);
      #pragma unroll
      for (int mt = 0; mt < 2; mt++) { MFMA3(acc[mt][nt], ah[mt], al[mt], bh, bl); }
    }
  }
  #pragma unroll
  for (int nt = 0; nt < 2; nt++) {
    int n = (2*wv + nt)*16 + l15;
    float bb = bias[n];
    #pragma unroll
    for (int mt = 0; mt < 2; mt++)
      #pragma unroll
      for (int i = 0; i < 4; i++) {
        long row = r0 + mt*16 + q*4 + i;
        if (row < M) {
          float val = acc[mt][nt][i] + bb;
          if constexpr (SILU) val = silu_f(val);
          C[row*128 + n] = val;
        }
      }
  }
  #undef ASH
  #undef ASL
}

// ---------------- tri-slice phi GEMM (pre-split LDS): C[M,384] = A @ Wm2 + bm2 ----------------
// slice0 -> C0, slice1 -> C1, slice2 -> C2 (C2==A in-place safe: block owns its rows)
__global__ void __launch_bounds__(256) mfma_gemm_phi_kernel(
    const float* A, const short* __restrict__ Bth, const short* __restrict__ Btl,
    const float* __restrict__ bias,
    float* __restrict__ C0, float* __restrict__ C1, float* C2, int M) {
  __shared__ short As2[2 * 32 * 136];
  #define ASH(r,c) As2[(r)*136 + (c)]
  #define ASL(r,c) As2[4352 + (r)*136 + (c)]
  int tid = threadIdx.x;
  long r0 = (long)blockIdx.x * 32;
  #pragma unroll
  for (int i = 0; i < 4; i++) {
    int lin = i*256 + tid;
    int r = lin >> 5, c4 = lin & 31;
    long row = r0 + r; if (row >= M) row = M - 1;
    float4 f = *(const float4*)(A + row*128 + c4*4);
    split_store4(f, &ASH(r, c4*4), &ASL(r, c4*4));
  }
  __syncthreads();
  int lane = tid & 63, wv = tid >> 6;
  int l15 = lane & 15, q = lane >> 4;
  v4f acc[2][6] = {};
  #pragma unroll
  for (int s = 0; s < 4; s++) {
    v8s ah[2], al[2];
    #pragma unroll
    for (int mt = 0; mt < 2; mt++) {
      ah[mt] = *(const v8s*)&ASH(mt*16 + l15, s*32 + q*8);
      al[mt] = *(const v8s*)&ASL(mt*16 + l15, s*32 + q*8);
    }
    #pragma unroll
    for (int g = 0; g < 6; g++) {
      int n = (wv*6 + g)*16 + l15;           // 0..383
      v8s bh = *(const v8s*)(Bth + (long)n*128 + s*32 + q*8);
      v8s bl = *(const v8s*)(Btl + (long)n*128 + s*32 + q*8);
      #pragma unroll
      for (int mt = 0; mt < 2; mt++) { MFMA3(acc[mt][g], ah[mt], al[mt], bh, bl); }
    }
  }
  #pragma unroll
  for (int g = 0; g < 6; g++) {
    int n = (wv*6 + g)*16 + l15;
    int sl = n >> 7, col = n & 127;          // slice uniform per (wv,g)
    float* C = (sl == 0) ? C0 : (sl == 1) ? C1 : C2;
    float bb = bias[n];
    #pragma unroll
    for (int mt = 0; mt < 2; mt++)
      #pragma unroll
      for (int i = 0; i < 4; i++) {
        long row = r0 + mt*16 + q*4 + i;
        if (row < M) C[row*128 + col] = acc[mt][g][i] + bb;
      }
  }
  #undef ASH
  #undef ASL
}

// ---------------- merged message pass: all 3 slices, one edge sweep ----------------
// x += seg(phi0*f0); vB = vA + seg(phi1*f1*dir + phi2*f2*v[src])   (plane layout)
__global__ void __launch_bounds__(128) msg012_kernel(
    const float* __restrict__ phi0, const float* __restrict__ phi1,
    const float* __restrict__ phi2, const float* __restrict__ vA,
    float* __restrict__ vB, float* __restrict__ x,
    const int* __restrict__ srcs, const float4* __restrict__ eg1,
    const float4* __restrict__ eg2, const int* __restrict__ indptr,
    const float* __restrict__ Wf_l, const float* __restrict__ bf_l) {
  const long NND = (long)NN*DD;
  int d = threadIdx.x;
  float wf0[NB_], wf1[NB_], wf2[NB_];
  #pragma unroll
  for (int k = 0; k < NB_; k++) {
    wf0[k] = Wf_l[k*D3 + d];
    wf1[k] = Wf_l[k*D3 + DD + d];
    wf2[k] = Wf_l[k*D3 + 2*DD + d];
  }
  float bf0 = bf_l[d], bf1 = bf_l[DD + d], bf2 = bf_l[2*DD + d];
  int n0 = blockIdx.x * 8;
  for (int j = 0; j < 8; j++) {
    int n = n0 + j;
    int t = indptr[n], end = indptr[n+1];
    float xacc = 0.f, a0 = 0.f, a1 = 0.f, a2 = 0.f;
    float4 g1C = {}, g2C = {};
    float p0C = 0.f, p1C = 0.f, p2C = 0.f, w0C = 0.f, w1C = 0.f, w2C = 0.f;
    if (t < end) {
      int s0 = srcs[t]; g1C = eg1[t]; g2C = eg2[t];
      long b = (long)s0*DD + d;
      p0C = phi0[b]; p1C = phi1[b]; p2C = phi2[b];
      w0C = vA[b]; w1C = vA[NND + b]; w2C = vA[2*NND + b];
    }
    for (; t < end; t++) {
      float4 g = g1C, dv = g2C;
      float p0 = p0C, p1 = p1C, p2 = p2C, w0 = w0C, w1 = w1C, w2 = w2C;
      if (t + 1 < end) {
        int sN = srcs[t+1]; g1C = eg1[t+1]; g2C = eg2[t+1];
        long b = (long)sN*DD + d;
        p0C = phi0[b]; p1C = phi1[b]; p2C = phi2[b];
        w0C = vA[b]; w1C = vA[NND + b]; w2C = vA[2*NND + b];
      }
      float c2 = 2.0f * g.y;
      float rkm1 = 0.f, rk = g.x, dot0 = 0.f, dot1 = 0.f, dot2 = 0.f;
      #pragma unroll
      for (int k = 0; k < NB_; k++) {
        dot0 = fmaf(rk, wf0[k], dot0);
        dot1 = fmaf(rk, wf1[k], dot1);
        dot2 = fmaf(rk, wf2[k], dot2);
        float rn = fmaf(c2, rk, -rkm1);
        rkm1 = rk; rk = rn;
      }
      xacc = fmaf(p0, bf0*g.z + g.w*dot0, xacc);
      float m1 = p1 * (bf1*g.z + g.w*dot1);
      float m2 = p2 * (bf2*g.z + g.w*dot2);
      a0 = fmaf(m1, dv.x, fmaf(m2, w0, a0));
      a1 = fmaf(m1, dv.y, fmaf(m2, w1, a1));
      a2 = fmaf(m1, dv.z, fmaf(m2, w2, a2));
    }
    long b = (long)n*DD + d;
    x[b] += xacc;
    vB[b]         = vA[b]         + a0;
    vB[NND + b]   = vA[NND + b]   + a1;
    vB[2*NND + b] = vA[2*NND + b] + a2;
  }
}

// ---------------- fused Uv/Vv/Vn/s + a-MLP + update (uva): 16 nodes/block ----------------
// v in plane layout [c][N][128]; node-local state (s, Vn^2, Uv) in registers.
// All MFMA A-operands pre-split to bf16 hi/lo in LDS (split once, not per wave).
__global__ void __launch_bounds__(256) uva_kernel(
    float* __restrict__ x, float* __restrict__ v,
    const short* __restrict__ Uth, const short* __restrict__ Utl,
    const short* __restrict__ Vth, const short* __restrict__ Vtl,
    const short* __restrict__ W1h, const short* __restrict__ W1l, const float* __restrict__ b1,
    const short* __restrict__ W2h, const short* __restrict__ W2l, const float* __restrict__ b2) {
  __shared__ short smem[13824];   // 27648 B
  // phase 1: vs hi[48][136] | lo[48][136]
  #define VSH(r,c)  smem[(r)*136 + (c)]
  #define VSL(r,c)  smem[6528 + (r)*136 + (c)]
  // phase 2+: cat hi[16][280] | lo[16][280] ; t2s hi[16][152] | lo[16][152]
  #define CATH(r,c) smem[(r)*280 + (c)]
  #define CATL(r,c) smem[4480 + (r)*280 + (c)]
  #define T2H(r,c)  smem[8960 + (r)*152 + (c)]
  #define T2L(r,c)  smem[11392 + (r)*152 + (c)]
  const long NND = (long)NN*DD;
  int tid = threadIdx.x;
  long nb = (long)blockIdx.x * 16;
  // stage v tile (48 rows = 3 planes x 16 nodes), pre-split
  #pragma unroll
  for (int i = 0; i < 6; i++) {
    int lin = i*256 + tid;
    int r = lin >> 5, c4 = lin & 31;
    int c = r >> 4, nr = r & 15;
    float4 f = *(const float4*)(v + (long)c*NND + (nb + nr)*DD + c4*4);
    split_store4(f, &VSH(r, c4*4), &VSL(r, c4*4));
  }
  __syncthreads();
  int lane = tid & 63, wv = tid >> 6;
  int l15 = lane & 15, q = lane >> 4;
  // ---- phase 1: U & V projections, per channel ----
  v4f aU[3][2] = {}, aV[3][2] = {};
  #pragma unroll
  for (int s = 0; s < 4; s++) {
    v8s buh[2], bul[2], bvh[2], bvl[2];
    #pragma unroll
    for (int nt = 0; nt < 2; nt++) {
      int n = (2*wv + nt)*16 + l15;
      long boff = (long)n*128 + s*32 + q*8;
      buh[nt] = *(const v8s*)(Uth + boff);
      bul[nt] = *(const v8s*)(Utl + boff);
      bvh[nt] = *(const v8s*)(Vth + boff);
      bvl[nt] = *(const v8s*)(Vtl + boff);
    }
    #pragma unroll
    for (int c = 0; c < 3; c++) {
      v8s ah = *(const v8s*)&VSH(c*16 + l15, s*32 + q*8);
      v8s al = *(const v8s*)&VSL(c*16 + l15, s*32 + q*8);
      #pragma unroll
      for (int nt = 0; nt < 2; nt++) {
        MFMA3(aU[c][nt], ah, al, buh[nt], bul[nt]);
        MFMA3(aV[c][nt], ah, al, bvh[nt], bvl[nt]);
      }
    }
  }
  float sreg[2][4], vn2[2][4];
  #pragma unroll
  for (int nt = 0; nt < 2; nt++)
    #pragma unroll
    for (int i = 0; i < 4; i++) {
      sreg[nt][i] = aU[0][nt][i]*aV[0][nt][i] + aU[1][nt][i]*aV[1][nt][i] + aU[2][nt][i]*aV[2][nt][i];
      vn2[nt][i]  = aV[0][nt][i]*aV[0][nt][i] + aV[1][nt][i]*aV[1][nt][i] + aV[2][nt][i]*aV[2][nt][i];
    }
  __syncthreads();   // vs dead; cat/t2s regions free
  // ---- build cat = [x | Vn], pre-split ----
  #pragma unroll
  for (int i = 0; i < 2; i++) {
    int lin = i*256 + tid;
    int r = lin >> 5, c4 = lin & 31;
    float4 f = *(const float4*)(x + (nb + r)*DD + c4*4);
    split_store4(f, &CATH(r, c4*4), &CATL(r, c4*4));
  }
  #pragma unroll
  for (int nt = 0; nt < 2; nt++)
    #pragma unroll
    for (int i = 0; i < 4; i++) {
      int rr = q*4 + i, cc = 128 + (2*wv + nt)*16 + l15;
      short h, l;
      split2(sqrtf(vn2[nt][i] + 1e-8f), h, l);
      CATH(rr, cc) = h; CATL(rr, cc) = l;
    }
  __syncthreads();
  // ---- GEMM1: t2 = silu(cat @ Wu1 + b1), K=256 ----
  {
    v4f acc[2] = {};
    #pragma unroll
    for (int s = 0; s < 8; s++) {
      v8s ah = *(const v8s*)&CATH(l15, s*32 + q*8);
      v8s al = *(const v8s*)&CATL(l15, s*32 + q*8);
      #pragma unroll
      for (int nt = 0; nt < 2; nt++) {
        int n = (2*wv + nt)*16 + l15;
        v8s bh = *(const v8s*)(W1h + (long)n*256 + s*32 + q*8);
        v8s bl = *(const v8s*)(W1l + (long)n*256 + s*32 + q*8);
        MFMA3(acc[nt], ah, al, bh, bl);
      }
    }
    #pragma unroll
    for (int nt = 0; nt < 2; nt++) {
      int n = (2*wv + nt)*16 + l15;
      float bb = b1[n];
      #pragma unroll
      for (int i = 0; i < 4; i++) {
        short h, l;
        split2(silu_f(acc[nt][i] + bb), h, l);
        T2H(q*4 + i, n) = h; T2L(q*4 + i, n) = l;
      }
    }
  }
  __syncthreads();
  // ---- GEMM2 (+ v-old prefetch) + in-register update ----
  {
    float vold[2][4][3];
    #pragma unroll
    for (int p = 0; p < 2; p++) {
      int d = (2*wv + p)*16 + l15;
      #pragma unroll
      for (int i = 0; i < 4; i++) {
        long row = nb + q*4 + i;
        #pragma unroll
        for (int c = 0; c < 3; c++) vold[p][i][c] = v[(long)c*NND + row*DD + d];
      }
    }
    v4f acc[6] = {};
    #pragma unroll
    for (int s = 0; s < 4; s++) {
      v8s ah = *(const v8s*)&T2H(l15, s*32 + q*8);
      v8s al = *(const v8s*)&T2L(l15, s*32 + q*8);
      #pragma unroll
      for (int g = 0; g < 6; g++) {
        int nt = (g >> 1)*8 + 2*wv + (g & 1);
        int n = nt*16 + l15;                 // 0..383
        v8s bh = *(const v8s*)(W2h + (long)n*128 + s*32 + q*8);
        v8s bl = *(const v8s*)(W2l + (long)n*128 + s*32 + q*8);
        MFMA3(acc[g], ah, al, bh, bl);
      }
    }
    #pragma unroll
    for (int p = 0; p < 2; p++) {
      int d = (2*wv + p)*16 + l15;
      float bavv = b2[d], basv = b2[128 + d], bass = b2[256 + d];
      #pragma unroll
      for (int i = 0; i < 4; i++) {
        int lr = q*4 + i;
        long row = nb + lr;
        float avv = acc[p][i]     + bavv;
        float asv = acc[2 + p][i] + basv;
        float ass = acc[4 + p][i] + bass;
        float xold = x[row*DD + d];
        x[row*DD + d] = xold + ass + asv * sreg[p][i];
        #pragma unroll
        for (int c = 0; c < 3; c++)
          v[(long)c*NND + row*DD + d] = fmaf(avv, aU[c][p][i], vold[p][i][c]);
      }
    }
  }
  #undef VSH
  #undef VSL
  #undef CATH
  #undef CATL
  #undef T2H
  #undef T2L
}

// ---------------- output head + segment sum: 4 nodes/block, LDS-staged x ----------------
__global__ void __launch_bounds__(256) out_kernel(
    const float* __restrict__ x, const float* __restrict__ Wo1,
    const float* __restrict__ bo1, const float* __restrict__ Wo2,
    const float* __restrict__ bo2, const int* __restrict__ batch,
    float* __restrict__ out) {
  __shared__ float xs[4][132];
  int tid = threadIdx.x;
  long n0 = (long)blockIdx.x * 4;
  if (tid < 128) {
    int r = tid >> 5, c4 = tid & 31;
    *(float4*)&xs[r][c4*4] = *(const float4*)(x + (n0 + r)*128 + c4*4);
  }
  __syncthreads();
  int wv = tid >> 6, t = tid & 63;
  float acc = bo1[t];
  #pragma unroll 16
  for (int k = 0; k < DD; k++) acc = fmaf(xs[wv][k], Wo1[k*HH + t], acc);
  float val = silu_f(acc) * Wo2[t];
  #pragma unroll
  for (int off = 32; off > 0; off >>= 1) val += __shfl_down(val, off);
  if (t == 0) atomicAdd(&out[batch[n0 + wv]], val + bo2[0]);
}

// ---------------- launcher ----------------
extern "C" void kernel_launch(void* const* d_in, const int* in_sizes, int n_in,
                              void* d_out, int out_size, void* d_ws, size_t ws_size,
                              hipStream_t stream) {
  const int*   at_no = (const int*)d_in[0];
  const float* pos   = (const float*)d_in[1];
  const int*   ei    = (const int*)d_in[2];
  const int*   batch = (const int*)d_in[3];
  const float* emb   = (const float*)d_in[4];
  const float* Wf    = (const float*)d_in[5];
  const float* bfp   = (const float*)d_in[6];
  const float* Wm1   = (const float*)d_in[7];
  const float* bm1   = (const float*)d_in[8];
  const float* Wm2   = (const float*)d_in[9];
  const float* bm2   = (const float*)d_in[10];
  const float* U     = (const float*)d_in[11];
  const float* V     = (const float*)d_in[12];
  const float* Wu1   = (const float*)d_in[13];
  const float* bu1   = (const float*)d_in[14];
  const float* Wu2   = (const float*)d_in[15];
  const float* bu2   = (const float*)d_in[16];
  const float* Wo1   = (const float*)d_in[17];
  const float* bo1   = (const float*)d_in[18];
  const float* Wo2   = (const float*)d_in[19];
  const float* bo2   = (const float*)d_in[20];
  float* out = (float*)d_out;

  char* w = (char*)d_ws;
  auto alloc = [&](size_t bytes) -> void* {
    void* p = (void*)w;
    w += (bytes + 255) & ~(size_t)255;
    return p;
  };
  float*  x      = (float*)alloc(sizeof(float)*(size_t)NN*DD);
  float*  v_a    = (float*)alloc(sizeof(float)*(size_t)NN*D3);   // plane layout [3][NN][DD]
  float*  v_b    = (float*)alloc(sizeof(float)*(size_t)NN*D3);
  float*  t1     = (float*)alloc(sizeof(float)*(size_t)NN*DD);   // phi slice 2 (in-place)
  float*  phiS   = (float*)alloc(sizeof(float)*(size_t)NN*DD);   // phi slice 1
  float*  phi0   = (float*)alloc(sizeof(float)*(size_t)NN*DD);   // phi slice 0
  short*  wbh    = (short*)alloc(sizeof(short)*(size_t)3*LSZ);   // bf16-hi weights
  short*  wbl    = (short*)alloc(sizeof(short)*(size_t)3*LSZ);   // bf16-lo weights
  int*    srcs   = (int*)alloc(sizeof(int)*(size_t)ECAP);
  float4* eg1    = (float4*)alloc(sizeof(float4)*(size_t)ECAP);
  float4* eg2    = (float4*)alloc(sizeof(float4)*(size_t)ECAP);
  int*    indptr = (int*)alloc(sizeof(int)*((size_t)NN+1));
  int*    counts = (int*)alloc(sizeof(int)*(size_t)NN);

  if ((size_t)(w - (char*)d_ws) > ws_size) {   // diagnostic guard: zeros => ws too small
    zero_f_kernel<<<2, 256, 0, stream>>>(out, NG_);
    return;
  }

  zero_f_kernel<<<2048, 256, 0, stream>>>(v_a, (long)NN*D3);
  zero_f_kernel<<<2, 256, 0, stream>>>(out, NG_);
  zero_i_kernel<<<64, 256, 0, stream>>>(counts, NN);
  init_x_kernel<<<(NN*DD + 255)/256, 256, 0, stream>>>(at_no, emb, x);
  prep_w_kernel<<<(3*LSZ + 255)/256, 256, 0, stream>>>(Wm1, Wm2, U, V, Wu1, Wu2, wbh, wbl);
  hist_kernel<<<(NE + 255)/256, 256, 0, stream>>>(ei, pos, counts);
  scan_kernel<<<1, 1024, 0, stream>>>(counts, indptr, NN);
  zero_i_kernel<<<64, 256, 0, stream>>>(counts, NN);
  fill_kernel<<<(NE + 255)/256, 256, 0, stream>>>(ei, pos, indptr, counts, srcs, eg1, eg2);

  const int MB = (NN + 31) / 32;    // 1563
  float* vcur = v_a;
  float* vnext = v_b;
  for (int l = 0; l < 3; l++) {
    const float* Wf_l  = Wf  + (size_t)l*NB_*D3;
    const float* bf_l  = bfp + (size_t)l*D3;
    const float* bm1_l = bm1 + (size_t)l*DD;
    const float* bm2_l = bm2 + (size_t)l*D3;
    const float* bu1_l = bu1 + (size_t)l*DD;
    const float* bu2_l = bu2 + (size_t)l*D3;
    const short* Lh = wbh + (size_t)l*LSZ;
    const short* Ll = wbl + (size_t)l*LSZ;
    const short* Wm1h = Lh,          *Wm1L = Ll;
    const short* Wm2h = Lh + 16384,  *Wm2L = Ll + 16384;
    const short* Uh   = Lh + 65536,  *UL   = Ll + 65536;
    const short* Vh   = Lh + 81920,  *VL   = Ll + 81920;
    const short* Wu1h = Lh + 98304,  *Wu1L = Ll + 98304;
    const short* Wu2h = Lh + 131072, *Wu2L = Ll + 131072;

    // t1 = silu(x@Wm1 + bm1)
    mfma_gemm_kernel<true><<<MB, 256, 0, stream>>>(x, Wm1h, Wm1L, bm1_l, t1, NN);
    // all 3 phi slices in one pass: slice0->phi0, slice1->phiS, slice2->t1 (in place)
    mfma_gemm_phi_kernel<<<MB, 256, 0, stream>>>(t1, Wm2h, Wm2L, bm2_l, phi0, phiS, t1, NN);
    // merged message pass (one edge sweep for x and v)
    msg012_kernel<<<NN/8, 128, 0, stream>>>(phi0, phiS, t1, vcur, vnext, x,
                                            srcs, eg1, eg2, indptr, Wf_l, bf_l);
    // fused Uv/Vv/Vn/s + a-MLP + x,v update
    uva_kernel<<<NN/16, 256, 0, stream>>>(x, vnext, Uh, UL, Vh, VL,
                                          Wu1h, Wu1L, bu1_l, Wu2h, Wu2L, bu2_l);

    float* tmp = vcur; vcur = vnext; vnext = tmp;
  }

  out_kernel<<<NN/4, 256, 0, stream>>>(x, Wo1, bo1, Wo2, bo2, batch, out);

  (void)in_sizes; (void)n_in; (void)out_size; (void)ws_size;
}

// Round 11
// 1496.178 us; speedup vs baseline: 1.6703x; 1.0133x over previous
//
#include <hip/hip_runtime.h>
#include <math.h>

#define NN 50000
#define NE 600000
#define ECAP 230000  // capacity for filtered edges (actual ~183K)
#define DD 128
#define D3 384
#define NB_ 20
#define HH 64
#define NG_ 512
#define LSZ 180224   // shorts per layer of transposed-bf16 weights

typedef short v8s __attribute__((ext_vector_type(8)));
typedef short v4sh __attribute__((ext_vector_type(4)));
typedef float v4f __attribute__((ext_vector_type(4)));

__device__ __forceinline__ float silu_f(float z) { return z / (1.0f + expf(-z)); }

__device__ __forceinline__ short f2bf(float f) {
  unsigned u = __float_as_uint(f);
  u += 0x7FFF + ((u >> 16) & 1);          // RNE
  return (short)(u >> 16);
}
__device__ __forceinline__ float bf2f(short s) {
  return __uint_as_float(((unsigned)(unsigned short)s) << 16);
}
__device__ __forceinline__ void split2(float x, short& h, short& l) {
  h = f2bf(x);
  l = f2bf(x - bf2f(h));
}
// split a float4 and store hi/lo as short4 (8B LDS stores)
__device__ __forceinline__ void split_store4(float4 f, short* hp, short* lp) {
  short h0,l0,h1,l1,h2,l2,h3,l3;
  split2(f.x,h0,l0); split2(f.y,h1,l1); split2(f.z,h2,l2); split2(f.w,h3,l3);
  v4sh hv = {h0,h1,h2,h3}, lv = {l0,l1,l2,l3};
  *(v4sh*)hp = hv; *(v4sh*)lp = lv;
}
// 3-term Markidis split: acc += ah@bh + al@bh + ah@bl   (proven: absmax 4.3e9)
#define MFMA3(acc, ah, al, bh, bl) \
  acc = __builtin_amdgcn_mfma_f32_16x16x32_bf16(ah, bh, acc, 0, 0, 0); \
  acc = __builtin_amdgcn_mfma_f32_16x16x32_bf16(al, bh, acc, 0, 0, 0); \
  acc = __builtin_amdgcn_mfma_f32_16x16x32_bf16(ah, bl, acc, 0, 0, 0);

// ---------------- utility ----------------
__global__ void zero_f_kernel(float* __restrict__ p, long n) {
  long i = (long)blockIdx.x * blockDim.x + threadIdx.x;
  long s = (long)gridDim.x * blockDim.x;
  for (; i < n; i += s) p[i] = 0.0f;
}

__global__ void zero_i_kernel(int* __restrict__ p, long n) {
  long i = (long)blockIdx.x * blockDim.x + threadIdx.x;
  long s = (long)gridDim.x * blockDim.x;
  for (; i < n; i += s) p[i] = 0;
}

__global__ void init_x_kernel(const int* __restrict__ at_no, const float* __restrict__ emb,
                              float* __restrict__ x) {
  int i = blockIdx.x * blockDim.x + threadIdx.x;
  if (i >= NN * DD) return;
  x[i] = emb[at_no[i >> 7] * DD + (i & 127)];
}

// ---------------- weight prep: fp32 [K][N] -> transposed bf16 hi/lo [N][K] ----------------
__global__ void prep_w_kernel(const float* __restrict__ Wm1, const float* __restrict__ Wm2,
                              const float* __restrict__ U, const float* __restrict__ V,
                              const float* __restrict__ Wu1, const float* __restrict__ Wu2,
                              short* __restrict__ hi, short* __restrict__ lo) {
  int idx = blockIdx.x * 256 + threadIdx.x;
  if (idx >= 3 * LSZ) return;
  int l = idx / LSZ, r = idx % LSZ;
  const float* src; int K, N, nk;
  if (r < 16384)       { src = Wm1 + (size_t)l*16384; K = 128; N = 128; nk = r; }
  else if (r < 65536)  { src = Wm2 + (size_t)l*49152; K = 128; N = 384; nk = r - 16384; }
  else if (r < 81920)  { src = U   + (size_t)l*16384; K = 128; N = 128; nk = r - 65536; }
  else if (r < 98304)  { src = V   + (size_t)l*16384; K = 128; N = 128; nk = r - 81920; }
  else if (r < 131072) { src = Wu1 + (size_t)l*32768; K = 256; N = 128; nk = r - 98304; }
  else                 { src = Wu2 + (size_t)l*49152; K = 128; N = 384; nk = r - 131072; }
  int n = nk / K, k = nk - n * K;
  float xx = src[(size_t)k * N + n];
  short h = f2bf(xx);
  hi[idx] = h;
  lo[idx] = f2bf(xx - bf2f(h));
}

// ---------------- CSR build (dst-sorted), filtering dist>=CUTOFF edges ----------------
__global__ void hist_kernel(const int* __restrict__ ei, const float* __restrict__ pos,
                            int* __restrict__ counts) {
  int e = blockIdx.x * blockDim.x + threadIdx.x;
  if (e >= NE) return;
  int s = ei[e], d = ei[NE + e];
  float dx = pos[3*d]   - pos[3*s];
  float dy = pos[3*d+1] - pos[3*s+1];
  float dz = pos[3*d+2] - pos[3*s+2];
  float d2 = dx*dx + dy*dy + dz*dz + 1e-12f;
  if (d2 < 25.0f) atomicAdd(&counts[d], 1);
}

__global__ void scan_kernel(const int* __restrict__ counts, int* __restrict__ indptr, int n) {
  __shared__ int sm[1024];
  __shared__ int carry_s;
  if (threadIdx.x == 0) carry_s = 0;
  __syncthreads();
  for (int start = 0; start < n; start += 1024) {
    int i = start + (int)threadIdx.x;
    int val = (i < n) ? counts[i] : 0;
    sm[threadIdx.x] = val;
    __syncthreads();
    for (int off = 1; off < 1024; off <<= 1) {
      int t = (threadIdx.x >= (unsigned)off) ? sm[threadIdx.x - off] : 0;
      __syncthreads();
      sm[threadIdx.x] += t;
      __syncthreads();
    }
    int c = carry_s;
    if (i < n) indptr[i] = c + sm[threadIdx.x] - val;
    __syncthreads();
    if (threadIdx.x == 0) carry_s = c + sm[1023];
    __syncthreads();
  }
  if (threadIdx.x == 0) indptr[n] = carry_s;
}

__global__ void fill_kernel(const int* __restrict__ ei, const float* __restrict__ pos,
                            const int* __restrict__ indptr, int* __restrict__ cursor,
                            int* __restrict__ srcs, float4* __restrict__ eg1,
                            float4* __restrict__ eg2) {
  int e = blockIdx.x * blockDim.x + threadIdx.x;
  if (e >= NE) return;
  int s = ei[e], d = ei[NE + e];
  float dx = pos[3*d]   - pos[3*s];
  float dy = pos[3*d+1] - pos[3*s+1];
  float dz = pos[3*d+2] - pos[3*s+2];
  float d2 = dx*dx + dy*dy + dz*dz + 1e-12f;
  if (d2 < 25.0f) {
    int p = atomicAdd(&cursor[d], 1);
    int slot = indptr[d] + p;
    float dist = sqrtf(d2);
    float inv = 1.0f / dist;
    float wang = 0.62831853071795864769f * dist;   // pi*dist/CUTOFF
    float s1 = __sinf(wang), c1 = __cosf(wang);
    float fc = 0.5f * (c1 + 1.0f);
    srcs[slot] = s;
    eg1[slot] = make_float4(s1, c1, fc, fc * inv);
    eg2[slot] = make_float4(dx * inv, dy * inv, dz * inv, 0.0f);
  }
}

// ---------------- MFMA 3-term GEMM (pre-split LDS): C[M,128] = op(A@B + bias) ----------------
template<bool SILU>
__global__ void __launch_bounds__(256) mfma_gemm_kernel(
    const float* A, const short* __restrict__ Bth, const short* __restrict__ Btl,
    const float* __restrict__ bias, float* C, int M) {
  __shared__ short As2[2 * 32 * 136];   // hi[32][136] | lo[32][136]
  #define ASH(r,c) As2[(r)*136 + (c)]
  #define ASL(r,c) As2[4352 + (r)*136 + (c)]
  int tid = threadIdx.x;
  long r0 = (long)blockIdx.x * 32;
  #pragma unroll
  for (int i = 0; i < 4; i++) {
    int lin = i*256 + tid;
    int r = lin >> 5, c4 = lin & 31;
    long row = r0 + r; if (row >= M) row = M - 1;
    float4 f = *(const float4*)(A + row*128 + c4*4);
    split_store4(f, &ASH(r, c4*4), &ASL(r, c4*4));
  }
  __syncthreads();
  int lane = tid & 63, wv = tid >> 6;
  int l15 = lane & 15, q = lane >> 4;
  v4f acc[2][2] = {};
  #pragma unroll
  for (int s = 0; s < 4; s++) {
    v8s ah[2], al[2];
    #pragma unroll
    for (int mt = 0; mt < 2; mt++) {
      ah[mt] = *(const v8s*)&ASH(mt*16 + l15, s*32 + q*8);
      al[mt] = *(const v8s*)&ASL(mt*16 + l15, s*32 + q*8);
    }
    #pragma unroll
    for (int nt = 0; nt < 2; nt++) {
      int n = (2*wv + nt)*16 + l15;
      v8s bh = *(const v8s*)(Bth + (long)n*128 + s*32 + q*8);
      v8s bl = *(const v8s*)(Btl + (long)n*128 + s*32 + q*8);
      #pragma unroll
      for (int mt = 0; mt < 2; mt++) { MFMA3(acc[mt][nt], ah[mt], al[mt], bh, bl); }
    }
  }
  #pragma unroll
  for (int nt = 0; nt < 2; nt++) {
    int n = (2*wv + nt)*16 + l15;
    float bb = bias[n];
    #pragma unroll
    for (int mt = 0; mt < 2; mt++)
      #pragma unroll
      for (int i = 0; i < 4; i++) {
        long row = r0 + mt*16 + q*4 + i;
        if (row < M) {
          float val = acc[mt][nt][i] + bb;
          if constexpr (SILU) val = silu_f(val);
          C[row*128 + n] = val;
        }
      }
  }
  #undef ASH
  #undef ASL
}

// ---------------- tri-slice phi GEMM: 512 thr / 8 waves, 3 n-tile-tasks per wave ----------------
// slice0 -> C0, slice1 -> C1, slice2 -> C2 (C2==A in-place safe: block owns its rows)
__global__ void __launch_bounds__(512) mfma_gemm_phi_kernel(
    const float* A, const short* __restrict__ Bth, const short* __restrict__ Btl,
    const float* __restrict__ bias,
    float* __restrict__ C0, float* __restrict__ C1, float* C2, int M) {
  __shared__ short As2[2 * 32 * 136];
  #define ASH(r,c) As2[(r)*136 + (c)]
  #define ASL(r,c) As2[4352 + (r)*136 + (c)]
  int tid = threadIdx.x;
  long r0 = (long)blockIdx.x * 32;
  #pragma unroll
  for (int i = 0; i < 2; i++) {
    int lin = i*512 + tid;
    int r = lin >> 5, c4 = lin & 31;
    long row = r0 + r; if (row >= M) row = M - 1;
    float4 f = *(const float4*)(A + row*128 + c4*4);
    split_store4(f, &ASH(r, c4*4), &ASL(r, c4*4));
  }
  __syncthreads();
  int lane = tid & 63, wv = tid >> 6;     // wv 0..7
  int l15 = lane & 15, q = lane >> 4;
  v4f acc[2][3] = {};
  #pragma unroll
  for (int s = 0; s < 4; s++) {
    v8s ah[2], al[2];
    #pragma unroll
    for (int mt = 0; mt < 2; mt++) {
      ah[mt] = *(const v8s*)&ASH(mt*16 + l15, s*32 + q*8);
      al[mt] = *(const v8s*)&ASL(mt*16 + l15, s*32 + q*8);
    }
    #pragma unroll
    for (int j = 0; j < 3; j++) {
      int n = (wv*3 + j)*16 + l15;         // 0..383
      v8s bh = *(const v8s*)(Bth + (long)n*128 + s*32 + q*8);
      v8s bl = *(const v8s*)(Btl + (long)n*128 + s*32 + q*8);
      #pragma unroll
      for (int mt = 0; mt < 2; mt++) { MFMA3(acc[mt][j], ah[mt], al[mt], bh, bl); }
    }
  }
  #pragma unroll
  for (int j = 0; j < 3; j++) {
    int n = (wv*3 + j)*16 + l15;
    int sl = n >> 7, col = n & 127;        // slice uniform per (wv,j)
    float* C = (sl == 0) ? C0 : (sl == 1) ? C1 : C2;
    float bb = bias[n];
    #pragma unroll
    for (int mt = 0; mt < 2; mt++)
      #pragma unroll
      for (int i = 0; i < 4; i++) {
        long row = r0 + mt*16 + q*4 + i;
        if (row < M) C[row*128 + col] = acc[mt][j][i] + bb;
      }
  }
  #undef ASH
  #undef ASL
}

// ---------------- merged message pass: all 3 slices, one edge sweep ----------------
// x += seg(phi0*f0); vB = vA + seg(phi1*f1*dir + phi2*f2*v[src])   (plane layout)
__global__ void __launch_bounds__(128) msg012_kernel(
    const float* __restrict__ phi0, const float* __restrict__ phi1,
    const float* __restrict__ phi2, const float* __restrict__ vA,
    float* __restrict__ vB, float* __restrict__ x,
    const int* __restrict__ srcs, const float4* __restrict__ eg1,
    const float4* __restrict__ eg2, const int* __restrict__ indptr,
    const float* __restrict__ Wf_l, const float* __restrict__ bf_l) {
  const long NND = (long)NN*DD;
  int d = threadIdx.x;
  float wf0[NB_], wf1[NB_], wf2[NB_];
  #pragma unroll
  for (int k = 0; k < NB_; k++) {
    wf0[k] = Wf_l[k*D3 + d];
    wf1[k] = Wf_l[k*D3 + DD + d];
    wf2[k] = Wf_l[k*D3 + 2*DD + d];
  }
  float bf0 = bf_l[d], bf1 = bf_l[DD + d], bf2 = bf_l[2*DD + d];
  int n0 = blockIdx.x * 8;
  for (int j = 0; j < 8; j++) {
    int n = n0 + j;
    int t = indptr[n], end = indptr[n+1];
    float xacc = 0.f, a0 = 0.f, a1 = 0.f, a2 = 0.f;
    float4 g1C = {}, g2C = {};
    float p0C = 0.f, p1C = 0.f, p2C = 0.f, w0C = 0.f, w1C = 0.f, w2C = 0.f;
    if (t < end) {
      int s0 = srcs[t]; g1C = eg1[t]; g2C = eg2[t];
      long b = (long)s0*DD + d;
      p0C = phi0[b]; p1C = phi1[b]; p2C = phi2[b];
      w0C = vA[b]; w1C = vA[NND + b]; w2C = vA[2*NND + b];
    }
    for (; t < end; t++) {
      float4 g = g1C, dv = g2C;
      float p0 = p0C, p1 = p1C, p2 = p2C, w0 = w0C, w1 = w1C, w2 = w2C;
      if (t + 1 < end) {
        int sN = srcs[t+1]; g1C = eg1[t+1]; g2C = eg2[t+1];
        long b = (long)sN*DD + d;
        p0C = phi0[b]; p1C = phi1[b]; p2C = phi2[b];
        w0C = vA[b]; w1C = vA[NND + b]; w2C = vA[2*NND + b];
      }
      float c2 = 2.0f * g.y;
      float rkm1 = 0.f, rk = g.x, dot0 = 0.f, dot1 = 0.f, dot2 = 0.f;
      #pragma unroll
      for (int k = 0; k < NB_; k++) {
        dot0 = fmaf(rk, wf0[k], dot0);
        dot1 = fmaf(rk, wf1[k], dot1);
        dot2 = fmaf(rk, wf2[k], dot2);
        float rn = fmaf(c2, rk, -rkm1);
        rkm1 = rk; rk = rn;
      }
      xacc = fmaf(p0, bf0*g.z + g.w*dot0, xacc);
      float m1 = p1 * (bf1*g.z + g.w*dot1);
      float m2 = p2 * (bf2*g.z + g.w*dot2);
      a0 = fmaf(m1, dv.x, fmaf(m2, w0, a0));
      a1 = fmaf(m1, dv.y, fmaf(m2, w1, a1));
      a2 = fmaf(m1, dv.z, fmaf(m2, w2, a2));
    }
    long b = (long)n*DD + d;
    x[b] += xacc;
    vB[b]         = vA[b]         + a0;
    vB[NND + b]   = vA[NND + b]   + a1;
    vB[2*NND + b] = vA[2*NND + b] + a2;
  }
}

// ---------------- fused Uv/Vv/Vn/s + a-MLP + update (uva): 16 nodes/block ----------------
// 512 threads / 8 waves; wave w owns column slice d = w*16 + (lane&15) for ALL phases:
// phase1 n-tile w, GEMM1 n-tile w, GEMM2 tiles {w, 8+w, 16+w} (avv/asv/ass same lane).
// vold/xold prefetched at entry; s/Vn^2/Uv in registers.
__global__ void __launch_bounds__(512) uva_kernel(
    float* __restrict__ x, float* __restrict__ v,
    const short* __restrict__ Uth, const short* __restrict__ Utl,
    const short* __restrict__ Vth, const short* __restrict__ Vtl,
    const short* __restrict__ W1h, const short* __restrict__ W1l, const float* __restrict__ b1,
    const short* __restrict__ W2h, const short* __restrict__ W2l, const float* __restrict__ b2) {
  __shared__ short smem[13824];   // 27648 B
  // phase 1: vs hi[48][136] | lo[48][136]
  #define VSH(r,c)  smem[(r)*136 + (c)]
  #define VSL(r,c)  smem[6528 + (r)*136 + (c)]
  // phase 2+: cat hi[16][280] | lo[16][280] ; t2s hi[16][152] | lo[16][152]
  #define CATH(r,c) smem[(r)*280 + (c)]
  #define CATL(r,c) smem[4480 + (r)*280 + (c)]
  #define T2H(r,c)  smem[8960 + (r)*152 + (c)]
  #define T2L(r,c)  smem[11392 + (r)*152 + (c)]
  const long NND = (long)NN*DD;
  int tid = threadIdx.x;
  long nb = (long)blockIdx.x * 16;
  int lane = tid & 63, wv = tid >> 6;   // wv 0..7
  int l15 = lane & 15, q = lane >> 4;
  int d = wv*16 + l15;                  // this wave's column slice
  // prefetch v-old and x-old for the epilogue (x, v stable inputs to this kernel)
  float vold[4][3], xold[4];
  #pragma unroll
  for (int i = 0; i < 4; i++) {
    long row = nb + q*4 + i;
    xold[i] = x[row*DD + d];
    #pragma unroll
    for (int c = 0; c < 3; c++) vold[i][c] = v[(long)c*NND + row*DD + d];
  }
  // stage v tile (48 rows = 3 planes x 16 nodes), pre-split
  #pragma unroll
  for (int i = 0; i < 3; i++) {
    int lin = i*512 + tid;
    int r = lin >> 5, c4 = lin & 31;
    int c = r >> 4, nr = r & 15;
    float4 f = *(const float4*)(v + (long)c*NND + (nb + nr)*DD + c4*4);
    split_store4(f, &VSH(r, c4*4), &VSL(r, c4*4));
  }
  __syncthreads();
  // ---- phase 1: U & V projections for column-slice d, per channel ----
  v4f aU[3] = {}, aV[3] = {};
  #pragma unroll
  for (int s = 0; s < 4; s++) {
    long boff = (long)d*128 + s*32 + q*8;
    v8s buh = *(const v8s*)(Uth + boff);
    v8s bul = *(const v8s*)(Utl + boff);
    v8s bvh = *(const v8s*)(Vth + boff);
    v8s bvl = *(const v8s*)(Vtl + boff);
    #pragma unroll
    for (int c = 0; c < 3; c++) {
      v8s ah = *(const v8s*)&VSH(c*16 + l15, s*32 + q*8);
      v8s al = *(const v8s*)&VSL(c*16 + l15, s*32 + q*8);
      MFMA3(aU[c], ah, al, buh, bul);
      MFMA3(aV[c], ah, al, bvh, bvl);
    }
  }
  float sreg[4], vn2[4];
  #pragma unroll
  for (int i = 0; i < 4; i++) {
    sreg[i] = aU[0][i]*aV[0][i] + aU[1][i]*aV[1][i] + aU[2][i]*aV[2][i];
    vn2[i]  = aV[0][i]*aV[0][i] + aV[1][i]*aV[1][i] + aV[2][i]*aV[2][i];
  }
  __syncthreads();   // vs dead; cat/t2s regions free
  // ---- build cat = [x | Vn], pre-split ----
  {
    int r = tid >> 5, c4 = tid & 31;     // 512 tasks exactly
    float4 f = *(const float4*)(x + (nb + r)*DD + c4*4);
    split_store4(f, &CATH(r, c4*4), &CATL(r, c4*4));
  }
  #pragma unroll
  for (int i = 0; i < 4; i++) {
    short h, l;
    split2(sqrtf(vn2[i] + 1e-8f), h, l);
    CATH(q*4 + i, 128 + d) = h; CATL(q*4 + i, 128 + d) = l;
  }
  __syncthreads();
  // ---- GEMM1: t2[:, d-slice] = silu(cat @ Wu1 + b1), K=256 ----
  {
    v4f acc = {};
    #pragma unroll
    for (int s = 0; s < 8; s++) {
      v8s ah = *(const v8s*)&CATH(l15, s*32 + q*8);
      v8s al = *(const v8s*)&CATL(l15, s*32 + q*8);
      v8s bh = *(const v8s*)(W1h + (long)d*256 + s*32 + q*8);
      v8s bl = *(const v8s*)(W1l + (long)d*256 + s*32 + q*8);
      MFMA3(acc, ah, al, bh, bl);
    }
    float bb = b1[d];
    #pragma unroll
    for (int i = 0; i < 4; i++) {
      short h, l;
      split2(silu_f(acc[i] + bb), h, l);
      T2H(q*4 + i, d) = h; T2L(q*4 + i, d) = l;
    }
  }
  __syncthreads();
  // ---- GEMM2 + in-register update ----
  {
    v4f acc[3] = {};
    #pragma unroll
    for (int s = 0; s < 4; s++) {
      v8s ah = *(const v8s*)&T2H(l15, s*32 + q*8);
      v8s al = *(const v8s*)&T2L(l15, s*32 + q*8);
      #pragma unroll
      for (int g = 0; g < 3; g++) {
        int n = g*128 + d;                 // avv: d, asv: 128+d, ass: 256+d
        v8s bh = *(const v8s*)(W2h + (long)n*128 + s*32 + q*8);
        v8s bl = *(const v8s*)(W2l + (long)n*128 + s*32 + q*8);
        MFMA3(acc[g], ah, al, bh, bl);
      }
    }
    float bavv = b2[d], basv = b2[128 + d], bass = b2[256 + d];
    #pragma unroll
    for (int i = 0; i < 4; i++) {
      long row = nb + q*4 + i;
      float avv = acc[0][i] + bavv;
      float asv = acc[1][i] + basv;
      float ass = acc[2][i] + bass;
      x[row*DD + d] = xold[i] + ass + asv * sreg[i];
      #pragma unroll
      for (int c = 0; c < 3; c++)
        v[(long)c*NND + row*DD + d] = fmaf(avv, aU[c][i], vold[i][c]);
    }
  }
  #undef VSH
  #undef VSL
  #undef CATH
  #undef CATL
  #undef T2H
  #undef T2L
}

// ---------------- output head + segment sum: 4 nodes/block, LDS-staged x ----------------
__global__ void __launch_bounds__(256) out_kernel(
    const float* __restrict__ x, const float* __restrict__ Wo1,
    const float* __restrict__ bo1, const float* __restrict__ Wo2,
    const float* __restrict__ bo2, const int* __restrict__ batch,
    float* __restrict__ out) {
  __shared__ float xs[4][132];
  int tid = threadIdx.x;
  long n0 = (long)blockIdx.x * 4;
  if (tid < 128) {
    int r = tid >> 5, c4 = tid & 31;
    *(float4*)&xs[r][c4*4] = *(const float4*)(x + (n0 + r)*128 + c4*4);
  }
  __syncthreads();
  int wv = tid >> 6, t = tid & 63;
  float acc = bo1[t];
  #pragma unroll 16
  for (int k = 0; k < DD; k++) acc = fmaf(xs[wv][k], Wo1[k*HH + t], acc);
  float val = silu_f(acc) * Wo2[t];
  #pragma unroll
  for (int off = 32; off > 0; off >>= 1) val += __shfl_down(val, off);
  if (t == 0) atomicAdd(&out[batch[n0 + wv]], val + bo2[0]);
}

// ---------------- launcher ----------------
extern "C" void kernel_launch(void* const* d_in, const int* in_sizes, int n_in,
                              void* d_out, int out_size, void* d_ws, size_t ws_size,
                              hipStream_t stream) {
  const int*   at_no = (const int*)d_in[0];
  const float* pos   = (const float*)d_in[1];
  const int*   ei    = (const int*)d_in[2];
  const int*   batch = (const int*)d_in[3];
  const float* emb   = (const float*)d_in[4];
  const float* Wf    = (const float*)d_in[5];
  const float* bfp   = (const float*)d_in[6];
  const float* Wm1   = (const float*)d_in[7];
  const float* bm1   = (const float*)d_in[8];
  const float* Wm2   = (const float*)d_in[9];
  const float* bm2   = (const float*)d_in[10];
  const float* U     = (const float*)d_in[11];
  const float* V     = (const float*)d_in[12];
  const float* Wu1   = (const float*)d_in[13];
  const float* bu1   = (const float*)d_in[14];
  const float* Wu2   = (const float*)d_in[15];
  const float* bu2   = (const float*)d_in[16];
  const float* Wo1   = (const float*)d_in[17];
  const float* bo1   = (const float*)d_in[18];
  const float* Wo2   = (const float*)d_in[19];
  const float* bo2   = (const float*)d_in[20];
  float* out = (float*)d_out;

  char* w = (char*)d_ws;
  auto alloc = [&](size_t bytes) -> void* {
    void* p = (void*)w;
    w += (bytes + 255) & ~(size_t)255;
    return p;
  };
  float*  x      = (float*)alloc(sizeof(float)*(size_t)NN*DD);
  float*  v_a    = (float*)alloc(sizeof(float)*(size_t)NN*D3);   // plane layout [3][NN][DD]
  float*  v_b    = (float*)alloc(sizeof(float)*(size_t)NN*D3);
  float*  t1     = (float*)alloc(sizeof(float)*(size_t)NN*DD);   // phi slice 2 (in-place)
  float*  phiS   = (float*)alloc(sizeof(float)*(size_t)NN*DD);   // phi slice 1
  float*  phi0   = (float*)alloc(sizeof(float)*(size_t)NN*DD);   // phi slice 0
  short*  wbh    = (short*)alloc(sizeof(short)*(size_t)3*LSZ);   // bf16-hi weights
  short*  wbl    = (short*)alloc(sizeof(short)*(size_t)3*LSZ);   // bf16-lo weights
  int*    srcs   = (int*)alloc(sizeof(int)*(size_t)ECAP);
  float4* eg1    = (float4*)alloc(sizeof(float4)*(size_t)ECAP);
  float4* eg2    = (float4*)alloc(sizeof(float4)*(size_t)ECAP);
  int*    indptr = (int*)alloc(sizeof(int)*((size_t)NN+1));
  int*    counts = (int*)alloc(sizeof(int)*(size_t)NN);

  if ((size_t)(w - (char*)d_ws) > ws_size) {   // diagnostic guard: zeros => ws too small
    zero_f_kernel<<<2, 256, 0, stream>>>(out, NG_);
    return;
  }

  zero_f_kernel<<<2048, 256, 0, stream>>>(v_a, (long)NN*D3);
  zero_f_kernel<<<2, 256, 0, stream>>>(out, NG_);
  zero_i_kernel<<<64, 256, 0, stream>>>(counts, NN);
  init_x_kernel<<<(NN*DD + 255)/256, 256, 0, stream>>>(at_no, emb, x);
  prep_w_kernel<<<(3*LSZ + 255)/256, 256, 0, stream>>>(Wm1, Wm2, U, V, Wu1, Wu2, wbh, wbl);
  hist_kernel<<<(NE + 255)/256, 256, 0, stream>>>(ei, pos, counts);
  scan_kernel<<<1, 1024, 0, stream>>>(counts, indptr, NN);
  zero_i_kernel<<<64, 256, 0, stream>>>(counts, NN);
  fill_kernel<<<(NE + 255)/256, 256, 0, stream>>>(ei, pos, indptr, counts, srcs, eg1, eg2);

  const int MB = (NN + 31) / 32;    // 1563
  float* vcur = v_a;
  float* vnext = v_b;
  for (int l = 0; l < 3; l++) {
    const float* Wf_l  = Wf  + (size_t)l*NB_*D3;
    const float* bf_l  = bfp + (size_t)l*D3;
    const float* bm1_l = bm1 + (size_t)l*DD;
    const float* bm2_l = bm2 + (size_t)l*D3;
    const float* bu1_l = bu1 + (size_t)l*DD;
    const float* bu2_l = bu2 + (size_t)l*D3;
    const short* Lh = wbh + (size_t)l*LSZ;
    const short* Ll = wbl + (size_t)l*LSZ;
    const short* Wm1h = Lh,          *Wm1L = Ll;
    const short* Wm2h = Lh + 16384,  *Wm2L = Ll + 16384;
    const short* Uh   = Lh + 65536,  *UL   = Ll + 65536;
    const short* Vh   = Lh + 81920,  *VL   = Ll + 81920;
    const short* Wu1h = Lh + 98304,  *Wu1L = Ll + 98304;
    const short* Wu2h = Lh + 131072, *Wu2L = Ll + 131072;

    // t1 = silu(x@Wm1 + bm1)
    mfma_gemm_kernel<true><<<MB, 256, 0, stream>>>(x, Wm1h, Wm1L, bm1_l, t1, NN);
    // all 3 phi slices in one pass: slice0->phi0, slice1->phiS, slice2->t1 (in place)
    mfma_gemm_phi_kernel<<<MB, 512, 0, stream>>>(t1, Wm2h, Wm2L, bm2_l, phi0, phiS, t1, NN);
    // merged message pass (one edge sweep for x and v)
    msg012_kernel<<<NN/8, 128, 0, stream>>>(phi0, phiS, t1, vcur, vnext, x,
                                            srcs, eg1, eg2, indptr, Wf_l, bf_l);
    // fused Uv/Vv/Vn/s + a-MLP + x,v update
    uva_kernel<<<NN/16, 512, 0, stream>>>(x, vnext, Uh, UL, Vh, VL,
                                          Wu1h, Wu1L, bu1_l, Wu2h, Wu2L, bu2_l);

    float* tmp = vcur; vcur = vnext; vnext = tmp;
  }

  out_kernel<<<NN/4, 256, 0, stream>>>(x, Wo1, bo1, Wo2, bo2, batch, out);

  (void)in_sizes; (void)n_in; (void)out_size; (void)ws_size;
}

// Round 12
// 1476.805 us; speedup vs baseline: 1.6923x; 1.0131x over previous
//
#include <hip/hip_runtime.h>
#include <math.h>

#define NN 50000
#define NE 600000
#define ECAP 230000  // capacity for filtered edges (actual ~174K)
#define DD 128
#define D3 384
#define NB_ 20
#define HH 64
#define NG_ 512
#define LSZ 180224   // shorts per layer of transposed-bf16 weights

typedef short v8s __attribute__((ext_vector_type(8)));
typedef short v4sh __attribute__((ext_vector_type(4)));
typedef float v4f __attribute__((ext_vector_type(4)));

__device__ __forceinline__ float silu_f(float z) { return z / (1.0f + expf(-z)); }

__device__ __forceinline__ short f2bf(float f) {
  unsigned u = __float_as_uint(f);
  u += 0x7FFF + ((u >> 16) & 1);          // RNE
  return (short)(u >> 16);
}
__device__ __forceinline__ float bf2f(short s) {
  return __uint_as_float(((unsigned)(unsigned short)s) << 16);
}
__device__ __forceinline__ void split2(float x, short& h, short& l) {
  h = f2bf(x);
  l = f2bf(x - bf2f(h));
}
#define SPLIT8(f0, f1, ah, al) { short h,l; \
  split2(f0.x,h,l); ah[0]=h; al[0]=l;  split2(f0.y,h,l); ah[1]=h; al[1]=l; \
  split2(f0.z,h,l); ah[2]=h; al[2]=l;  split2(f0.w,h,l); ah[3]=h; al[3]=l; \
  split2(f1.x,h,l); ah[4]=h; al[4]=l;  split2(f1.y,h,l); ah[5]=h; al[5]=l; \
  split2(f1.z,h,l); ah[6]=h; al[6]=l;  split2(f1.w,h,l); ah[7]=h; al[7]=l; }
// split a float4 and store hi/lo as short4 (8B LDS stores)
__device__ __forceinline__ void split_store4(float4 f, short* hp, short* lp) {
  short h0,l0,h1,l1,h2,l2,h3,l3;
  split2(f.x,h0,l0); split2(f.y,h1,l1); split2(f.z,h2,l2); split2(f.w,h3,l3);
  v4sh hv = {h0,h1,h2,h3}, lv = {l0,l1,l2,l3};
  *(v4sh*)hp = hv; *(v4sh*)lp = lv;
}
// 3-term Markidis split: acc += ah@bh + al@bh + ah@bl   (proven: absmax 4.3e9)
#define MFMA3(acc, ah, al, bh, bl) \
  acc = __builtin_amdgcn_mfma_f32_16x16x32_bf16(ah, bh, acc, 0, 0, 0); \
  acc = __builtin_amdgcn_mfma_f32_16x16x32_bf16(al, bh, acc, 0, 0, 0); \
  acc = __builtin_amdgcn_mfma_f32_16x16x32_bf16(ah, bl, acc, 0, 0, 0);

// ---------------- utility ----------------
__global__ void zero_f_kernel(float* __restrict__ p, long n) {
  long i = (long)blockIdx.x * blockDim.x + threadIdx.x;
  long s = (long)gridDim.x * blockDim.x;
  for (; i < n; i += s) p[i] = 0.0f;
}

__global__ void zero_i_kernel(int* __restrict__ p, long n) {
  long i = (long)blockIdx.x * blockDim.x + threadIdx.x;
  long s = (long)gridDim.x * blockDim.x;
  for (; i < n; i += s) p[i] = 0;
}

__global__ void init_x_kernel(const int* __restrict__ at_no, const float* __restrict__ emb,
                              float* __restrict__ x) {
  int i = blockIdx.x * blockDim.x + threadIdx.x;
  if (i >= NN * DD) return;
  x[i] = emb[at_no[i >> 7] * DD + (i & 127)];
}

// ---------------- weight prep: fp32 [K][N] -> transposed bf16 hi/lo [N][K] ----------------
__global__ void prep_w_kernel(const float* __restrict__ Wm1, const float* __restrict__ Wm2,
                              const float* __restrict__ U, const float* __restrict__ V,
                              const float* __restrict__ Wu1, const float* __restrict__ Wu2,
                              short* __restrict__ hi, short* __restrict__ lo) {
  int idx = blockIdx.x * 256 + threadIdx.x;
  if (idx >= 3 * LSZ) return;
  int l = idx / LSZ, r = idx % LSZ;
  const float* src; int K, N, nk;
  if (r < 16384)       { src = Wm1 + (size_t)l*16384; K = 128; N = 128; nk = r; }
  else if (r < 65536)  { src = Wm2 + (size_t)l*49152; K = 128; N = 384; nk = r - 16384; }
  else if (r < 81920)  { src = U   + (size_t)l*16384; K = 128; N = 128; nk = r - 65536; }
  else if (r < 98304)  { src = V   + (size_t)l*16384; K = 128; N = 128; nk = r - 81920; }
  else if (r < 131072) { src = Wu1 + (size_t)l*32768; K = 256; N = 128; nk = r - 98304; }
  else                 { src = Wu2 + (size_t)l*49152; K = 128; N = 384; nk = r - 131072; }
  int n = nk / K, k = nk - n * K;
  float xx = src[(size_t)k * N + n];
  short h = f2bf(xx);
  hi[idx] = h;
  lo[idx] = f2bf(xx - bf2f(h));
}

// ---------------- CSR build (dst-sorted), filtering dist>=CUTOFF edges ----------------
__global__ void hist_kernel(const int* __restrict__ ei, const float* __restrict__ pos,
                            int* __restrict__ counts) {
  int e = blockIdx.x * blockDim.x + threadIdx.x;
  if (e >= NE) return;
  int s = ei[e], d = ei[NE + e];
  float dx = pos[3*d]   - pos[3*s];
  float dy = pos[3*d+1] - pos[3*s+1];
  float dz = pos[3*d+2] - pos[3*s+2];
  float d2 = dx*dx + dy*dy + dz*dz + 1e-12f;
  if (d2 < 25.0f) atomicAdd(&counts[d], 1);
}

__global__ void scan_kernel(const int* __restrict__ counts, int* __restrict__ indptr, int n) {
  __shared__ int sm[1024];
  __shared__ int carry_s;
  if (threadIdx.x == 0) carry_s = 0;
  __syncthreads();
  for (int start = 0; start < n; start += 1024) {
    int i = start + (int)threadIdx.x;
    int val = (i < n) ? counts[i] : 0;
    sm[threadIdx.x] = val;
    __syncthreads();
    for (int off = 1; off < 1024; off <<= 1) {
      int t = (threadIdx.x >= (unsigned)off) ? sm[threadIdx.x - off] : 0;
      __syncthreads();
      sm[threadIdx.x] += t;
      __syncthreads();
    }
    int c = carry_s;
    if (i < n) indptr[i] = c + sm[threadIdx.x] - val;
    __syncthreads();
    if (threadIdx.x == 0) carry_s = c + sm[1023];
    __syncthreads();
  }
  if (threadIdx.x == 0) indptr[n] = carry_s;
}

__global__ void fill_kernel(const int* __restrict__ ei, const float* __restrict__ pos,
                            const int* __restrict__ indptr, int* __restrict__ cursor,
                            int* __restrict__ srcs, float4* __restrict__ eg1,
                            float4* __restrict__ eg2) {
  int e = blockIdx.x * blockDim.x + threadIdx.x;
  if (e >= NE) return;
  int s = ei[e], d = ei[NE + e];
  float dx = pos[3*d]   - pos[3*s];
  float dy = pos[3*d+1] - pos[3*s+1];
  float dz = pos[3*d+2] - pos[3*s+2];
  float d2 = dx*dx + dy*dy + dz*dz + 1e-12f;
  if (d2 < 25.0f) {
    int p = atomicAdd(&cursor[d], 1);
    int slot = indptr[d] + p;
    float dist = sqrtf(d2);
    float inv = 1.0f / dist;
    float wang = 0.62831853071795864769f * dist;   // pi*dist/CUTOFF
    float s1 = __sinf(wang), c1 = __cosf(wang);
    float fc = 0.5f * (c1 + 1.0f);
    srcs[slot] = s;
    eg1[slot] = make_float4(s1, c1, fc, fc * inv);
    eg2[slot] = make_float4(dx * inv, dy * inv, dz * inv, 0.0f);
  }
}

// ---------------- MFMA 3-term GEMM (pre-split LDS): C[M,128] = op(A@B + bias) ----------------
template<bool SILU>
__global__ void __launch_bounds__(256) mfma_gemm_kernel(
    const float* A, const short* __restrict__ Bth, const short* __restrict__ Btl,
    const float* __restrict__ bias, float* C, int M) {
  __shared__ short As2[2 * 32 * 136];   // hi[32][136] | lo[32][136]
  #define ASH(r,c) As2[(r)*136 + (c)]
  #define ASL(r,c) As2[4352 + (r)*136 + (c)]
  int tid = threadIdx.x;
  long r0 = (long)blockIdx.x * 32;
  #pragma unroll
  for (int i = 0; i < 4; i++) {
    int lin = i*256 + tid;
    int r = lin >> 5, c4 = lin & 31;
    long row = r0 + r; if (row >= M) row = M - 1;
    float4 f = *(const float4*)(A + row*128 + c4*4);
    split_store4(f, &ASH(r, c4*4), &ASL(r, c4*4));
  }
  __syncthreads();
  int lane = tid & 63, wv = tid >> 6;
  int l15 = lane & 15, q = lane >> 4;
  v4f acc[2][2] = {};
  #pragma unroll
  for (int s = 0; s < 4; s++) {
    v8s ah[2], al[2];
    #pragma unroll
    for (int mt = 0; mt < 2; mt++) {
      ah[mt] = *(const v8s*)&ASH(mt*16 + l15, s*32 + q*8);
      al[mt] = *(const v8s*)&ASL(mt*16 + l15, s*32 + q*8);
    }
    #pragma unroll
    for (int nt = 0; nt < 2; nt++) {
      int n = (2*wv + nt)*16 + l15;
      v8s bh = *(const v8s*)(Bth + (long)n*128 + s*32 + q*8);
      v8s bl = *(const v8s*)(Btl + (long)n*128 + s*32 + q*8);
      #pragma unroll
      for (int mt = 0; mt < 2; mt++) { MFMA3(acc[mt][nt], ah[mt], al[mt], bh, bl); }
    }
  }
  #pragma unroll
  for (int nt = 0; nt < 2; nt++) {
    int n = (2*wv + nt)*16 + l15;
    float bb = bias[n];
    #pragma unroll
    for (int mt = 0; mt < 2; mt++)
      #pragma unroll
      for (int i = 0; i < 4; i++) {
        long row = r0 + mt*16 + q*4 + i;
        if (row < M) {
          float val = acc[mt][nt][i] + bb;
          if constexpr (SILU) val = silu_f(val);
          C[row*128 + n] = val;
        }
      }
  }
  #undef ASH
  #undef ASL
}

// ---------------- tri-slice phi GEMM: 512 thr / 8 waves, 3 n-tile-tasks per wave ----------------
// slice0 -> C0, slice1 -> C1, slice2 -> C2 (C2==A in-place safe: block owns its rows)
__global__ void __launch_bounds__(512) mfma_gemm_phi_kernel(
    const float* A, const short* __restrict__ Bth, const short* __restrict__ Btl,
    const float* __restrict__ bias,
    float* __restrict__ C0, float* __restrict__ C1, float* C2, int M) {
  __shared__ short As2[2 * 32 * 136];
  #define ASH(r,c) As2[(r)*136 + (c)]
  #define ASL(r,c) As2[4352 + (r)*136 + (c)]
  int tid = threadIdx.x;
  long r0 = (long)blockIdx.x * 32;
  #pragma unroll
  for (int i = 0; i < 2; i++) {
    int lin = i*512 + tid;
    int r = lin >> 5, c4 = lin & 31;
    long row = r0 + r; if (row >= M) row = M - 1;
    float4 f = *(const float4*)(A + row*128 + c4*4);
    split_store4(f, &ASH(r, c4*4), &ASL(r, c4*4));
  }
  __syncthreads();
  int lane = tid & 63, wv = tid >> 6;     // wv 0..7
  int l15 = lane & 15, q = lane >> 4;
  v4f acc[2][3] = {};
  #pragma unroll
  for (int s = 0; s < 4; s++) {
    v8s ah[2], al[2];
    #pragma unroll
    for (int mt = 0; mt < 2; mt++) {
      ah[mt] = *(const v8s*)&ASH(mt*16 + l15, s*32 + q*8);
      al[mt] = *(const v8s*)&ASL(mt*16 + l15, s*32 + q*8);
    }
    #pragma unroll
    for (int j = 0; j < 3; j++) {
      int n = (wv*3 + j)*16 + l15;         // 0..383
      v8s bh = *(const v8s*)(Bth + (long)n*128 + s*32 + q*8);
      v8s bl = *(const v8s*)(Btl + (long)n*128 + s*32 + q*8);
      #pragma unroll
      for (int mt = 0; mt < 2; mt++) { MFMA3(acc[mt][j], ah[mt], al[mt], bh, bl); }
    }
  }
  #pragma unroll
  for (int j = 0; j < 3; j++) {
    int n = (wv*3 + j)*16 + l15;
    int sl = n >> 7, col = n & 127;        // slice uniform per (wv,j)
    float* C = (sl == 0) ? C0 : (sl == 1) ? C1 : C2;
    float bb = bias[n];
    #pragma unroll
    for (int mt = 0; mt < 2; mt++)
      #pragma unroll
      for (int i = 0; i < 4; i++) {
        long row = r0 + mt*16 + q*4 + i;
        if (row < M) C[row*128 + col] = acc[mt][j][i] + bb;
      }
  }
  #undef ASH
  #undef ASL
}

// ---------------- FUSED message pass + Uv/Vv/Vn/s + a-MLP + update (muva) ----------------
// 16 nodes/block, 512 threads. Edge sweep -> x_new/v_new in LDS (never globalized);
// then U/V projections (wave w owns column slice d=w*16+l15), GEMM1, GEMM2, epilogue.
// x updated in place (only phi is gathered cross-node); v double-buffered (vA gathered).
__global__ void __launch_bounds__(512) muva_kernel(
    const float* __restrict__ phi0, const float* __restrict__ phi1,
    const float* __restrict__ phi2, const float* __restrict__ vA,
    float* __restrict__ vB, float* __restrict__ x,
    const int* __restrict__ srcs, const float4* __restrict__ eg1,
    const float4* __restrict__ eg2, const int* __restrict__ indptr,
    const float* __restrict__ Wf_l, const float* __restrict__ bf_l,
    const short* __restrict__ Uth, const short* __restrict__ Utl,
    const short* __restrict__ Vth, const short* __restrict__ Vtl,
    const short* __restrict__ W1h, const short* __restrict__ W1l, const float* __restrict__ b1,
    const short* __restrict__ W2h, const short* __restrict__ W2l, const float* __restrict__ b2) {
  __shared__ float smem[8704];   // 34816 B
  // region A [0,6528): v_new [48][136]; later overlaid by cat[16][272] | t2[16][136]
  // region B [6528,8704): x_new [16][136]
  #define VN(r,c)  smem[(r)*136 + (c)]
  #define XN(r,c)  smem[6528 + (r)*136 + (c)]
  #define CAT(r,c) smem[(r)*272 + (c)]
  #define T2(r,c)  smem[4352 + (r)*136 + (c)]
  const long NND = (long)NN*DD;
  int tid = threadIdx.x;
  long nb = (long)blockIdx.x * 16;
  // ---- phase E: edge sweep. 4 groups x 128 d-lanes; group g handles nodes 4g..4g+3 ----
  {
    int g = tid >> 7, d = tid & 127;
    float wf0[NB_], wf1[NB_], wf2[NB_];
    #pragma unroll
    for (int k = 0; k < NB_; k++) {
      wf0[k] = Wf_l[k*D3 + d];
      wf1[k] = Wf_l[k*D3 + DD + d];
      wf2[k] = Wf_l[k*D3 + 2*DD + d];
    }
    float bf0 = bf_l[d], bf1 = bf_l[DD + d], bf2 = bf_l[2*DD + d];
    for (int j = 0; j < 4; j++) {
      int nr = 4*g + j;
      long n = nb + nr;
      int t = indptr[n], end = indptr[n+1];
      float xacc = 0.f, a0 = 0.f, a1 = 0.f, a2 = 0.f;
      float4 g1C = {}, g2C = {};
      float p0C = 0.f, p1C = 0.f, p2C = 0.f, w0C = 0.f, w1C = 0.f, w2C = 0.f;
      if (t < end) {
        int s0 = srcs[t]; g1C = eg1[t]; g2C = eg2[t];
        long b = (long)s0*DD + d;
        p0C = phi0[b]; p1C = phi1[b]; p2C = phi2[b];
        w0C = vA[b]; w1C = vA[NND + b]; w2C = vA[2*NND + b];
      }
      for (; t < end; t++) {
        float4 gg = g1C, dv = g2C;
        float p0 = p0C, p1 = p1C, p2 = p2C, w0 = w0C, w1 = w1C, w2 = w2C;
        if (t + 1 < end) {
          int sN = srcs[t+1]; g1C = eg1[t+1]; g2C = eg2[t+1];
          long b = (long)sN*DD + d;
          p0C = phi0[b]; p1C = phi1[b]; p2C = phi2[b];
          w0C = vA[b]; w1C = vA[NND + b]; w2C = vA[2*NND + b];
        }
        float c2 = 2.0f * gg.y;
        float rkm1 = 0.f, rk = gg.x, dot0 = 0.f, dot1 = 0.f, dot2 = 0.f;
        #pragma unroll
        for (int k = 0; k < NB_; k++) {
          dot0 = fmaf(rk, wf0[k], dot0);
          dot1 = fmaf(rk, wf1[k], dot1);
          dot2 = fmaf(rk, wf2[k], dot2);
          float rn = fmaf(c2, rk, -rkm1);
          rkm1 = rk; rk = rn;
        }
        xacc = fmaf(p0, bf0*gg.z + gg.w*dot0, xacc);
        float m1 = p1 * (bf1*gg.z + gg.w*dot1);
        float m2 = p2 * (bf2*gg.z + gg.w*dot2);
        a0 = fmaf(m1, dv.x, fmaf(m2, w0, a0));
        a1 = fmaf(m1, dv.y, fmaf(m2, w1, a1));
        a2 = fmaf(m1, dv.z, fmaf(m2, w2, a2));
      }
      long b = n*DD + d;
      XN(nr, d) = x[b] + xacc;
      VN(nr, d)      = vA[b]         + a0;   // channel 0 rows 0..15
      VN(16 + nr, d) = vA[NND + b]   + a1;   // channel 1 rows 16..31
      VN(32 + nr, d) = vA[2*NND + b] + a2;   // channel 2 rows 32..47
    }
  }
  __syncthreads();
  int lane = tid & 63, wv = tid >> 6;   // wv 0..7
  int l15 = lane & 15, q = lane >> 4;
  int d = wv*16 + l15;                  // this wave's column slice
  // ---- phase 1: U & V projections for column-slice d, per channel (split per-wave) ----
  v4f aU[3] = {}, aV[3] = {};
  #pragma unroll
  for (int s = 0; s < 4; s++) {
    long boff = (long)d*128 + s*32 + q*8;
    v8s buh = *(const v8s*)(Uth + boff);
    v8s bul = *(const v8s*)(Utl + boff);
    v8s bvh = *(const v8s*)(Vth + boff);
    v8s bvl = *(const v8s*)(Vtl + boff);
    #pragma unroll
    for (int c = 0; c < 3; c++) {
      float4 f0 = *(const float4*)&VN(c*16 + l15, s*32 + q*8);
      float4 f1 = *(const float4*)&VN(c*16 + l15, s*32 + q*8 + 4);
      v8s ah, al;
      SPLIT8(f0, f1, ah, al);
      MFMA3(aU[c], ah, al, buh, bul);
      MFMA3(aV[c], ah, al, bvh, bvl);
    }
  }
  float sreg[4], vn2[4];
  #pragma unroll
  for (int i = 0; i < 4; i++) {
    sreg[i] = aU[0][i]*aV[0][i] + aU[1][i]*aV[1][i] + aU[2][i]*aV[2][i];
    vn2[i]  = aV[0][i]*aV[0][i] + aV[1][i]*aV[1][i] + aV[2][i]*aV[2][i];
  }
  // capture vold (v_new) to registers before the cat/t2 overlay destroys VN
  float vold[4][3];
  #pragma unroll
  for (int i = 0; i < 4; i++)
    #pragma unroll
    for (int c = 0; c < 3; c++) vold[i][c] = VN(c*16 + q*4 + i, d);
  __syncthreads();   // all reads of VN complete
  // ---- build cat = [x_new | Vn] (fp32, overlays VN region) ----
  {
    int r = tid >> 5, c4 = tid & 31;   // 512 tasks: 16 rows x 32 float4-chunks
    *(float4*)&CAT(r, c4*4) = *(const float4*)&XN(r, c4*4);
  }
  #pragma unroll
  for (int i = 0; i < 4; i++)
    CAT(q*4 + i, 128 + d) = sqrtf(vn2[i] + 1e-8f);
  __syncthreads();
  // ---- GEMM1: t2[:, d] = silu(cat @ Wu1 + b1), K=256 ----
  {
    v4f acc = {};
    #pragma unroll
    for (int s = 0; s < 8; s++) {
      float4 f0 = *(const float4*)&CAT(l15, s*32 + q*8);
      float4 f1 = *(const float4*)&CAT(l15, s*32 + q*8 + 4);
      v8s ah, al;
      SPLIT8(f0, f1, ah, al);
      v8s bh = *(const v8s*)(W1h + (long)d*256 + s*32 + q*8);
      v8s bl = *(const v8s*)(W1l + (long)d*256 + s*32 + q*8);
      MFMA3(acc, ah, al, bh, bl);
    }
    float bb = b1[d];
    #pragma unroll
    for (int i = 0; i < 4; i++)
      T2(q*4 + i, d) = silu_f(acc[i] + bb);
  }
  __syncthreads();
  // ---- GEMM2 + epilogue ----
  {
    v4f acc[3] = {};
    #pragma unroll
    for (int s = 0; s < 4; s++) {
      float4 f0 = *(const float4*)&T2(l15, s*32 + q*8);
      float4 f1 = *(const float4*)&T2(l15, s*32 + q*8 + 4);
      v8s ah, al;
      SPLIT8(f0, f1, ah, al);
      #pragma unroll
      for (int g = 0; g < 3; g++) {
        int n = g*128 + d;                 // avv: d, asv: 128+d, ass: 256+d
        v8s bh = *(const v8s*)(W2h + (long)n*128 + s*32 + q*8);
        v8s bl = *(const v8s*)(W2l + (long)n*128 + s*32 + q*8);
        MFMA3(acc[g], ah, al, bh, bl);
      }
    }
    float bavv = b2[d], basv = b2[128 + d], bass = b2[256 + d];
    #pragma unroll
    for (int i = 0; i < 4; i++) {
      int lr = q*4 + i;
      long row = nb + lr;
      float avv = acc[0][i] + bavv;
      float asv = acc[1][i] + basv;
      float ass = acc[2][i] + bass;
      x[row*DD + d] = CAT(lr, d) + ass + asv * sreg[i];
      #pragma unroll
      for (int c = 0; c < 3; c++)
        vB[(long)c*NND + row*DD + d] = fmaf(avv, aU[c][i], vold[i][c]);
    }
  }
  #undef VN
  #undef XN
  #undef CAT
  #undef T2
}

// ---------------- output head + segment sum: 4 nodes/block, LDS-staged x ----------------
__global__ void __launch_bounds__(256) out_kernel(
    const float* __restrict__ x, const float* __restrict__ Wo1,
    const float* __restrict__ bo1, const float* __restrict__ Wo2,
    const float* __restrict__ bo2, const int* __restrict__ batch,
    float* __restrict__ out) {
  __shared__ float xs[4][132];
  int tid = threadIdx.x;
  long n0 = (long)blockIdx.x * 4;
  if (tid < 128) {
    int r = tid >> 5, c4 = tid & 31;
    *(float4*)&xs[r][c4*4] = *(const float4*)(x + (n0 + r)*128 + c4*4);
  }
  __syncthreads();
  int wv = tid >> 6, t = tid & 63;
  float acc = bo1[t];
  #pragma unroll 16
  for (int k = 0; k < DD; k++) acc = fmaf(xs[wv][k], Wo1[k*HH + t], acc);
  float val = silu_f(acc) * Wo2[t];
  #pragma unroll
  for (int off = 32; off > 0; off >>= 1) val += __shfl_down(val, off);
  if (t == 0) atomicAdd(&out[batch[n0 + wv]], val + bo2[0]);
}

// ---------------- launcher ----------------
extern "C" void kernel_launch(void* const* d_in, const int* in_sizes, int n_in,
                              void* d_out, int out_size, void* d_ws, size_t ws_size,
                              hipStream_t stream) {
  const int*   at_no = (const int*)d_in[0];
  const float* pos   = (const float*)d_in[1];
  const int*   ei    = (const int*)d_in[2];
  const int*   batch = (const int*)d_in[3];
  const float* emb   = (const float*)d_in[4];
  const float* Wf    = (const float*)d_in[5];
  const float* bfp   = (const float*)d_in[6];
  const float* Wm1   = (const float*)d_in[7];
  const float* bm1   = (const float*)d_in[8];
  const float* Wm2   = (const float*)d_in[9];
  const float* bm2   = (const float*)d_in[10];
  const float* U     = (const float*)d_in[11];
  const float* V     = (const float*)d_in[12];
  const float* Wu1   = (const float*)d_in[13];
  const float* bu1   = (const float*)d_in[14];
  const float* Wu2   = (const float*)d_in[15];
  const float* bu2   = (const float*)d_in[16];
  const float* Wo1   = (const float*)d_in[17];
  const float* bo1   = (const float*)d_in[18];
  const float* Wo2   = (const float*)d_in[19];
  const float* bo2   = (const float*)d_in[20];
  float* out = (float*)d_out;

  char* w = (char*)d_ws;
  auto alloc = [&](size_t bytes) -> void* {
    void* p = (void*)w;
    w += (bytes + 255) & ~(size_t)255;
    return p;
  };
  float*  x      = (float*)alloc(sizeof(float)*(size_t)NN*DD);
  float*  v_a    = (float*)alloc(sizeof(float)*(size_t)NN*D3);   // plane layout [3][NN][DD]
  float*  v_b    = (float*)alloc(sizeof(float)*(size_t)NN*D3);
  float*  t1     = (float*)alloc(sizeof(float)*(size_t)NN*DD);   // phi slice 2 (in-place)
  float*  phiS   = (float*)alloc(sizeof(float)*(size_t)NN*DD);   // phi slice 1
  float*  phi0   = (float*)alloc(sizeof(float)*(size_t)NN*DD);   // phi slice 0
  short*  wbh    = (short*)alloc(sizeof(short)*(size_t)3*LSZ);   // bf16-hi weights
  short*  wbl    = (short*)alloc(sizeof(short)*(size_t)3*LSZ);   // bf16-lo weights
  int*    srcs   = (int*)alloc(sizeof(int)*(size_t)ECAP);
  float4* eg1    = (float4*)alloc(sizeof(float4)*(size_t)ECAP);
  float4* eg2    = (float4*)alloc(sizeof(float4)*(size_t)ECAP);
  int*    indptr = (int*)alloc(sizeof(int)*((size_t)NN+1));
  int*    counts = (int*)alloc(sizeof(int)*(size_t)NN);

  if ((size_t)(w - (char*)d_ws) > ws_size) {   // diagnostic guard: zeros => ws too small
    zero_f_kernel<<<2, 256, 0, stream>>>(out, NG_);
    return;
  }

  zero_f_kernel<<<2048, 256, 0, stream>>>(v_a, (long)NN*D3);
  zero_f_kernel<<<2, 256, 0, stream>>>(out, NG_);
  zero_i_kernel<<<64, 256, 0, stream>>>(counts, NN);
  init_x_kernel<<<(NN*DD + 255)/256, 256, 0, stream>>>(at_no, emb, x);
  prep_w_kernel<<<(3*LSZ + 255)/256, 256, 0, stream>>>(Wm1, Wm2, U, V, Wu1, Wu2, wbh, wbl);
  hist_kernel<<<(NE + 255)/256, 256, 0, stream>>>(ei, pos, counts);
  scan_kernel<<<1, 1024, 0, stream>>>(counts, indptr, NN);
  zero_i_kernel<<<64, 256, 0, stream>>>(counts, NN);
  fill_kernel<<<(NE + 255)/256, 256, 0, stream>>>(ei, pos, indptr, counts, srcs, eg1, eg2);

  const int MB = (NN + 31) / 32;    // 1563
  float* vcur = v_a;
  float* vnext = v_b;
  for (int l = 0; l < 3; l++) {
    const float* Wf_l  = Wf  + (size_t)l*NB_*D3;
    const float* bf_l  = bfp + (size_t)l*D3;
    const float* bm1_l = bm1 + (size_t)l*DD;
    const float* bm2_l = bm2 + (size_t)l*D3;
    const float* bu1_l = bu1 + (size_t)l*DD;
    const float* bu2_l = bu2 + (size_t)l*D3;
    const short* Lh = wbh + (size_t)l*LSZ;
    const short* Ll = wbl + (size_t)l*LSZ;
    const short* Wm1h = Lh,          *Wm1L = Ll;
    const short* Wm2h = Lh + 16384,  *Wm2L = Ll + 16384;
    const short* Uh   = Lh + 65536,  *UL   = Ll + 65536;
    const short* Vh   = Lh + 81920,  *VL   = Ll + 81920;
    const short* Wu1h = Lh + 98304,  *Wu1L = Ll + 98304;
    const short* Wu2h = Lh + 131072, *Wu2L = Ll + 131072;

    // t1 = silu(x@Wm1 + bm1)
    mfma_gemm_kernel<true><<<MB, 256, 0, stream>>>(x, Wm1h, Wm1L, bm1_l, t1, NN);
    // all 3 phi slices in one pass: slice0->phi0, slice1->phiS, slice2->t1 (in place)
    mfma_gemm_phi_kernel<<<MB, 512, 0, stream>>>(t1, Wm2h, Wm2L, bm2_l, phi0, phiS, t1, NN);
    // fused: edge sweep + U/V proj + a-MLP + x,v update (x_new/v_new stay in LDS)
    muva_kernel<<<NN/16, 512, 0, stream>>>(phi0, phiS, t1, vcur, vnext, x,
                                           srcs, eg1, eg2, indptr, Wf_l, bf_l,
                                           Uh, UL, Vh, VL,
                                           Wu1h, Wu1L, bu1_l, Wu2h, Wu2L, bu2_l);

    float* tmp = vcur; vcur = vnext; vnext = tmp;
  }

  out_kernel<<<NN/4, 256, 0, stream>>>(x, Wo1, bo1, Wo2, bo2, batch, out);

  (void)in_sizes; (void)n_in; (void)out_size; (void)ws_size;
}